// Round 4
// baseline (5665.351 us; speedup 1.0000x reference)
//
#include <hip/hip_runtime.h>
#include <hip/hip_bf16.h>
#include <stdint.h>

#define B_ 64
#define S_ 1024
#define E_ 1024
#define H_ 2048
#define NF_ 8
#define NH_ 4
#define NIT_ 10

typedef __attribute__((ext_vector_type(8))) short vshort8;
typedef __attribute__((ext_vector_type(8))) __bf16 vbf16x8;
typedef __attribute__((ext_vector_type(4))) float vfloat4;

// ---------------- threefry2x32 (JAX-exact) ----------------
__device__ __forceinline__ uint32_t rotl32(uint32_t v, int n) { return (v << n) | (v >> (32 - n)); }

__device__ __forceinline__ void threefry2x32(uint32_t k0, uint32_t k1, uint32_t x0, uint32_t x1,
                                             uint32_t& o0, uint32_t& o1) {
  uint32_t ks2 = k0 ^ k1 ^ 0x1BD11BDAu;
  x0 += k0; x1 += k1;
#define TF_R(r) { x0 += x1; x1 = rotl32(x1, (r)); x1 ^= x0; }
  TF_R(13) TF_R(15) TF_R(26) TF_R(6)
  x0 += k1;  x1 += ks2 + 1u;
  TF_R(17) TF_R(29) TF_R(16) TF_R(24)
  x0 += ks2; x1 += k0 + 2u;
  TF_R(13) TF_R(15) TF_R(26) TF_R(6)
  x0 += k0;  x1 += k1 + 3u;
  TF_R(17) TF_R(29) TF_R(16) TF_R(24)
  x0 += k1;  x1 += ks2 + 4u;
  TF_R(13) TF_R(15) TF_R(26) TF_R(6)
  x0 += ks2; x1 += k0 + 5u;
#undef TF_R
  o0 = x0; o1 = x1;
}

// partitionable threefry 32-bit bits: element i (i < 2^32) ->
//   bits1 ^ bits2 of threefry(key, (counts_hi=0, counts_lo=i))   [jax#13862]
__device__ __forceinline__ uint32_t tf_bits_part(uint32_t k0, uint32_t k1, uint32_t i) {
  uint32_t o0, o1;
  threefry2x32(k0, k1, 0u, i, o0, o1);
  return o0 ^ o1;
}

// XLA/Giles erfinv (f32)
__device__ __forceinline__ float erfinv_f(float x) {
  float w = -log1pf(-x * x);
  float p;
  if (w < 5.0f) {
    w -= 2.5f;
    p = 2.81022636e-08f;
    p = 3.43273939e-07f + p * w;
    p = -3.5233877e-06f + p * w;
    p = -4.39150654e-06f + p * w;
    p = 0.00021858087f + p * w;
    p = -0.00125372503f + p * w;
    p = -0.00417768164f + p * w;
    p = 0.246640727f + p * w;
    p = 1.50140941f + p * w;
  } else {
    w = sqrtf(w) - 3.0f;
    p = -0.000200214257f;
    p = 0.000100950558f + p * w;
    p = 0.00134934322f + p * w;
    p = -0.00367342844f + p * w;
    p = 0.00573950773f + p * w;
    p = -0.0076224613f + p * w;
    p = 0.00943887047f + p * w;
    p = 1.00167406f + p * w;
    p = 2.83297682f + p * w;
  }
  return p * x;
}

__device__ __forceinline__ float bits_to_normal(uint32_t bits) {
  uint32_t fb = (bits >> 9) | 0x3F800000u;
  float f = __uint_as_float(fb) - 1.0f;       // [0,1)
  const float lo = -0.99999994f;              // nextafter(-1,0)
  float u = fmaxf(lo, f * 2.0f + lo);         // (maxval-minval) rounds to exactly 2.0f
  return 1.41421356f * erfinv_f(u);
}

// split helper: v = hi + lo (both bf16)
__device__ __forceinline__ void split_bf16(float v, __hip_bfloat16& hi, __hip_bfloat16& lo) {
  hi = __float2bfloat16(v);
  lo = __float2bfloat16(v - __bfloat162float(hi));
}

// ---------------- ctx = mean over S ----------------
__global__ __launch_bounds__(256) void colmean_partial(const float* __restrict__ cur,
                                                       float* __restrict__ part) {
  int blk = blockIdx.x;            // 512 blocks: b*8 + chunk
  int b = blk >> 3, c = blk & 7;
  int t = threadIdx.x;
  const float* base = cur + ((size_t)b * S_ + (size_t)c * 128) * E_;
  float4 s = {0.f, 0.f, 0.f, 0.f};
  for (int si = 0; si < 128; ++si) {
    float4 v = *(const float4*)(base + (size_t)si * E_ + t * 4);
    s.x += v.x; s.y += v.y; s.z += v.z; s.w += v.w;
  }
  *(float4*)(part + ((size_t)c * B_ + b) * E_ + t * 4) = s;
}

__global__ __launch_bounds__(256) void colmean_final(const float* __restrict__ part,
                                                     float* __restrict__ ctx) {
  int i = blockIdx.x * 256 + threadIdx.x;  // < 65536
  float s = 0.f;
#pragma unroll
  for (int c = 0; c < 8; ++c) s += part[(size_t)c * (B_ * E_) + i];
  ctx[i] = s * (1.0f / S_);
}

// ---------------- small-M (64) f32 GEMM: C = A@W + bias ----------------
__global__ __launch_bounds__(256) void gemm_m64(const float* __restrict__ A,
                                                const float* __restrict__ W,
                                                const float* __restrict__ bias,
                                                float* __restrict__ C, int K, int N) {
  __shared__ float Als[64][36];
  int t = threadIdx.x;
  int col = blockIdx.x * 64 + (t & 63);
  int mg = t >> 6;
  float acc[16];
#pragma unroll
  for (int m = 0; m < 16; ++m) acc[m] = 0.f;
  int lrow = t >> 2, lkc = (t & 3) * 8;
  for (int k0 = 0; k0 < K; k0 += 32) {
    *(float4*)&Als[lrow][lkc]     = *(const float4*)&A[(size_t)lrow * K + k0 + lkc];
    *(float4*)&Als[lrow][lkc + 4] = *(const float4*)&A[(size_t)lrow * K + k0 + lkc + 4];
    __syncthreads();
#pragma unroll 8
    for (int k = 0; k < 32; ++k) {
      float wv = W[(size_t)(k0 + k) * N + col];
#pragma unroll
      for (int m = 0; m < 16; ++m) acc[m] += Als[mg * 16 + m][k] * wv;
    }
    __syncthreads();
  }
  float bv = bias[col];
#pragma unroll
  for (int m = 0; m < 16; ++m) C[(size_t)(mg * 16 + m) * N + col] = acc[m] + bv;
}

// ---------------- LayerNorm (+relu), f32 in, f32 or bf16 out ----------------
template <bool OUT_BF16, bool RELU>
__global__ __launch_bounds__(256) void ln_kernel(const float* __restrict__ X,
                                                 const float* __restrict__ g,
                                                 const float* __restrict__ be,
                                                 void* __restrict__ out, int Wd) {
  __shared__ float red[256];
  int row = blockIdx.x, t = threadIdx.x;
  const float* xr = X + (size_t)row * Wd;
  float s = 0.f;
  for (int c = t; c < Wd; c += 256) s += xr[c];
  red[t] = s; __syncthreads();
  for (int k = 128; k > 0; k >>= 1) { if (t < k) red[t] += red[t + k]; __syncthreads(); }
  float mean = red[0] / Wd;
  __syncthreads();
  float s2 = 0.f;
  for (int c = t; c < Wd; c += 256) { float d = xr[c] - mean; s2 += d * d; }
  red[t] = s2; __syncthreads();
  for (int k = 128; k > 0; k >>= 1) { if (t < k) red[t] += red[t + k]; __syncthreads(); }
  float rstd = rsqrtf(red[0] / Wd + 1e-5f);
  for (int c = t; c < Wd; c += 256) {
    float v = (xr[c] - mean) * rstd * g[c] + be[c];
    if (RELU) v = fmaxf(v, 0.f);
    if (OUT_BF16) ((__hip_bfloat16*)out)[(size_t)row * Wd + c] = __float2bfloat16(v);
    else          ((float*)out)[(size_t)row * Wd + c] = v;
  }
}

// ---------------- LayerNorm + relu, split hi/lo bf16 outputs ----------------
__global__ __launch_bounds__(256) void ln_kernel2(const float* __restrict__ X,
                                                  const float* __restrict__ g,
                                                  const float* __restrict__ be,
                                                  __hip_bfloat16* __restrict__ oh,
                                                  __hip_bfloat16* __restrict__ ol, int Wd) {
  __shared__ float red[256];
  int row = blockIdx.x, t = threadIdx.x;
  const float* xr = X + (size_t)row * Wd;
  float s = 0.f;
  for (int c = t; c < Wd; c += 256) s += xr[c];
  red[t] = s; __syncthreads();
  for (int k = 128; k > 0; k >>= 1) { if (t < k) red[t] += red[t + k]; __syncthreads(); }
  float mean = red[0] / Wd;
  __syncthreads();
  float s2 = 0.f;
  for (int c = t; c < Wd; c += 256) { float d = xr[c] - mean; s2 += d * d; }
  red[t] = s2; __syncthreads();
  for (int k = 128; k > 0; k >>= 1) { if (t < k) red[t] += red[t + k]; __syncthreads(); }
  float rstd = rsqrtf(red[0] / Wd + 1e-5f);
  for (int c = t; c < Wd; c += 256) {
    float v = (xr[c] - mean) * rstd * g[c] + be[c];
    v = fmaxf(v, 0.f);
    __hip_bfloat16 hi, lo;
    split_bf16(v, hi, lo);
    oh[(size_t)row * Wd + c] = hi;
    ol[(size_t)row * Wd + c] = lo;
  }
}

// ---------------- f32 -> bf16 transpose: Wt[n][k] = W[k][n] ----------------
__global__ __launch_bounds__(256) void transpose_to_bf16(const float* __restrict__ W,
                                                         __hip_bfloat16* __restrict__ Wt,
                                                         int K, int N) {
  __shared__ float tile[32][33];
  int n0 = blockIdx.x * 32, k0 = blockIdx.y * 32;
  int tx = threadIdx.x & 31, ty = threadIdx.x >> 5;
  for (int r = ty; r < 32; r += 8) tile[r][tx] = W[(size_t)(k0 + r) * N + n0 + tx];
  __syncthreads();
  for (int r = ty; r < 32; r += 8) Wt[(size_t)(n0 + r) * K + k0 + tx] = __float2bfloat16(tile[tx][r]);
}

// ---------------- f32 -> split bf16 transpose ----------------
__global__ __launch_bounds__(256) void transpose_to_bf16x2(const float* __restrict__ W,
                                                           __hip_bfloat16* __restrict__ Wh,
                                                           __hip_bfloat16* __restrict__ Wl,
                                                           int K, int N) {
  __shared__ float tile[32][33];
  int n0 = blockIdx.x * 32, k0 = blockIdx.y * 32;
  int tx = threadIdx.x & 31, ty = threadIdx.x >> 5;
  for (int r = ty; r < 32; r += 8) tile[r][tx] = W[(size_t)(k0 + r) * N + n0 + tx];
  __syncthreads();
  for (int r = ty; r < 32; r += 8) {
    __hip_bfloat16 hi, lo;
    split_bf16(tile[tx][r], hi, lo);
    Wh[(size_t)(n0 + r) * K + k0 + tx] = hi;
    Wl[(size_t)(n0 + r) * K + k0 + tx] = lo;
  }
}

// ---------------- bf16 MFMA GEMM (plain): C = A @ Bt^T + bias ----------------
__global__ __launch_bounds__(256) void mfma_gemm(const __hip_bfloat16* __restrict__ A,
                                                 const __hip_bfloat16* __restrict__ Bt,
                                                 const float* __restrict__ bias,
                                                 float* __restrict__ C,
                                                 int M, int N, int K, int relu) {
  __shared__ short Als[128][40];
  __shared__ short Bls[128][40];
  int t = threadIdx.x;
  int m0 = blockIdx.y * 128, n0 = blockIdx.x * 128;
  int lane = t & 63, wid = t >> 6;
  int wm = (wid >> 1) * 64, wn = (wid & 1) * 64;
  int lrow = lane & 15, kb = (lane >> 4) * 8;
  vfloat4 acc[4][4];
#pragma unroll
  for (int i = 0; i < 4; ++i)
#pragma unroll
    for (int j = 0; j < 4; ++j) acc[i][j] = (vfloat4){0.f, 0.f, 0.f, 0.f};
  const short* Ag = (const short*)A;
  const short* Bg = (const short*)Bt;
  int srow = t >> 2, skc = (t & 3) * 8;
  for (int k0 = 0; k0 < K; k0 += 32) {
#pragma unroll
    for (int rr = 0; rr < 128; rr += 64) {
      *(vshort8*)&Als[srow + rr][skc] = *(const vshort8*)&Ag[(size_t)(m0 + srow + rr) * K + k0 + skc];
      *(vshort8*)&Bls[srow + rr][skc] = *(const vshort8*)&Bg[(size_t)(n0 + srow + rr) * K + k0 + skc];
    }
    __syncthreads();
    vbf16x8 af[4], bq[4];
#pragma unroll
    for (int i = 0; i < 4; ++i) af[i] = *(const vbf16x8*)&Als[wm + i * 16 + lrow][kb];
#pragma unroll
    for (int j = 0; j < 4; ++j) bq[j] = *(const vbf16x8*)&Bls[wn + j * 16 + lrow][kb];
#pragma unroll
    for (int i = 0; i < 4; ++i)
#pragma unroll
      for (int j = 0; j < 4; ++j)
        acc[i][j] = __builtin_amdgcn_mfma_f32_16x16x32_bf16(af[i], bq[j], acc[i][j], 0, 0, 0);
    __syncthreads();
  }
  int crow0 = m0 + wm + (lane >> 4) * 4;
  int ccol0 = n0 + wn + lrow;
#pragma unroll
  for (int i = 0; i < 4; ++i) {
#pragma unroll
    for (int j = 0; j < 4; ++j) {
      int col = ccol0 + j * 16;
      float bv = bias[col];
#pragma unroll
      for (int r = 0; r < 4; ++r) {
        int rowi = crow0 + i * 16 + r;
        float v = acc[i][j][r] + bv;
        if (relu) v = fmaxf(v, 0.f);
        C[(size_t)rowi * N + col] = v;
      }
    }
  }
}

// ---------------- split-bf16 MFMA GEMM (3 MFMA): C = (Ah+Al)@(Bh+Bl)^T + bias ----------------
__global__ __launch_bounds__(256) void mfma_gemm3(const __hip_bfloat16* __restrict__ Ah,
                                                  const __hip_bfloat16* __restrict__ Al,
                                                  const __hip_bfloat16* __restrict__ Bh,
                                                  const __hip_bfloat16* __restrict__ Bl,
                                                  const float* __restrict__ bias,
                                                  float* __restrict__ C,
                                                  int M, int N, int K) {
  __shared__ short Ahs[128][40];
  __shared__ short Als_[128][40];
  __shared__ short Bhs[128][40];
  __shared__ short Bls_[128][40];
  int t = threadIdx.x;
  int m0 = blockIdx.y * 128, n0 = blockIdx.x * 128;
  int lane = t & 63, wid = t >> 6;
  int wm = (wid >> 1) * 64, wn = (wid & 1) * 64;
  int lrow = lane & 15, kb = (lane >> 4) * 8;
  vfloat4 acc[4][4];
#pragma unroll
  for (int i = 0; i < 4; ++i)
#pragma unroll
    for (int j = 0; j < 4; ++j) acc[i][j] = (vfloat4){0.f, 0.f, 0.f, 0.f};
  const short* Ahg = (const short*)Ah;
  const short* Alg = (const short*)Al;
  const short* Bhg = (const short*)Bh;
  const short* Blg = (const short*)Bl;
  int srow = t >> 2, skc = (t & 3) * 8;
  for (int k0 = 0; k0 < K; k0 += 32) {
#pragma unroll
    for (int rr = 0; rr < 128; rr += 64) {
      size_t ga = (size_t)(m0 + srow + rr) * K + k0 + skc;
      size_t gb = (size_t)(n0 + srow + rr) * K + k0 + skc;
      *(vshort8*)&Ahs[srow + rr][skc]  = *(const vshort8*)&Ahg[ga];
      *(vshort8*)&Als_[srow + rr][skc] = *(const vshort8*)&Alg[ga];
      *(vshort8*)&Bhs[srow + rr][skc]  = *(const vshort8*)&Bhg[gb];
      *(vshort8*)&Bls_[srow + rr][skc] = *(const vshort8*)&Blg[gb];
    }
    __syncthreads();
    vbf16x8 afh[4], afl[4], bqh[4], bql[4];
#pragma unroll
    for (int i = 0; i < 4; ++i) {
      afh[i] = *(const vbf16x8*)&Ahs[wm + i * 16 + lrow][kb];
      afl[i] = *(const vbf16x8*)&Als_[wm + i * 16 + lrow][kb];
    }
#pragma unroll
    for (int j = 0; j < 4; ++j) {
      bqh[j] = *(const vbf16x8*)&Bhs[wn + j * 16 + lrow][kb];
      bql[j] = *(const vbf16x8*)&Bls_[wn + j * 16 + lrow][kb];
    }
#pragma unroll
    for (int i = 0; i < 4; ++i)
#pragma unroll
      for (int j = 0; j < 4; ++j) {
        acc[i][j] = __builtin_amdgcn_mfma_f32_16x16x32_bf16(afl[i], bqh[j], acc[i][j], 0, 0, 0);
        acc[i][j] = __builtin_amdgcn_mfma_f32_16x16x32_bf16(afh[i], bql[j], acc[i][j], 0, 0, 0);
        acc[i][j] = __builtin_amdgcn_mfma_f32_16x16x32_bf16(afh[i], bqh[j], acc[i][j], 0, 0, 0);
      }
    __syncthreads();
  }
  int crow0 = m0 + wm + (lane >> 4) * 4;
  int ccol0 = n0 + wn + lrow;
#pragma unroll
  for (int i = 0; i < 4; ++i) {
#pragma unroll
    for (int j = 0; j < 4; ++j) {
      int col = ccol0 + j * 16;
      float bv = bias[col];
#pragma unroll
      for (int r = 0; r < 4; ++r) {
        int rowi = crow0 + i * 16 + r;
        C[(size_t)rowi * N + col] = acc[i][j][r] + bv;
      }
    }
  }
}

// ---------------- hyp = traj + 0.1 * normal(key(42))  [partitionable threefry] ----------------
__global__ __launch_bounds__(256) void hyp_noise(const float* __restrict__ traj,
                                                 float* __restrict__ x) {
  uint32_t j = blockIdx.x * 256 + threadIdx.x;  // < 1048576
#pragma unroll
  for (int h = 0; h < 2; ++h) {
    uint32_t i = j + h * 1048576u;
    float n = bits_to_normal(tf_bits_part(0u, 42u, i));
    uint32_t b0 = i >> 15, fe0 = i & 8191u;
    x[i] = traj[((size_t)b0 << 13) + fe0] + 0.1f * n;
  }
}

// ---------------- x -= 0.1*u (+ 0.01*normal(fold_in(key(7),it)) if it<9) ----------------
__global__ __launch_bounds__(256) void update_x(float* __restrict__ x, const float* __restrict__ u,
                                                int it) {
  uint32_t j = blockIdx.x * 256 + threadIdx.x;  // < 1048576
  uint32_t k0 = 0, k1 = 0;
  if (it < NIT_ - 1) threefry2x32(0u, 7u, 0u, (uint32_t)it, k0, k1);  // fold_in(key(7), it)
#pragma unroll
  for (int h = 0; h < 2; ++h) {
    uint32_t i = j + h * 1048576u;
    float xv = x[i] - 0.1f * u[i];
    if (it < NIT_ - 1) xv += 0.01f * bits_to_normal(tf_bits_part(k0, k1, i));
    x[i] = xv;
  }
}

// ---------------- build refine input (split bf16): [x | ce | neighbor] ----------------
__global__ __launch_bounds__(256) void build_inp2(const float* __restrict__ x,
                                                  const float* __restrict__ ctx_h,
                                                  __hip_bfloat16* __restrict__ ih,
                                                  __hip_bfloat16* __restrict__ il) {
  int row = blockIdx.y;                      // 2048 = bh*8 + f
  int col = blockIdx.x * 256 + threadIdx.x;  // < 3072
  int bh = row >> 3, f = row & 7;
  float v;
  if (col < E_) {
    v = x[(size_t)row * E_ + col];
  } else if (col < 2 * E_) {
    v = ctx_h[(size_t)(bh >> 2) * H_ + (col - E_)];
  } else {
    int c = col - 2 * E_;
    int fp = (f == 0) ? 0 : f - 1;
    int fn = (f == NF_ - 1) ? NF_ - 1 : f + 1;
    v = 0.5f * (x[(size_t)(bh * NF_ + fp) * E_ + c] + x[(size_t)(bh * NF_ + fn) * E_ + c]);
  }
  __hip_bfloat16 hi, lo;
  split_bf16(v, hi, lo);
  ih[(size_t)row * 3072 + col] = hi;
  il[(size_t)row * 3072 + col] = lo;
}

// ---------------- energy: concat input (bf16) ----------------
__global__ __launch_bounds__(256) void build_xcat(const float* __restrict__ x,
                                                  const float* __restrict__ ctx_h,
                                                  __hip_bfloat16* __restrict__ xc) {
  int row = blockIdx.y;
  int col = blockIdx.x * 256 + threadIdx.x;  // < 2048
  int bh = row >> 3;
  float v = (col < E_) ? x[(size_t)row * E_ + col]
                       : ctx_h[(size_t)(bh >> 2) * H_ + (col - E_)];
  xc[(size_t)row * 2048 + col] = __float2bfloat16(v);
}

// ---------------- per-row dot with en_w3 ----------------
__global__ __launch_bounds__(256) void rowdot(const float* __restrict__ X2,
                                              const float* __restrict__ w3,
                                              const float* __restrict__ b3,
                                              float* __restrict__ srow) {
  __shared__ float red[256];
  int row = blockIdx.x, t = threadIdx.x;
  const float* xr = X2 + (size_t)row * E_;
  float s = 0.f;
  for (int c = t; c < E_; c += 256) s += xr[c] * w3[c];
  red[t] = s; __syncthreads();
  for (int k = 128; k > 0; k >>= 1) { if (t < k) red[t] += red[t + k]; __syncthreads(); }
  if (t == 0) srow[row] = red[0] + b3[0];
}

// ---------------- energies[bh] = coherence + 0.1*smoothness + supervision ----------------
__global__ __launch_bounds__(256) void energy_final(const float* __restrict__ x,
                                                    const float* __restrict__ ft,
                                                    const float* __restrict__ srow,
                                                    float* __restrict__ energ) {
  __shared__ float red[256];
  int bh = blockIdx.x, t = threadIdx.x;
  int b = bh >> 2;
  const float* xb = x + (size_t)bh * (NF_ * E_);
  const float* fb = ft + (size_t)b * (NF_ * E_);
  float sup = 0.f;
  for (int i = t; i < NF_ * E_; i += 256) { float d = xb[i] - fb[i]; sup += d * d; }
  red[t] = sup; __syncthreads();
  for (int k = 128; k > 0; k >>= 1) { if (t < k) red[t] += red[t + k]; __syncthreads(); }
  float supervision = red[0] / (NF_ * E_);
  float smooth = 0.f;
  for (int d = 0; d < NF_ - 1; ++d) {
    __syncthreads();
    float sd = 0.f;
    for (int e = t; e < E_; e += 256) {
      float df = xb[(d + 1) * E_ + e] - xb[d * E_ + e];
      sd += df * df;
    }
    red[t] = sd; __syncthreads();
    for (int k = 128; k > 0; k >>= 1) { if (t < k) red[t] += red[t + k]; __syncthreads(); }
    smooth += sqrtf(red[0]);
  }
  smooth *= (1.0f / (NF_ - 1));
  if (t == 0) {
    float coh = 0.f;
    for (int f = 0; f < NF_; ++f) coh += srow[bh * NF_ + f];
    coh *= (1.0f / NF_);
    energ[bh] = coh + 0.1f * smooth + supervision;
  }
}

__global__ void softmax_probs(const float* __restrict__ energ, float* __restrict__ probs) {
  int b = threadIdx.x;
  if (b < B_) {
    float e[NH_], m = -1e30f;
#pragma unroll
    for (int h = 0; h < NH_; ++h) { e[h] = -energ[b * NH_ + h]; m = fmaxf(m, e[h]); }
    float s = 0.f, p[NH_];
#pragma unroll
    for (int h = 0; h < NH_; ++h) { p[h] = expf(e[h] - m); s += p[h]; }
#pragma unroll
    for (int h = 0; h < NH_; ++h) probs[b * NH_ + h] = p[h] / s;
  }
}

__global__ __launch_bounds__(256) void predict(const float* __restrict__ x,
                                               const float* __restrict__ probs,
                                               float* __restrict__ out) {
  int i = blockIdx.x * 256 + threadIdx.x;  // < 524288
  int b = i >> 13, fe = i & 8191;
  float s = 0.f;
#pragma unroll
  for (int h = 0; h < NH_; ++h) s += x[(size_t)(b * NH_ + h) * 8192 + fe] * probs[b * NH_ + h];
  out[i] = s;
}

extern "C" void kernel_launch(void* const* d_in, const int* in_sizes, int n_in,
                              void* d_out, int out_size, void* d_ws, size_t ws_size,
                              hipStream_t stream) {
  const float* cur   = (const float*)d_in[0];
  const float* ftrue = (const float*)d_in[1];
  const float* ce_w1 = (const float*)d_in[2];
  const float* ce_b1 = (const float*)d_in[3];
  const float* ce_g  = (const float*)d_in[4];
  const float* ce_be = (const float*)d_in[5];
  const float* ce_w2 = (const float*)d_in[6];
  const float* ce_b2 = (const float*)d_in[7];
  const float* tp_w1 = (const float*)d_in[8];
  const float* tp_b1 = (const float*)d_in[9];
  const float* tp_g  = (const float*)d_in[10];
  const float* tp_be = (const float*)d_in[11];
  const float* tp_w2 = (const float*)d_in[12];
  const float* tp_b2 = (const float*)d_in[13];
  const float* en_w1 = (const float*)d_in[14];
  const float* en_b1 = (const float*)d_in[15];
  const float* en_g  = (const float*)d_in[16];
  const float* en_be = (const float*)d_in[17];
  const float* en_w2 = (const float*)d_in[18];
  const float* en_b2 = (const float*)d_in[19];
  const float* en_w3 = (const float*)d_in[20];
  const float* en_b3 = (const float*)d_in[21];
  const float* rn_w1 = (const float*)d_in[22];
  const float* rn_b1 = (const float*)d_in[23];
  const float* rn_g  = (const float*)d_in[24];
  const float* rn_be = (const float*)d_in[25];
  const float* rn_w2 = (const float*)d_in[26];
  const float* rn_b2 = (const float*)d_in[27];
  (void)in_sizes; (void)n_in; (void)out_size; (void)ws_size;

  char* w = (char*)d_ws;
  size_t off = 0;
  auto alloc = [&](size_t bytes) -> void* {
    void* p = w + off;
    off += (bytes + 255) & ~(size_t)255;
    return p;
  };
  float* part   = (float*)alloc((size_t)8 * B_ * E_ * 4);
  float* ctx    = (float*)alloc((size_t)B_ * E_ * 4);
  float* g1     = (float*)alloc((size_t)B_ * H_ * 4);
  float* act    = (float*)alloc((size_t)B_ * H_ * 4);
  float* ctx_h  = (float*)alloc((size_t)B_ * H_ * 4);
  float* traj   = (float*)alloc((size_t)B_ * NF_ * E_ * 4);
  float* x      = (float*)alloc((size_t)2097152 * 4);
  float* h1     = (float*)alloc((size_t)2048 * 2048 * 4);
  float* u      = (float*)alloc((size_t)2048 * 1024 * 4);
  __hip_bfloat16* inp_h  = (__hip_bfloat16*)alloc((size_t)2048 * 3072 * 2);
  __hip_bfloat16* inp_l  = (__hip_bfloat16*)alloc((size_t)2048 * 3072 * 2);
  __hip_bfloat16* ub_h   = (__hip_bfloat16*)alloc((size_t)2048 * 2048 * 2);
  __hip_bfloat16* ub_l   = (__hip_bfloat16*)alloc((size_t)2048 * 2048 * 2);
  float* srow   = (float*)alloc((size_t)2048 * 4);
  float* energ  = (float*)alloc((size_t)256 * 4);
  float* probs  = (float*)alloc((size_t)256 * 4);
  __hip_bfloat16* rn_w1t_h = (__hip_bfloat16*)alloc((size_t)2048 * 3072 * 2);
  __hip_bfloat16* rn_w1t_l = (__hip_bfloat16*)alloc((size_t)2048 * 3072 * 2);
  __hip_bfloat16* rn_w2t_h = (__hip_bfloat16*)alloc((size_t)1024 * 2048 * 2);
  __hip_bfloat16* rn_w2t_l = (__hip_bfloat16*)alloc((size_t)1024 * 2048 * 2);
  __hip_bfloat16* en_w1t = (__hip_bfloat16*)alloc((size_t)2048 * 2048 * 2);
  __hip_bfloat16* en_w2t = (__hip_bfloat16*)alloc((size_t)1024 * 2048 * 2);

  // ctx = mean_S
  colmean_partial<<<512, 256, 0, stream>>>(cur, part);
  colmean_final<<<256, 256, 0, stream>>>(part, ctx);

  // weight prep
  transpose_to_bf16x2<<<dim3(2048 / 32, 3072 / 32), 256, 0, stream>>>(rn_w1, rn_w1t_h, rn_w1t_l, 3072, 2048);
  transpose_to_bf16x2<<<dim3(1024 / 32, 2048 / 32), 256, 0, stream>>>(rn_w2, rn_w2t_h, rn_w2t_l, 2048, 1024);
  transpose_to_bf16<<<dim3(2048 / 32, 2048 / 32), 256, 0, stream>>>(en_w1, en_w1t, 2048, 2048);
  transpose_to_bf16<<<dim3(1024 / 32, 2048 / 32), 256, 0, stream>>>(en_w2, en_w2t, 2048, 1024);

  // context/trajectory path (f32)
  gemm_m64<<<H_ / 64, 256, 0, stream>>>(ctx, ce_w1, ce_b1, g1, E_, H_);
  ln_kernel<false, true><<<B_, 256, 0, stream>>>(g1, ce_g, ce_be, act, H_);
  gemm_m64<<<H_ / 64, 256, 0, stream>>>(act, ce_w2, ce_b2, ctx_h, H_, H_);
  gemm_m64<<<H_ / 64, 256, 0, stream>>>(ctx_h, tp_w1, tp_b1, g1, H_, H_);
  ln_kernel<false, true><<<B_, 256, 0, stream>>>(g1, tp_g, tp_be, act, H_);
  gemm_m64<<<8192 / 64, 256, 0, stream>>>(act, tp_w2, tp_b2, traj, H_, 8192);

  // hypotheses = traj + noise
  hyp_noise<<<4096, 256, 0, stream>>>(traj, x);

  // refinement loop (split-bf16 GEMMs for precision)
  for (int it = 0; it < NIT_; ++it) {
    build_inp2<<<dim3(12, 2048), 256, 0, stream>>>(x, ctx_h, inp_h, inp_l);
    mfma_gemm3<<<dim3(16, 16), 256, 0, stream>>>(inp_h, inp_l, rn_w1t_h, rn_w1t_l, rn_b1, h1,
                                                 2048, 2048, 3072);
    ln_kernel2<<<2048, 256, 0, stream>>>(h1, rn_g, rn_be, ub_h, ub_l, 2048);
    mfma_gemm3<<<dim3(8, 16), 256, 0, stream>>>(ub_h, ub_l, rn_w2t_h, rn_w2t_l, rn_b2, u,
                                                2048, 1024, 2048);
    update_x<<<4096, 256, 0, stream>>>(x, u, it);
  }

  // energy + softmax + weighted prediction (plain bf16 is plenty here)
  build_xcat<<<dim3(8, 2048), 256, 0, stream>>>(x, ctx_h, inp_h);
  mfma_gemm<<<dim3(16, 16), 256, 0, stream>>>(inp_h, en_w1t, en_b1, h1, 2048, 2048, 2048, 0);
  ln_kernel<true, true><<<2048, 256, 0, stream>>>(h1, en_g, en_be, ub_h, 2048);
  mfma_gemm<<<dim3(8, 16), 256, 0, stream>>>(ub_h, en_w2t, en_b2, u, 2048, 1024, 2048, 1);
  rowdot<<<2048, 256, 0, stream>>>(u, en_w3, en_b3, srow);
  energy_final<<<256, 256, 0, stream>>>(x, ftrue, srow, energ);
  softmax_probs<<<1, 64, 0, stream>>>(energ, probs);
  predict<<<2048, 256, 0, stream>>>(x, probs, (float*)d_out);
}

// Round 5
// 3025.224 us; speedup vs baseline: 1.8727x; 1.8727x over previous
//
#include <hip/hip_runtime.h>
#include <hip/hip_bf16.h>
#include <stdint.h>

#define B_ 64
#define S_ 1024
#define E_ 1024
#define H_ 2048
#define NF_ 8
#define NH_ 4
#define NIT_ 10

typedef __attribute__((ext_vector_type(8))) short vshort8;
typedef __attribute__((ext_vector_type(8))) __bf16 vbf16x8;
typedef __attribute__((ext_vector_type(4))) float vfloat4;

// ---------------- threefry2x32 (JAX-exact) ----------------
__device__ __forceinline__ uint32_t rotl32(uint32_t v, int n) { return (v << n) | (v >> (32 - n)); }

__device__ __forceinline__ void threefry2x32(uint32_t k0, uint32_t k1, uint32_t x0, uint32_t x1,
                                             uint32_t& o0, uint32_t& o1) {
  uint32_t ks2 = k0 ^ k1 ^ 0x1BD11BDAu;
  x0 += k0; x1 += k1;
#define TF_R(r) { x0 += x1; x1 = rotl32(x1, (r)); x1 ^= x0; }
  TF_R(13) TF_R(15) TF_R(26) TF_R(6)
  x0 += k1;  x1 += ks2 + 1u;
  TF_R(17) TF_R(29) TF_R(16) TF_R(24)
  x0 += ks2; x1 += k0 + 2u;
  TF_R(13) TF_R(15) TF_R(26) TF_R(6)
  x0 += k0;  x1 += k1 + 3u;
  TF_R(17) TF_R(29) TF_R(16) TF_R(24)
  x0 += k1;  x1 += ks2 + 4u;
  TF_R(13) TF_R(15) TF_R(26) TF_R(6)
  x0 += ks2; x1 += k0 + 5u;
#undef TF_R
  o0 = x0; o1 = x1;
}

// partitionable threefry 32-bit bits: element i -> bits1 ^ bits2 of threefry(key, (0, i))
__device__ __forceinline__ uint32_t tf_bits_part(uint32_t k0, uint32_t k1, uint32_t i) {
  uint32_t o0, o1;
  threefry2x32(k0, k1, 0u, i, o0, o1);
  return o0 ^ o1;
}

// XLA/Giles erfinv (f32)
__device__ __forceinline__ float erfinv_f(float x) {
  float w = -log1pf(-x * x);
  float p;
  if (w < 5.0f) {
    w -= 2.5f;
    p = 2.81022636e-08f;
    p = 3.43273939e-07f + p * w;
    p = -3.5233877e-06f + p * w;
    p = -4.39150654e-06f + p * w;
    p = 0.00021858087f + p * w;
    p = -0.00125372503f + p * w;
    p = -0.00417768164f + p * w;
    p = 0.246640727f + p * w;
    p = 1.50140941f + p * w;
  } else {
    w = sqrtf(w) - 3.0f;
    p = -0.000200214257f;
    p = 0.000100950558f + p * w;
    p = 0.00134934322f + p * w;
    p = -0.00367342844f + p * w;
    p = 0.00573950773f + p * w;
    p = -0.0076224613f + p * w;
    p = 0.00943887047f + p * w;
    p = 1.00167406f + p * w;
    p = 2.83297682f + p * w;
  }
  return p * x;
}

__device__ __forceinline__ float bits_to_normal(uint32_t bits) {
  uint32_t fb = (bits >> 9) | 0x3F800000u;
  float f = __uint_as_float(fb) - 1.0f;       // [0,1)
  const float lo = -0.99999994f;              // nextafter(-1,0)
  float u = fmaxf(lo, f * 2.0f + lo);
  return 1.41421356f * erfinv_f(u);
}

// split helper: v = hi + lo (both bf16)
__device__ __forceinline__ void split_bf16(float v, __hip_bfloat16& hi, __hip_bfloat16& lo) {
  hi = __float2bfloat16(v);
  lo = __float2bfloat16(v - __bfloat162float(hi));
}

// ---------------- ctx = mean over S ----------------
__global__ __launch_bounds__(256) void colmean_partial(const float* __restrict__ cur,
                                                       float* __restrict__ part) {
  int blk = blockIdx.x;            // 512 blocks: b*8 + chunk
  int b = blk >> 3, c = blk & 7;
  int t = threadIdx.x;
  const float* base = cur + ((size_t)b * S_ + (size_t)c * 128) * E_;
  float4 s = {0.f, 0.f, 0.f, 0.f};
  for (int si = 0; si < 128; ++si) {
    float4 v = *(const float4*)(base + (size_t)si * E_ + t * 4);
    s.x += v.x; s.y += v.y; s.z += v.z; s.w += v.w;
  }
  *(float4*)(part + ((size_t)c * B_ + b) * E_ + t * 4) = s;
}

__global__ __launch_bounds__(256) void colmean_final(const float* __restrict__ part,
                                                     float* __restrict__ ctx) {
  int i = blockIdx.x * 256 + threadIdx.x;  // < 65536
  float s = 0.f;
#pragma unroll
  for (int c = 0; c < 8; ++c) s += part[(size_t)c * (B_ * E_) + i];
  ctx[i] = s * (1.0f / S_);
}

// ---------------- f32 -> split bf16 elementwise ----------------
__global__ __launch_bounds__(256) void split_f32(const float* __restrict__ X,
                                                 __hip_bfloat16* __restrict__ hi,
                                                 __hip_bfloat16* __restrict__ lo) {
  int i = blockIdx.x * 256 + threadIdx.x;
  __hip_bfloat16 h, l;
  split_bf16(X[i], h, l);
  hi[i] = h;
  lo[i] = l;
}

// ---------------- LayerNorm (+relu), f32 in, f32 or bf16 out ----------------
template <bool OUT_BF16, bool RELU>
__global__ __launch_bounds__(256) void ln_kernel(const float* __restrict__ X,
                                                 const float* __restrict__ g,
                                                 const float* __restrict__ be,
                                                 void* __restrict__ out, int Wd) {
  __shared__ float red[256];
  int row = blockIdx.x, t = threadIdx.x;
  const float* xr = X + (size_t)row * Wd;
  float s = 0.f;
  for (int c = t; c < Wd; c += 256) s += xr[c];
  red[t] = s; __syncthreads();
  for (int k = 128; k > 0; k >>= 1) { if (t < k) red[t] += red[t + k]; __syncthreads(); }
  float mean = red[0] / Wd;
  __syncthreads();
  float s2 = 0.f;
  for (int c = t; c < Wd; c += 256) { float d = xr[c] - mean; s2 += d * d; }
  red[t] = s2; __syncthreads();
  for (int k = 128; k > 0; k >>= 1) { if (t < k) red[t] += red[t + k]; __syncthreads(); }
  float rstd = rsqrtf(red[0] / Wd + 1e-5f);
  for (int c = t; c < Wd; c += 256) {
    float v = (xr[c] - mean) * rstd * g[c] + be[c];
    if (RELU) v = fmaxf(v, 0.f);
    if (OUT_BF16) ((__hip_bfloat16*)out)[(size_t)row * Wd + c] = __float2bfloat16(v);
    else          ((float*)out)[(size_t)row * Wd + c] = v;
  }
}

// ---------------- LayerNorm + relu, split hi/lo bf16 outputs ----------------
__global__ __launch_bounds__(256) void ln_kernel2(const float* __restrict__ X,
                                                  const float* __restrict__ g,
                                                  const float* __restrict__ be,
                                                  __hip_bfloat16* __restrict__ oh,
                                                  __hip_bfloat16* __restrict__ ol, int Wd) {
  __shared__ float red[256];
  int row = blockIdx.x, t = threadIdx.x;
  const float* xr = X + (size_t)row * Wd;
  float s = 0.f;
  for (int c = t; c < Wd; c += 256) s += xr[c];
  red[t] = s; __syncthreads();
  for (int k = 128; k > 0; k >>= 1) { if (t < k) red[t] += red[t + k]; __syncthreads(); }
  float mean = red[0] / Wd;
  __syncthreads();
  float s2 = 0.f;
  for (int c = t; c < Wd; c += 256) { float d = xr[c] - mean; s2 += d * d; }
  red[t] = s2; __syncthreads();
  for (int k = 128; k > 0; k >>= 1) { if (t < k) red[t] += red[t + k]; __syncthreads(); }
  float rstd = rsqrtf(red[0] / Wd + 1e-5f);
  for (int c = t; c < Wd; c += 256) {
    float v = (xr[c] - mean) * rstd * g[c] + be[c];
    v = fmaxf(v, 0.f);
    __hip_bfloat16 hi, lo;
    split_bf16(v, hi, lo);
    oh[(size_t)row * Wd + c] = hi;
    ol[(size_t)row * Wd + c] = lo;
  }
}

// ---------------- f32 -> bf16 transpose: Wt[n][k] = W[k][n] ----------------
__global__ __launch_bounds__(256) void transpose_to_bf16(const float* __restrict__ W,
                                                         __hip_bfloat16* __restrict__ Wt,
                                                         int K, int N) {
  __shared__ float tile[32][33];
  int n0 = blockIdx.x * 32, k0 = blockIdx.y * 32;
  int tx = threadIdx.x & 31, ty = threadIdx.x >> 5;
  for (int r = ty; r < 32; r += 8) tile[r][tx] = W[(size_t)(k0 + r) * N + n0 + tx];
  __syncthreads();
  for (int r = ty; r < 32; r += 8) Wt[(size_t)(n0 + r) * K + k0 + tx] = __float2bfloat16(tile[tx][r]);
}

// ---------------- f32 -> split bf16 transpose ----------------
__global__ __launch_bounds__(256) void transpose_to_bf16x2(const float* __restrict__ W,
                                                           __hip_bfloat16* __restrict__ Wh,
                                                           __hip_bfloat16* __restrict__ Wl,
                                                           int K, int N) {
  __shared__ float tile[32][33];
  int n0 = blockIdx.x * 32, k0 = blockIdx.y * 32;
  int tx = threadIdx.x & 31, ty = threadIdx.x >> 5;
  for (int r = ty; r < 32; r += 8) tile[r][tx] = W[(size_t)(k0 + r) * N + n0 + tx];
  __syncthreads();
  for (int r = ty; r < 32; r += 8) {
    __hip_bfloat16 hi, lo;
    split_bf16(tile[tx][r], hi, lo);
    Wh[(size_t)(n0 + r) * K + k0 + tx] = hi;
    Wl[(size_t)(n0 + r) * K + k0 + tx] = lo;
  }
}

// ---------------- skinny split-bf16 MFMA GEMM: M=64, tile 64x128, split-K ----------------
// grid: (N/128, SK). partial[z][64][N] += A(64xKc) @ Bt(128xKc)^T
__global__ __launch_bounds__(256) void mfma_skinny3(const __hip_bfloat16* __restrict__ Ah,
                                                    const __hip_bfloat16* __restrict__ Al,
                                                    const __hip_bfloat16* __restrict__ Bh,
                                                    const __hip_bfloat16* __restrict__ Bl,
                                                    float* __restrict__ part,
                                                    int N, int K, int Kc) {
  __shared__ short AhS[64][40];
  __shared__ short AlS[64][40];
  __shared__ short BhS[128][40];
  __shared__ short BlS[128][40];
  int t = threadIdx.x;
  int n0 = blockIdx.x * 128;
  int kbeg = blockIdx.y * Kc;
  int lane = t & 63, wid = t >> 6;
  int wn = wid * 32;
  int lrow = lane & 15, kb = (lane >> 4) * 8;
  vfloat4 acc[4][2];
#pragma unroll
  for (int i = 0; i < 4; ++i)
#pragma unroll
    for (int j = 0; j < 2; ++j) acc[i][j] = (vfloat4){0.f, 0.f, 0.f, 0.f};
  const short* Ahg = (const short*)Ah;
  const short* Alg = (const short*)Al;
  const short* Bhg = (const short*)Bh;
  const short* Blg = (const short*)Bl;
  int srow = t >> 2, skc = (t & 3) * 8;
  for (int k0 = kbeg; k0 < kbeg + Kc; k0 += 32) {
    size_t ga = (size_t)srow * K + k0 + skc;
    *(vshort8*)&AhS[srow][skc] = *(const vshort8*)&Ahg[ga];
    *(vshort8*)&AlS[srow][skc] = *(const vshort8*)&Alg[ga];
#pragma unroll
    for (int rr = 0; rr < 128; rr += 64) {
      size_t gb = (size_t)(n0 + srow + rr) * K + k0 + skc;
      *(vshort8*)&BhS[srow + rr][skc] = *(const vshort8*)&Bhg[gb];
      *(vshort8*)&BlS[srow + rr][skc] = *(const vshort8*)&Blg[gb];
    }
    __syncthreads();
    vbf16x8 afh[4], afl[4], bqh[2], bql[2];
#pragma unroll
    for (int i = 0; i < 4; ++i) {
      afh[i] = *(const vbf16x8*)&AhS[i * 16 + lrow][kb];
      afl[i] = *(const vbf16x8*)&AlS[i * 16 + lrow][kb];
    }
#pragma unroll
    for (int j = 0; j < 2; ++j) {
      bqh[j] = *(const vbf16x8*)&BhS[wn + j * 16 + lrow][kb];
      bql[j] = *(const vbf16x8*)&BlS[wn + j * 16 + lrow][kb];
    }
#pragma unroll
    for (int i = 0; i < 4; ++i)
#pragma unroll
      for (int j = 0; j < 2; ++j) {
        acc[i][j] = __builtin_amdgcn_mfma_f32_16x16x32_bf16(afl[i], bqh[j], acc[i][j], 0, 0, 0);
        acc[i][j] = __builtin_amdgcn_mfma_f32_16x16x32_bf16(afh[i], bql[j], acc[i][j], 0, 0, 0);
        acc[i][j] = __builtin_amdgcn_mfma_f32_16x16x32_bf16(afh[i], bqh[j], acc[i][j], 0, 0, 0);
      }
    __syncthreads();
  }
  size_t zbase = (size_t)blockIdx.y * 64;
  int crow0 = (lane >> 4) * 4;
  int ccol0 = n0 + wn + lrow;
#pragma unroll
  for (int i = 0; i < 4; ++i) {
#pragma unroll
    for (int j = 0; j < 2; ++j) {
      int col = ccol0 + j * 16;
#pragma unroll
      for (int r = 0; r < 4; ++r) {
        int rowi = i * 16 + crow0 + r;
        part[(zbase + rowi) * N + col] = acc[i][j][r];
      }
    }
  }
}

// ---------------- C[64][N] = sum_z part[z][64][N] + bias ----------------
__global__ __launch_bounds__(256) void reduce_bias(const float* __restrict__ part,
                                                   const float* __restrict__ bias,
                                                   float* __restrict__ C, int N, int SK) {
  int i = blockIdx.x * 256 + threadIdx.x;  // < 64*N
  int col = i & (N - 1);                   // N is a power of two
  float s = bias[col];
  for (int z = 0; z < SK; ++z) s += part[(size_t)z * 64 * N + i];
  C[i] = s;
}

// ---------------- bf16 MFMA GEMM (plain): C = A @ Bt^T + bias ----------------
__global__ __launch_bounds__(256) void mfma_gemm(const __hip_bfloat16* __restrict__ A,
                                                 const __hip_bfloat16* __restrict__ Bt,
                                                 const float* __restrict__ bias,
                                                 float* __restrict__ C,
                                                 int M, int N, int K, int relu) {
  __shared__ short Als[128][40];
  __shared__ short Bls[128][40];
  int t = threadIdx.x;
  int m0 = blockIdx.y * 128, n0 = blockIdx.x * 128;
  int lane = t & 63, wid = t >> 6;
  int wm = (wid >> 1) * 64, wn = (wid & 1) * 64;
  int lrow = lane & 15, kb = (lane >> 4) * 8;
  vfloat4 acc[4][4];
#pragma unroll
  for (int i = 0; i < 4; ++i)
#pragma unroll
    for (int j = 0; j < 4; ++j) acc[i][j] = (vfloat4){0.f, 0.f, 0.f, 0.f};
  const short* Ag = (const short*)A;
  const short* Bg = (const short*)Bt;
  int srow = t >> 2, skc = (t & 3) * 8;
  for (int k0 = 0; k0 < K; k0 += 32) {
#pragma unroll
    for (int rr = 0; rr < 128; rr += 64) {
      *(vshort8*)&Als[srow + rr][skc] = *(const vshort8*)&Ag[(size_t)(m0 + srow + rr) * K + k0 + skc];
      *(vshort8*)&Bls[srow + rr][skc] = *(const vshort8*)&Bg[(size_t)(n0 + srow + rr) * K + k0 + skc];
    }
    __syncthreads();
    vbf16x8 af[4], bq[4];
#pragma unroll
    for (int i = 0; i < 4; ++i) af[i] = *(const vbf16x8*)&Als[wm + i * 16 + lrow][kb];
#pragma unroll
    for (int j = 0; j < 4; ++j) bq[j] = *(const vbf16x8*)&Bls[wn + j * 16 + lrow][kb];
#pragma unroll
    for (int i = 0; i < 4; ++i)
#pragma unroll
      for (int j = 0; j < 4; ++j)
        acc[i][j] = __builtin_amdgcn_mfma_f32_16x16x32_bf16(af[i], bq[j], acc[i][j], 0, 0, 0);
    __syncthreads();
  }
  int crow0 = m0 + wm + (lane >> 4) * 4;
  int ccol0 = n0 + wn + lrow;
#pragma unroll
  for (int i = 0; i < 4; ++i) {
#pragma unroll
    for (int j = 0; j < 4; ++j) {
      int col = ccol0 + j * 16;
      float bv = bias[col];
#pragma unroll
      for (int r = 0; r < 4; ++r) {
        int rowi = crow0 + i * 16 + r;
        float v = acc[i][j][r] + bv;
        if (relu) v = fmaxf(v, 0.f);
        C[(size_t)rowi * N + col] = v;
      }
    }
  }
}

// ---------------- split-bf16 MFMA GEMM (3 MFMA): C = (Ah+Al)@(Bh+Bl)^T + bias ----------------
__global__ __launch_bounds__(256) void mfma_gemm3(const __hip_bfloat16* __restrict__ Ah,
                                                  const __hip_bfloat16* __restrict__ Al,
                                                  const __hip_bfloat16* __restrict__ Bh,
                                                  const __hip_bfloat16* __restrict__ Bl,
                                                  const float* __restrict__ bias,
                                                  float* __restrict__ C,
                                                  int M, int N, int K) {
  __shared__ short Ahs[128][40];
  __shared__ short Als_[128][40];
  __shared__ short Bhs[128][40];
  __shared__ short Bls_[128][40];
  int t = threadIdx.x;
  int m0 = blockIdx.y * 128, n0 = blockIdx.x * 128;
  int lane = t & 63, wid = t >> 6;
  int wm = (wid >> 1) * 64, wn = (wid & 1) * 64;
  int lrow = lane & 15, kb = (lane >> 4) * 8;
  vfloat4 acc[4][4];
#pragma unroll
  for (int i = 0; i < 4; ++i)
#pragma unroll
    for (int j = 0; j < 4; ++j) acc[i][j] = (vfloat4){0.f, 0.f, 0.f, 0.f};
  const short* Ahg = (const short*)Ah;
  const short* Alg = (const short*)Al;
  const short* Bhg = (const short*)Bh;
  const short* Blg = (const short*)Bl;
  int srow = t >> 2, skc = (t & 3) * 8;
  for (int k0 = 0; k0 < K; k0 += 32) {
#pragma unroll
    for (int rr = 0; rr < 128; rr += 64) {
      size_t ga = (size_t)(m0 + srow + rr) * K + k0 + skc;
      size_t gb = (size_t)(n0 + srow + rr) * K + k0 + skc;
      *(vshort8*)&Ahs[srow + rr][skc]  = *(const vshort8*)&Ahg[ga];
      *(vshort8*)&Als_[srow + rr][skc] = *(const vshort8*)&Alg[ga];
      *(vshort8*)&Bhs[srow + rr][skc]  = *(const vshort8*)&Bhg[gb];
      *(vshort8*)&Bls_[srow + rr][skc] = *(const vshort8*)&Blg[gb];
    }
    __syncthreads();
    vbf16x8 afh[4], afl[4], bqh[4], bql[4];
#pragma unroll
    for (int i = 0; i < 4; ++i) {
      afh[i] = *(const vbf16x8*)&Ahs[wm + i * 16 + lrow][kb];
      afl[i] = *(const vbf16x8*)&Als_[wm + i * 16 + lrow][kb];
    }
#pragma unroll
    for (int j = 0; j < 4; ++j) {
      bqh[j] = *(const vbf16x8*)&Bhs[wn + j * 16 + lrow][kb];
      bql[j] = *(const vbf16x8*)&Bls_[wn + j * 16 + lrow][kb];
    }
#pragma unroll
    for (int i = 0; i < 4; ++i)
#pragma unroll
      for (int j = 0; j < 4; ++j) {
        acc[i][j] = __builtin_amdgcn_mfma_f32_16x16x32_bf16(afl[i], bqh[j], acc[i][j], 0, 0, 0);
        acc[i][j] = __builtin_amdgcn_mfma_f32_16x16x32_bf16(afh[i], bql[j], acc[i][j], 0, 0, 0);
        acc[i][j] = __builtin_amdgcn_mfma_f32_16x16x32_bf16(afh[i], bqh[j], acc[i][j], 0, 0, 0);
      }
    __syncthreads();
  }
  int crow0 = m0 + wm + (lane >> 4) * 4;
  int ccol0 = n0 + wn + lrow;
#pragma unroll
  for (int i = 0; i < 4; ++i) {
#pragma unroll
    for (int j = 0; j < 4; ++j) {
      int col = ccol0 + j * 16;
      float bv = bias[col];
#pragma unroll
      for (int r = 0; r < 4; ++r) {
        int rowi = crow0 + i * 16 + r;
        C[(size_t)rowi * N + col] = acc[i][j][r] + bv;
      }
    }
  }
}

// ---------------- hyp = traj + 0.1 * normal(key(42)) ----------------
__global__ __launch_bounds__(256) void hyp_noise(const float* __restrict__ traj,
                                                 float* __restrict__ x) {
  uint32_t j = blockIdx.x * 256 + threadIdx.x;  // < 1048576
#pragma unroll
  for (int h = 0; h < 2; ++h) {
    uint32_t i = j + h * 1048576u;
    float n = bits_to_normal(tf_bits_part(0u, 42u, i));
    uint32_t b0 = i >> 15, fe0 = i & 8191u;
    x[i] = traj[((size_t)b0 << 13) + fe0] + 0.1f * n;
  }
}

// ---------------- x -= 0.1*u (+ 0.01*normal(fold_in(key(7),it)) if it<9) ----------------
__global__ __launch_bounds__(256) void update_x(float* __restrict__ x, const float* __restrict__ u,
                                                int it) {
  uint32_t j = blockIdx.x * 256 + threadIdx.x;  // < 1048576
  uint32_t k0 = 0, k1 = 0;
  if (it < NIT_ - 1) threefry2x32(0u, 7u, 0u, (uint32_t)it, k0, k1);  // fold_in(key(7), it)
#pragma unroll
  for (int h = 0; h < 2; ++h) {
    uint32_t i = j + h * 1048576u;
    float xv = x[i] - 0.1f * u[i];
    if (it < NIT_ - 1) xv += 0.01f * bits_to_normal(tf_bits_part(k0, k1, i));
    x[i] = xv;
  }
}

// ---------------- build refine input (split bf16): [x | ce | neighbor] ----------------
__global__ __launch_bounds__(256) void build_inp2(const float* __restrict__ x,
                                                  const float* __restrict__ ctx_h,
                                                  __hip_bfloat16* __restrict__ ih,
                                                  __hip_bfloat16* __restrict__ il) {
  int row = blockIdx.y;                      // 2048 = bh*8 + f
  int col = blockIdx.x * 256 + threadIdx.x;  // < 3072
  int bh = row >> 3, f = row & 7;
  float v;
  if (col < E_) {
    v = x[(size_t)row * E_ + col];
  } else if (col < 2 * E_) {
    v = ctx_h[(size_t)(bh >> 2) * H_ + (col - E_)];
  } else {
    int c = col - 2 * E_;
    int fp = (f == 0) ? 0 : f - 1;
    int fn = (f == NF_ - 1) ? NF_ - 1 : f + 1;
    v = 0.5f * (x[(size_t)(bh * NF_ + fp) * E_ + c] + x[(size_t)(bh * NF_ + fn) * E_ + c]);
  }
  __hip_bfloat16 hi, lo;
  split_bf16(v, hi, lo);
  ih[(size_t)row * 3072 + col] = hi;
  il[(size_t)row * 3072 + col] = lo;
}

// ---------------- energy: concat input (bf16) ----------------
__global__ __launch_bounds__(256) void build_xcat(const float* __restrict__ x,
                                                  const float* __restrict__ ctx_h,
                                                  __hip_bfloat16* __restrict__ xc) {
  int row = blockIdx.y;
  int col = blockIdx.x * 256 + threadIdx.x;  // < 2048
  int bh = row >> 3;
  float v = (col < E_) ? x[(size_t)row * E_ + col]
                       : ctx_h[(size_t)(bh >> 2) * H_ + (col - E_)];
  xc[(size_t)row * 2048 + col] = __float2bfloat16(v);
}

// ---------------- per-row dot with en_w3 ----------------
__global__ __launch_bounds__(256) void rowdot(const float* __restrict__ X2,
                                              const float* __restrict__ w3,
                                              const float* __restrict__ b3,
                                              float* __restrict__ srow) {
  __shared__ float red[256];
  int row = blockIdx.x, t = threadIdx.x;
  const float* xr = X2 + (size_t)row * E_;
  float s = 0.f;
  for (int c = t; c < E_; c += 256) s += xr[c] * w3[c];
  red[t] = s; __syncthreads();
  for (int k = 128; k > 0; k >>= 1) { if (t < k) red[t] += red[t + k]; __syncthreads(); }
  if (t == 0) srow[row] = red[0] + b3[0];
}

// ---------------- energies[bh] = coherence + 0.1*smoothness + supervision ----------------
__global__ __launch_bounds__(256) void energy_final(const float* __restrict__ x,
                                                    const float* __restrict__ ft,
                                                    const float* __restrict__ srow,
                                                    float* __restrict__ energ) {
  __shared__ float red[256];
  int bh = blockIdx.x, t = threadIdx.x;
  int b = bh >> 2;
  const float* xb = x + (size_t)bh * (NF_ * E_);
  const float* fb = ft + (size_t)b * (NF_ * E_);
  float sup = 0.f;
  for (int i = t; i < NF_ * E_; i += 256) { float d = xb[i] - fb[i]; sup += d * d; }
  red[t] = sup; __syncthreads();
  for (int k = 128; k > 0; k >>= 1) { if (t < k) red[t] += red[t + k]; __syncthreads(); }
  float supervision = red[0] / (NF_ * E_);
  float smooth = 0.f;
  for (int d = 0; d < NF_ - 1; ++d) {
    __syncthreads();
    float sd = 0.f;
    for (int e = t; e < E_; e += 256) {
      float df = xb[(d + 1) * E_ + e] - xb[d * E_ + e];
      sd += df * df;
    }
    red[t] = sd; __syncthreads();
    for (int k = 128; k > 0; k >>= 1) { if (t < k) red[t] += red[t + k]; __syncthreads(); }
    smooth += sqrtf(red[0]);
  }
  smooth *= (1.0f / (NF_ - 1));
  if (t == 0) {
    float coh = 0.f;
    for (int f = 0; f < NF_; ++f) coh += srow[bh * NF_ + f];
    coh *= (1.0f / NF_);
    energ[bh] = coh + 0.1f * smooth + supervision;
  }
}

__global__ void softmax_probs(const float* __restrict__ energ, float* __restrict__ probs) {
  int b = threadIdx.x;
  if (b < B_) {
    float e[NH_], m = -1e30f;
#pragma unroll
    for (int h = 0; h < NH_; ++h) { e[h] = -energ[b * NH_ + h]; m = fmaxf(m, e[h]); }
    float s = 0.f, p[NH_];
#pragma unroll
    for (int h = 0; h < NH_; ++h) { p[h] = expf(e[h] - m); s += p[h]; }
#pragma unroll
    for (int h = 0; h < NH_; ++h) probs[b * NH_ + h] = p[h] / s;
  }
}

__global__ __launch_bounds__(256) void predict(const float* __restrict__ x,
                                               const float* __restrict__ probs,
                                               float* __restrict__ out) {
  int i = blockIdx.x * 256 + threadIdx.x;  // < 524288
  int b = i >> 13, fe = i & 8191;
  float s = 0.f;
#pragma unroll
  for (int h = 0; h < NH_; ++h) s += x[(size_t)(b * NH_ + h) * 8192 + fe] * probs[b * NH_ + h];
  out[i] = s;
}

extern "C" void kernel_launch(void* const* d_in, const int* in_sizes, int n_in,
                              void* d_out, int out_size, void* d_ws, size_t ws_size,
                              hipStream_t stream) {
  const float* cur   = (const float*)d_in[0];
  const float* ftrue = (const float*)d_in[1];
  const float* ce_w1 = (const float*)d_in[2];
  const float* ce_b1 = (const float*)d_in[3];
  const float* ce_g  = (const float*)d_in[4];
  const float* ce_be = (const float*)d_in[5];
  const float* ce_w2 = (const float*)d_in[6];
  const float* ce_b2 = (const float*)d_in[7];
  const float* tp_w1 = (const float*)d_in[8];
  const float* tp_b1 = (const float*)d_in[9];
  const float* tp_g  = (const float*)d_in[10];
  const float* tp_be = (const float*)d_in[11];
  const float* tp_w2 = (const float*)d_in[12];
  const float* tp_b2 = (const float*)d_in[13];
  const float* en_w1 = (const float*)d_in[14];
  const float* en_b1 = (const float*)d_in[15];
  const float* en_g  = (const float*)d_in[16];
  const float* en_be = (const float*)d_in[17];
  const float* en_w2 = (const float*)d_in[18];
  const float* en_b2 = (const float*)d_in[19];
  const float* en_w3 = (const float*)d_in[20];
  const float* en_b3 = (const float*)d_in[21];
  const float* rn_w1 = (const float*)d_in[22];
  const float* rn_b1 = (const float*)d_in[23];
  const float* rn_g  = (const float*)d_in[24];
  const float* rn_be = (const float*)d_in[25];
  const float* rn_w2 = (const float*)d_in[26];
  const float* rn_b2 = (const float*)d_in[27];
  (void)in_sizes; (void)n_in; (void)out_size; (void)ws_size;

  char* w = (char*)d_ws;
  size_t off = 0;
  auto alloc = [&](size_t bytes) -> void* {
    void* p = w + off;
    off += (bytes + 255) & ~(size_t)255;
    return p;
  };
  float* part   = (float*)alloc((size_t)8 * B_ * E_ * 4);
  float* ctx    = (float*)alloc((size_t)B_ * E_ * 4);
  float* g1     = (float*)alloc((size_t)B_ * H_ * 4);
  float* ctx_h  = (float*)alloc((size_t)B_ * H_ * 4);
  float* traj   = (float*)alloc((size_t)B_ * NF_ * E_ * 4);
  float* x      = (float*)alloc((size_t)2097152 * 4);
  float* h1     = (float*)alloc((size_t)2048 * 2048 * 4);   // also aliased as split-K partial
  float* u      = (float*)alloc((size_t)2048 * 1024 * 4);
  __hip_bfloat16* inp_h  = (__hip_bfloat16*)alloc((size_t)2048 * 3072 * 2);
  __hip_bfloat16* inp_l  = (__hip_bfloat16*)alloc((size_t)2048 * 3072 * 2);
  __hip_bfloat16* ub_h   = (__hip_bfloat16*)alloc((size_t)2048 * 2048 * 2);
  __hip_bfloat16* ub_l   = (__hip_bfloat16*)alloc((size_t)2048 * 2048 * 2);
  float* srow   = (float*)alloc((size_t)2048 * 4);
  float* energ  = (float*)alloc((size_t)256 * 4);
  float* probs  = (float*)alloc((size_t)256 * 4);
  __hip_bfloat16* rn_w1t_h = (__hip_bfloat16*)alloc((size_t)2048 * 3072 * 2);
  __hip_bfloat16* rn_w1t_l = (__hip_bfloat16*)alloc((size_t)2048 * 3072 * 2);
  __hip_bfloat16* rn_w2t_h = (__hip_bfloat16*)alloc((size_t)1024 * 2048 * 2);
  __hip_bfloat16* rn_w2t_l = (__hip_bfloat16*)alloc((size_t)1024 * 2048 * 2);
  __hip_bfloat16* en_w1t = (__hip_bfloat16*)alloc((size_t)2048 * 2048 * 2);
  __hip_bfloat16* en_w2t = (__hip_bfloat16*)alloc((size_t)1024 * 2048 * 2);
  // ctx-path skinny-GEMM buffers
  __hip_bfloat16* aA_h = (__hip_bfloat16*)alloc((size_t)B_ * H_ * 2);  // A operand hi (up to 64x2048)
  __hip_bfloat16* aA_l = (__hip_bfloat16*)alloc((size_t)B_ * H_ * 2);
  __hip_bfloat16* cw1t_h = (__hip_bfloat16*)alloc((size_t)2048 * 1024 * 2);
  __hip_bfloat16* cw1t_l = (__hip_bfloat16*)alloc((size_t)2048 * 1024 * 2);
  __hip_bfloat16* cw2t_h = (__hip_bfloat16*)alloc((size_t)2048 * 2048 * 2);
  __hip_bfloat16* cw2t_l = (__hip_bfloat16*)alloc((size_t)2048 * 2048 * 2);
  __hip_bfloat16* tw1t_h = (__hip_bfloat16*)alloc((size_t)2048 * 2048 * 2);
  __hip_bfloat16* tw1t_l = (__hip_bfloat16*)alloc((size_t)2048 * 2048 * 2);
  __hip_bfloat16* tw2t_h = (__hip_bfloat16*)alloc((size_t)8192 * 2048 * 2);
  __hip_bfloat16* tw2t_l = (__hip_bfloat16*)alloc((size_t)8192 * 2048 * 2);
  float* skpart = h1;  // split-K partials (max 8*64*8192*4 = 16.78MB == h1 size)

  // ctx = mean_S
  colmean_partial<<<512, 256, 0, stream>>>(cur, part);
  colmean_final<<<256, 256, 0, stream>>>(part, ctx);

  // weight prep (refine/energy)
  transpose_to_bf16x2<<<dim3(2048 / 32, 3072 / 32), 256, 0, stream>>>(rn_w1, rn_w1t_h, rn_w1t_l, 3072, 2048);
  transpose_to_bf16x2<<<dim3(1024 / 32, 2048 / 32), 256, 0, stream>>>(rn_w2, rn_w2t_h, rn_w2t_l, 2048, 1024);
  transpose_to_bf16<<<dim3(2048 / 32, 2048 / 32), 256, 0, stream>>>(en_w1, en_w1t, 2048, 2048);
  transpose_to_bf16<<<dim3(1024 / 32, 2048 / 32), 256, 0, stream>>>(en_w2, en_w2t, 2048, 1024);
  // weight prep (ctx path)
  transpose_to_bf16x2<<<dim3(2048 / 32, 1024 / 32), 256, 0, stream>>>(ce_w1, cw1t_h, cw1t_l, 1024, 2048);
  transpose_to_bf16x2<<<dim3(2048 / 32, 2048 / 32), 256, 0, stream>>>(ce_w2, cw2t_h, cw2t_l, 2048, 2048);
  transpose_to_bf16x2<<<dim3(2048 / 32, 2048 / 32), 256, 0, stream>>>(tp_w1, tw1t_h, tw1t_l, 2048, 2048);
  transpose_to_bf16x2<<<dim3(8192 / 32, 2048 / 32), 256, 0, stream>>>(tp_w2, tw2t_h, tw2t_l, 2048, 8192);

  // ---- context/trajectory path via skinny MFMA GEMMs (M=64) ----
  // g1 = ctx @ ce_w1 + b1
  split_f32<<<(B_ * E_) / 256, 256, 0, stream>>>(ctx, aA_h, aA_l);
  mfma_skinny3<<<dim3(2048 / 128, 4), 256, 0, stream>>>(aA_h, aA_l, cw1t_h, cw1t_l, skpart, 2048, 1024, 256);
  reduce_bias<<<(B_ * 2048) / 256, 256, 0, stream>>>(skpart, ce_b1, g1, 2048, 4);
  // act = relu(LN(g1)) (split)
  ln_kernel2<<<B_, 256, 0, stream>>>(g1, ce_g, ce_be, aA_h, aA_l, H_);
  // ctx_h = act @ ce_w2 + b2
  mfma_skinny3<<<dim3(2048 / 128, 8), 256, 0, stream>>>(aA_h, aA_l, cw2t_h, cw2t_l, skpart, 2048, 2048, 256);
  reduce_bias<<<(B_ * 2048) / 256, 256, 0, stream>>>(skpart, ce_b2, ctx_h, 2048, 8);
  // g1 = ctx_h @ tp_w1 + b1
  split_f32<<<(B_ * H_) / 256, 256, 0, stream>>>(ctx_h, aA_h, aA_l);
  mfma_skinny3<<<dim3(2048 / 128, 8), 256, 0, stream>>>(aA_h, aA_l, tw1t_h, tw1t_l, skpart, 2048, 2048, 256);
  reduce_bias<<<(B_ * 2048) / 256, 256, 0, stream>>>(skpart, tp_b1, g1, 2048, 8);
  // act = relu(LN(g1)) (split)
  ln_kernel2<<<B_, 256, 0, stream>>>(g1, tp_g, tp_be, aA_h, aA_l, H_);
  // traj = act @ tp_w2 + b2
  mfma_skinny3<<<dim3(8192 / 128, 8), 256, 0, stream>>>(aA_h, aA_l, tw2t_h, tw2t_l, skpart, 8192, 2048, 256);
  reduce_bias<<<(B_ * 8192) / 256, 256, 0, stream>>>(skpart, tp_b2, traj, 8192, 8);

  // hypotheses = traj + noise
  hyp_noise<<<4096, 256, 0, stream>>>(traj, x);

  // refinement loop (split-bf16 GEMMs for precision)
  for (int it = 0; it < NIT_; ++it) {
    build_inp2<<<dim3(12, 2048), 256, 0, stream>>>(x, ctx_h, inp_h, inp_l);
    mfma_gemm3<<<dim3(16, 16), 256, 0, stream>>>(inp_h, inp_l, rn_w1t_h, rn_w1t_l, rn_b1, h1,
                                                 2048, 2048, 3072);
    ln_kernel2<<<2048, 256, 0, stream>>>(h1, rn_g, rn_be, ub_h, ub_l, 2048);
    mfma_gemm3<<<dim3(8, 16), 256, 0, stream>>>(ub_h, ub_l, rn_w2t_h, rn_w2t_l, rn_b2, u,
                                                2048, 1024, 2048);
    update_x<<<4096, 256, 0, stream>>>(x, u, it);
  }

  // energy + softmax + weighted prediction (plain bf16 is plenty here)
  build_xcat<<<dim3(8, 2048), 256, 0, stream>>>(x, ctx_h, inp_h);
  mfma_gemm<<<dim3(16, 16), 256, 0, stream>>>(inp_h, en_w1t, en_b1, h1, 2048, 2048, 2048, 0);
  ln_kernel<true, true><<<2048, 256, 0, stream>>>(h1, en_g, en_be, ub_h, 2048);
  mfma_gemm<<<dim3(8, 16), 256, 0, stream>>>(ub_h, en_w2t, en_b2, u, 2048, 1024, 2048, 1);
  rowdot<<<2048, 256, 0, stream>>>(u, en_w3, en_b3, srow);
  energy_final<<<256, 256, 0, stream>>>(x, ftrue, srow, energ);
  softmax_probs<<<1, 64, 0, stream>>>(energ, probs);
  predict<<<2048, 256, 0, stream>>>(x, probs, (float*)d_out);
}

// Round 6
// 1906.098 us; speedup vs baseline: 2.9722x; 1.5871x over previous
//
#include <hip/hip_runtime.h>
#include <hip/hip_bf16.h>
#include <stdint.h>

#define B_ 64
#define S_ 1024
#define E_ 1024
#define H_ 2048
#define NF_ 8
#define NH_ 4
#define NIT_ 10

typedef __attribute__((ext_vector_type(8))) short vshort8;
typedef __attribute__((ext_vector_type(8))) __bf16 vbf16x8;
typedef __attribute__((ext_vector_type(4))) float vfloat4;

// ---------------- threefry2x32 (JAX-exact) ----------------
__device__ __forceinline__ uint32_t rotl32(uint32_t v, int n) { return (v << n) | (v >> (32 - n)); }

__device__ __forceinline__ void threefry2x32(uint32_t k0, uint32_t k1, uint32_t x0, uint32_t x1,
                                             uint32_t& o0, uint32_t& o1) {
  uint32_t ks2 = k0 ^ k1 ^ 0x1BD11BDAu;
  x0 += k0; x1 += k1;
#define TF_R(r) { x0 += x1; x1 = rotl32(x1, (r)); x1 ^= x0; }
  TF_R(13) TF_R(15) TF_R(26) TF_R(6)
  x0 += k1;  x1 += ks2 + 1u;
  TF_R(17) TF_R(29) TF_R(16) TF_R(24)
  x0 += ks2; x1 += k0 + 2u;
  TF_R(13) TF_R(15) TF_R(26) TF_R(6)
  x0 += k0;  x1 += k1 + 3u;
  TF_R(17) TF_R(29) TF_R(16) TF_R(24)
  x0 += k1;  x1 += ks2 + 4u;
  TF_R(13) TF_R(15) TF_R(26) TF_R(6)
  x0 += ks2; x1 += k0 + 5u;
#undef TF_R
  o0 = x0; o1 = x1;
}

// partitionable threefry 32-bit bits: element i -> bits1 ^ bits2 of threefry(key, (0, i))
__device__ __forceinline__ uint32_t tf_bits_part(uint32_t k0, uint32_t k1, uint32_t i) {
  uint32_t o0, o1;
  threefry2x32(k0, k1, 0u, i, o0, o1);
  return o0 ^ o1;
}

// XLA/Giles erfinv (f32)
__device__ __forceinline__ float erfinv_f(float x) {
  float w = -log1pf(-x * x);
  float p;
  if (w < 5.0f) {
    w -= 2.5f;
    p = 2.81022636e-08f;
    p = 3.43273939e-07f + p * w;
    p = -3.5233877e-06f + p * w;
    p = -4.39150654e-06f + p * w;
    p = 0.00021858087f + p * w;
    p = -0.00125372503f + p * w;
    p = -0.00417768164f + p * w;
    p = 0.246640727f + p * w;
    p = 1.50140941f + p * w;
  } else {
    w = sqrtf(w) - 3.0f;
    p = -0.000200214257f;
    p = 0.000100950558f + p * w;
    p = 0.00134934322f + p * w;
    p = -0.00367342844f + p * w;
    p = 0.00573950773f + p * w;
    p = -0.0076224613f + p * w;
    p = 0.00943887047f + p * w;
    p = 1.00167406f + p * w;
    p = 2.83297682f + p * w;
  }
  return p * x;
}

__device__ __forceinline__ float bits_to_normal(uint32_t bits) {
  uint32_t fb = (bits >> 9) | 0x3F800000u;
  float f = __uint_as_float(fb) - 1.0f;       // [0,1)
  const float lo = -0.99999994f;              // nextafter(-1,0)
  float u = fmaxf(lo, f * 2.0f + lo);
  return 1.41421356f * erfinv_f(u);
}

// split helper: v = hi + lo (both bf16)
__device__ __forceinline__ void split_bf16(float v, __hip_bfloat16& hi, __hip_bfloat16& lo) {
  hi = __float2bfloat16(v);
  lo = __float2bfloat16(v - __bfloat162float(hi));
}

// ---------------- ctx = mean over S ----------------
__global__ __launch_bounds__(256) void colmean_partial(const float* __restrict__ cur,
                                                       float* __restrict__ part) {
  int blk = blockIdx.x;            // 512 blocks: b*8 + chunk
  int b = blk >> 3, c = blk & 7;
  int t = threadIdx.x;
  const float* base = cur + ((size_t)b * S_ + (size_t)c * 128) * E_;
  float4 s = {0.f, 0.f, 0.f, 0.f};
  for (int si = 0; si < 128; ++si) {
    float4 v = *(const float4*)(base + (size_t)si * E_ + t * 4);
    s.x += v.x; s.y += v.y; s.z += v.z; s.w += v.w;
  }
  *(float4*)(part + ((size_t)c * B_ + b) * E_ + t * 4) = s;
}

__global__ __launch_bounds__(256) void colmean_final(const float* __restrict__ part,
                                                     float* __restrict__ ctx) {
  int i = blockIdx.x * 256 + threadIdx.x;  // < 65536
  float s = 0.f;
#pragma unroll
  for (int c = 0; c < 8; ++c) s += part[(size_t)c * (B_ * E_) + i];
  ctx[i] = s * (1.0f / S_);
}

// ---------------- f32 -> split bf16 elementwise ----------------
__global__ __launch_bounds__(256) void split_f32(const float* __restrict__ X,
                                                 __hip_bfloat16* __restrict__ hi,
                                                 __hip_bfloat16* __restrict__ lo) {
  int i = blockIdx.x * 256 + threadIdx.x;
  __hip_bfloat16 h, l;
  split_bf16(X[i], h, l);
  hi[i] = h;
  lo[i] = l;
}

// ---------------- LayerNorm (+relu), f32 in, f32 or bf16 out ----------------
template <bool OUT_BF16, bool RELU>
__global__ __launch_bounds__(256) void ln_kernel(const float* __restrict__ X,
                                                 const float* __restrict__ g,
                                                 const float* __restrict__ be,
                                                 void* __restrict__ out, int Wd) {
  __shared__ float red[256];
  int row = blockIdx.x, t = threadIdx.x;
  const float* xr = X + (size_t)row * Wd;
  float s = 0.f;
  for (int c = t; c < Wd; c += 256) s += xr[c];
  red[t] = s; __syncthreads();
  for (int k = 128; k > 0; k >>= 1) { if (t < k) red[t] += red[t + k]; __syncthreads(); }
  float mean = red[0] / Wd;
  __syncthreads();
  float s2 = 0.f;
  for (int c = t; c < Wd; c += 256) { float d = xr[c] - mean; s2 += d * d; }
  red[t] = s2; __syncthreads();
  for (int k = 128; k > 0; k >>= 1) { if (t < k) red[t] += red[t + k]; __syncthreads(); }
  float rstd = rsqrtf(red[0] / Wd + 1e-5f);
  for (int c = t; c < Wd; c += 256) {
    float v = (xr[c] - mean) * rstd * g[c] + be[c];
    if (RELU) v = fmaxf(v, 0.f);
    if (OUT_BF16) ((__hip_bfloat16*)out)[(size_t)row * Wd + c] = __float2bfloat16(v);
    else          ((float*)out)[(size_t)row * Wd + c] = v;
  }
}

// ---------------- LayerNorm + relu, split hi/lo bf16 outputs ----------------
__global__ __launch_bounds__(256) void ln_kernel2(const float* __restrict__ X,
                                                  const float* __restrict__ g,
                                                  const float* __restrict__ be,
                                                  __hip_bfloat16* __restrict__ oh,
                                                  __hip_bfloat16* __restrict__ ol, int Wd) {
  __shared__ float red[256];
  int row = blockIdx.x, t = threadIdx.x;
  const float* xr = X + (size_t)row * Wd;
  float s = 0.f;
  for (int c = t; c < Wd; c += 256) s += xr[c];
  red[t] = s; __syncthreads();
  for (int k = 128; k > 0; k >>= 1) { if (t < k) red[t] += red[t + k]; __syncthreads(); }
  float mean = red[0] / Wd;
  __syncthreads();
  float s2 = 0.f;
  for (int c = t; c < Wd; c += 256) { float d = xr[c] - mean; s2 += d * d; }
  red[t] = s2; __syncthreads();
  for (int k = 128; k > 0; k >>= 1) { if (t < k) red[t] += red[t + k]; __syncthreads(); }
  float rstd = rsqrtf(red[0] / Wd + 1e-5f);
  for (int c = t; c < Wd; c += 256) {
    float v = (xr[c] - mean) * rstd * g[c] + be[c];
    v = fmaxf(v, 0.f);
    __hip_bfloat16 hi, lo;
    split_bf16(v, hi, lo);
    oh[(size_t)row * Wd + c] = hi;
    ol[(size_t)row * Wd + c] = lo;
  }
}

// ---------------- f32 -> bf16 transpose: Wt[n][k] = W[k][n] ----------------
__global__ __launch_bounds__(256) void transpose_to_bf16(const float* __restrict__ W,
                                                         __hip_bfloat16* __restrict__ Wt,
                                                         int K, int N) {
  __shared__ float tile[32][33];
  int n0 = blockIdx.x * 32, k0 = blockIdx.y * 32;
  int tx = threadIdx.x & 31, ty = threadIdx.x >> 5;
  for (int r = ty; r < 32; r += 8) tile[r][tx] = W[(size_t)(k0 + r) * N + n0 + tx];
  __syncthreads();
  for (int r = ty; r < 32; r += 8) Wt[(size_t)(n0 + r) * K + k0 + tx] = __float2bfloat16(tile[tx][r]);
}

// ---------------- f32 -> split bf16 transpose ----------------
__global__ __launch_bounds__(256) void transpose_to_bf16x2(const float* __restrict__ W,
                                                           __hip_bfloat16* __restrict__ Wh,
                                                           __hip_bfloat16* __restrict__ Wl,
                                                           int K, int N) {
  __shared__ float tile[32][33];
  int n0 = blockIdx.x * 32, k0 = blockIdx.y * 32;
  int tx = threadIdx.x & 31, ty = threadIdx.x >> 5;
  for (int r = ty; r < 32; r += 8) tile[r][tx] = W[(size_t)(k0 + r) * N + n0 + tx];
  __syncthreads();
  for (int r = ty; r < 32; r += 8) {
    __hip_bfloat16 hi, lo;
    split_bf16(tile[tx][r], hi, lo);
    Wh[(size_t)(n0 + r) * K + k0 + tx] = hi;
    Wl[(size_t)(n0 + r) * K + k0 + tx] = lo;
  }
}

// ---------------- skinny split-bf16 MFMA GEMM: M=64, tile 64x128, split-K ----------------
__global__ __launch_bounds__(256) void mfma_skinny3(const __hip_bfloat16* __restrict__ Ah,
                                                    const __hip_bfloat16* __restrict__ Al,
                                                    const __hip_bfloat16* __restrict__ Bh,
                                                    const __hip_bfloat16* __restrict__ Bl,
                                                    float* __restrict__ part,
                                                    int N, int K, int Kc) {
  __shared__ short AhS[64][40];
  __shared__ short AlS[64][40];
  __shared__ short BhS[128][40];
  __shared__ short BlS[128][40];
  int t = threadIdx.x;
  int n0 = blockIdx.x * 128;
  int kbeg = blockIdx.y * Kc;
  int lane = t & 63, wid = t >> 6;
  int wn = wid * 32;
  int lrow = lane & 15, kb = (lane >> 4) * 8;
  vfloat4 acc[4][2];
#pragma unroll
  for (int i = 0; i < 4; ++i)
#pragma unroll
    for (int j = 0; j < 2; ++j) acc[i][j] = (vfloat4){0.f, 0.f, 0.f, 0.f};
  const short* Ahg = (const short*)Ah;
  const short* Alg = (const short*)Al;
  const short* Bhg = (const short*)Bh;
  const short* Blg = (const short*)Bl;
  int srow = t >> 2, skc = (t & 3) * 8;
  for (int k0 = kbeg; k0 < kbeg + Kc; k0 += 32) {
    size_t ga = (size_t)srow * K + k0 + skc;
    *(vshort8*)&AhS[srow][skc] = *(const vshort8*)&Ahg[ga];
    *(vshort8*)&AlS[srow][skc] = *(const vshort8*)&Alg[ga];
#pragma unroll
    for (int rr = 0; rr < 128; rr += 64) {
      size_t gb = (size_t)(n0 + srow + rr) * K + k0 + skc;
      *(vshort8*)&BhS[srow + rr][skc] = *(const vshort8*)&Bhg[gb];
      *(vshort8*)&BlS[srow + rr][skc] = *(const vshort8*)&Blg[gb];
    }
    __syncthreads();
    vbf16x8 afh[4], afl[4], bqh[2], bql[2];
#pragma unroll
    for (int i = 0; i < 4; ++i) {
      afh[i] = *(const vbf16x8*)&AhS[i * 16 + lrow][kb];
      afl[i] = *(const vbf16x8*)&AlS[i * 16 + lrow][kb];
    }
#pragma unroll
    for (int j = 0; j < 2; ++j) {
      bqh[j] = *(const vbf16x8*)&BhS[wn + j * 16 + lrow][kb];
      bql[j] = *(const vbf16x8*)&BlS[wn + j * 16 + lrow][kb];
    }
#pragma unroll
    for (int i = 0; i < 4; ++i)
#pragma unroll
      for (int j = 0; j < 2; ++j) {
        acc[i][j] = __builtin_amdgcn_mfma_f32_16x16x32_bf16(afl[i], bqh[j], acc[i][j], 0, 0, 0);
        acc[i][j] = __builtin_amdgcn_mfma_f32_16x16x32_bf16(afh[i], bql[j], acc[i][j], 0, 0, 0);
        acc[i][j] = __builtin_amdgcn_mfma_f32_16x16x32_bf16(afh[i], bqh[j], acc[i][j], 0, 0, 0);
      }
    __syncthreads();
  }
  size_t zbase = (size_t)blockIdx.y * 64;
  int crow0 = (lane >> 4) * 4;
  int ccol0 = n0 + wn + lrow;
#pragma unroll
  for (int i = 0; i < 4; ++i) {
#pragma unroll
    for (int j = 0; j < 2; ++j) {
      int col = ccol0 + j * 16;
#pragma unroll
      for (int r = 0; r < 4; ++r) {
        int rowi = i * 16 + crow0 + r;
        part[(zbase + rowi) * N + col] = acc[i][j][r];
      }
    }
  }
}

// ---------------- C[64][N] = sum_z part[z][64][N] + bias ----------------
__global__ __launch_bounds__(256) void reduce_bias(const float* __restrict__ part,
                                                   const float* __restrict__ bias,
                                                   float* __restrict__ C, int N, int SK) {
  int i = blockIdx.x * 256 + threadIdx.x;  // < 64*N
  int col = i & (N - 1);                   // N is a power of two
  float s = bias[col];
  for (int z = 0; z < SK; ++z) s += part[(size_t)z * 64 * N + i];
  C[i] = s;
}

// ---------------- bf16 MFMA GEMM (plain): C = A @ Bt^T + bias ----------------
__global__ __launch_bounds__(256) void mfma_gemm(const __hip_bfloat16* __restrict__ A,
                                                 const __hip_bfloat16* __restrict__ Bt,
                                                 const float* __restrict__ bias,
                                                 float* __restrict__ C,
                                                 int M, int N, int K, int relu) {
  __shared__ short Als[128][40];
  __shared__ short Bls[128][40];
  int t = threadIdx.x;
  int m0 = blockIdx.y * 128, n0 = blockIdx.x * 128;
  int lane = t & 63, wid = t >> 6;
  int wm = (wid >> 1) * 64, wn = (wid & 1) * 64;
  int lrow = lane & 15, kb = (lane >> 4) * 8;
  vfloat4 acc[4][4];
#pragma unroll
  for (int i = 0; i < 4; ++i)
#pragma unroll
    for (int j = 0; j < 4; ++j) acc[i][j] = (vfloat4){0.f, 0.f, 0.f, 0.f};
  const short* Ag = (const short*)A;
  const short* Bg = (const short*)Bt;
  int srow = t >> 2, skc = (t & 3) * 8;
  for (int k0 = 0; k0 < K; k0 += 32) {
#pragma unroll
    for (int rr = 0; rr < 128; rr += 64) {
      *(vshort8*)&Als[srow + rr][skc] = *(const vshort8*)&Ag[(size_t)(m0 + srow + rr) * K + k0 + skc];
      *(vshort8*)&Bls[srow + rr][skc] = *(const vshort8*)&Bg[(size_t)(n0 + srow + rr) * K + k0 + skc];
    }
    __syncthreads();
    vbf16x8 af[4], bq[4];
#pragma unroll
    for (int i = 0; i < 4; ++i) af[i] = *(const vbf16x8*)&Als[wm + i * 16 + lrow][kb];
#pragma unroll
    for (int j = 0; j < 4; ++j) bq[j] = *(const vbf16x8*)&Bls[wn + j * 16 + lrow][kb];
#pragma unroll
    for (int i = 0; i < 4; ++i)
#pragma unroll
      for (int j = 0; j < 4; ++j)
        acc[i][j] = __builtin_amdgcn_mfma_f32_16x16x32_bf16(af[i], bq[j], acc[i][j], 0, 0, 0);
    __syncthreads();
  }
  int crow0 = m0 + wm + (lane >> 4) * 4;
  int ccol0 = n0 + wn + lrow;
#pragma unroll
  for (int i = 0; i < 4; ++i) {
#pragma unroll
    for (int j = 0; j < 4; ++j) {
      int col = ccol0 + j * 16;
      float bv = bias[col];
#pragma unroll
      for (int r = 0; r < 4; ++r) {
        int rowi = crow0 + i * 16 + r;
        float v = acc[i][j][r] + bv;
        if (relu) v = fmaxf(v, 0.f);
        C[(size_t)rowi * N + col] = v;
      }
    }
  }
}

// ---------------- hyp = traj + 0.1 * normal(key(42)) ----------------
__global__ __launch_bounds__(256) void hyp_noise(const float* __restrict__ traj,
                                                 float* __restrict__ x) {
  uint32_t j = blockIdx.x * 256 + threadIdx.x;  // < 1048576
#pragma unroll
  for (int h = 0; h < 2; ++h) {
    uint32_t i = j + h * 1048576u;
    float n = bits_to_normal(tf_bits_part(0u, 42u, i));
    uint32_t b0 = i >> 15, fe0 = i & 8191u;
    x[i] = traj[((size_t)b0 << 13) + fe0] + 0.1f * n;
  }
}

// ---------------- x -= 0.1*u (+ 0.01*normal(fold_in(key(7),it)) if it<9) ----------------
__global__ __launch_bounds__(256) void update_x(float* __restrict__ x, const float* __restrict__ u,
                                                int it) {
  uint32_t j = blockIdx.x * 256 + threadIdx.x;  // < 1048576
  uint32_t k0 = 0, k1 = 0;
  if (it < NIT_ - 1) threefry2x32(0u, 7u, 0u, (uint32_t)it, k0, k1);  // fold_in(key(7), it)
#pragma unroll
  for (int h = 0; h < 2; ++h) {
    uint32_t i = j + h * 1048576u;
    float xv = x[i] - 0.1f * u[i];
    if (it < NIT_ - 1) xv += 0.01f * bits_to_normal(tf_bits_part(k0, k1, i));
    x[i] = xv;
  }
}

// ---------------- build refine input (bf16): [x | ce | neighbor] ----------------
__global__ __launch_bounds__(256) void build_inp(const float* __restrict__ x,
                                                 const float* __restrict__ ctx_h,
                                                 __hip_bfloat16* __restrict__ inp) {
  int row = blockIdx.y;                      // 2048 = bh*8 + f
  int col = blockIdx.x * 256 + threadIdx.x;  // < 3072
  int bh = row >> 3, f = row & 7;
  float v;
  if (col < E_) {
    v = x[(size_t)row * E_ + col];
  } else if (col < 2 * E_) {
    v = ctx_h[(size_t)(bh >> 2) * H_ + (col - E_)];
  } else {
    int c = col - 2 * E_;
    int fp = (f == 0) ? 0 : f - 1;
    int fn = (f == NF_ - 1) ? NF_ - 1 : f + 1;
    v = 0.5f * (x[(size_t)(bh * NF_ + fp) * E_ + c] + x[(size_t)(bh * NF_ + fn) * E_ + c]);
  }
  inp[(size_t)row * 3072 + col] = __float2bfloat16(v);
}

// ---------------- energy: concat input (bf16) ----------------
__global__ __launch_bounds__(256) void build_xcat(const float* __restrict__ x,
                                                  const float* __restrict__ ctx_h,
                                                  __hip_bfloat16* __restrict__ xc) {
  int row = blockIdx.y;
  int col = blockIdx.x * 256 + threadIdx.x;  // < 2048
  int bh = row >> 3;
  float v = (col < E_) ? x[(size_t)row * E_ + col]
                       : ctx_h[(size_t)(bh >> 2) * H_ + (col - E_)];
  xc[(size_t)row * 2048 + col] = __float2bfloat16(v);
}

// ---------------- per-row dot with en_w3 ----------------
__global__ __launch_bounds__(256) void rowdot(const float* __restrict__ X2,
                                              const float* __restrict__ w3,
                                              const float* __restrict__ b3,
                                              float* __restrict__ srow) {
  __shared__ float red[256];
  int row = blockIdx.x, t = threadIdx.x;
  const float* xr = X2 + (size_t)row * E_;
  float s = 0.f;
  for (int c = t; c < E_; c += 256) s += xr[c] * w3[c];
  red[t] = s; __syncthreads();
  for (int k = 128; k > 0; k >>= 1) { if (t < k) red[t] += red[t + k]; __syncthreads(); }
  if (t == 0) srow[row] = red[0] + b3[0];
}

// ---------------- energies[bh] = coherence + 0.1*smoothness + supervision ----------------
__global__ __launch_bounds__(256) void energy_final(const float* __restrict__ x,
                                                    const float* __restrict__ ft,
                                                    const float* __restrict__ srow,
                                                    float* __restrict__ energ) {
  __shared__ float red[256];
  int bh = blockIdx.x, t = threadIdx.x;
  int b = bh >> 2;
  const float* xb = x + (size_t)bh * (NF_ * E_);
  const float* fb = ft + (size_t)b * (NF_ * E_);
  float sup = 0.f;
  for (int i = t; i < NF_ * E_; i += 256) { float d = xb[i] - fb[i]; sup += d * d; }
  red[t] = sup; __syncthreads();
  for (int k = 128; k > 0; k >>= 1) { if (t < k) red[t] += red[t + k]; __syncthreads(); }
  float supervision = red[0] / (NF_ * E_);
  float smooth = 0.f;
  for (int d = 0; d < NF_ - 1; ++d) {
    __syncthreads();
    float sd = 0.f;
    for (int e = t; e < E_; e += 256) {
      float df = xb[(d + 1) * E_ + e] - xb[d * E_ + e];
      sd += df * df;
    }
    red[t] = sd; __syncthreads();
    for (int k = 128; k > 0; k >>= 1) { if (t < k) red[t] += red[t + k]; __syncthreads(); }
    smooth += sqrtf(red[0]);
  }
  smooth *= (1.0f / (NF_ - 1));
  if (t == 0) {
    float coh = 0.f;
    for (int f = 0; f < NF_; ++f) coh += srow[bh * NF_ + f];
    coh *= (1.0f / NF_);
    energ[bh] = coh + 0.1f * smooth + supervision;
  }
}

__global__ void softmax_probs(const float* __restrict__ energ, float* __restrict__ probs) {
  int b = threadIdx.x;
  if (b < B_) {
    float e[NH_], m = -1e30f;
#pragma unroll
    for (int h = 0; h < NH_; ++h) { e[h] = -energ[b * NH_ + h]; m = fmaxf(m, e[h]); }
    float s = 0.f, p[NH_];
#pragma unroll
    for (int h = 0; h < NH_; ++h) { p[h] = expf(e[h] - m); s += p[h]; }
#pragma unroll
    for (int h = 0; h < NH_; ++h) probs[b * NH_ + h] = p[h] / s;
  }
}

__global__ __launch_bounds__(256) void predict(const float* __restrict__ x,
                                               const float* __restrict__ probs,
                                               float* __restrict__ out) {
  int i = blockIdx.x * 256 + threadIdx.x;  // < 524288
  int b = i >> 13, fe = i & 8191;
  float s = 0.f;
#pragma unroll
  for (int h = 0; h < NH_; ++h) s += x[(size_t)(b * NH_ + h) * 8192 + fe] * probs[b * NH_ + h];
  out[i] = s;
}

extern "C" void kernel_launch(void* const* d_in, const int* in_sizes, int n_in,
                              void* d_out, int out_size, void* d_ws, size_t ws_size,
                              hipStream_t stream) {
  const float* cur   = (const float*)d_in[0];
  const float* ftrue = (const float*)d_in[1];
  const float* ce_w1 = (const float*)d_in[2];
  const float* ce_b1 = (const float*)d_in[3];
  const float* ce_g  = (const float*)d_in[4];
  const float* ce_be = (const float*)d_in[5];
  const float* ce_w2 = (const float*)d_in[6];
  const float* ce_b2 = (const float*)d_in[7];
  const float* tp_w1 = (const float*)d_in[8];
  const float* tp_b1 = (const float*)d_in[9];
  const float* tp_g  = (const float*)d_in[10];
  const float* tp_be = (const float*)d_in[11];
  const float* tp_w2 = (const float*)d_in[12];
  const float* tp_b2 = (const float*)d_in[13];
  const float* en_w1 = (const float*)d_in[14];
  const float* en_b1 = (const float*)d_in[15];
  const float* en_g  = (const float*)d_in[16];
  const float* en_be = (const float*)d_in[17];
  const float* en_w2 = (const float*)d_in[18];
  const float* en_b2 = (const float*)d_in[19];
  const float* en_w3 = (const float*)d_in[20];
  const float* en_b3 = (const float*)d_in[21];
  const float* rn_w1 = (const float*)d_in[22];
  const float* rn_b1 = (const float*)d_in[23];
  const float* rn_g  = (const float*)d_in[24];
  const float* rn_be = (const float*)d_in[25];
  const float* rn_w2 = (const float*)d_in[26];
  const float* rn_b2 = (const float*)d_in[27];
  (void)in_sizes; (void)n_in; (void)out_size; (void)ws_size;

  char* w = (char*)d_ws;
  size_t off = 0;
  auto alloc = [&](size_t bytes) -> void* {
    void* p = w + off;
    off += (bytes + 255) & ~(size_t)255;
    return p;
  };
  float* part   = (float*)alloc((size_t)8 * B_ * E_ * 4);
  float* ctx    = (float*)alloc((size_t)B_ * E_ * 4);
  float* g1     = (float*)alloc((size_t)B_ * H_ * 4);
  float* ctx_h  = (float*)alloc((size_t)B_ * H_ * 4);
  float* traj   = (float*)alloc((size_t)B_ * NF_ * E_ * 4);
  float* x      = (float*)alloc((size_t)2097152 * 4);
  float* h1     = (float*)alloc((size_t)2048 * 2048 * 4);   // also aliased as split-K partial
  float* u      = (float*)alloc((size_t)2048 * 1024 * 4);
  __hip_bfloat16* inp_b  = (__hip_bfloat16*)alloc((size_t)2048 * 3072 * 2);
  __hip_bfloat16* ub     = (__hip_bfloat16*)alloc((size_t)2048 * 2048 * 2);
  float* srow   = (float*)alloc((size_t)2048 * 4);
  float* energ  = (float*)alloc((size_t)256 * 4);
  float* probs  = (float*)alloc((size_t)256 * 4);
  __hip_bfloat16* rn_w1t = (__hip_bfloat16*)alloc((size_t)2048 * 3072 * 2);
  __hip_bfloat16* rn_w2t = (__hip_bfloat16*)alloc((size_t)1024 * 2048 * 2);
  __hip_bfloat16* en_w1t = (__hip_bfloat16*)alloc((size_t)2048 * 2048 * 2);
  __hip_bfloat16* en_w2t = (__hip_bfloat16*)alloc((size_t)1024 * 2048 * 2);
  // ctx-path skinny-GEMM buffers (split-bf16 kept: exactness of ctx_h/traj base)
  __hip_bfloat16* aA_h = (__hip_bfloat16*)alloc((size_t)B_ * H_ * 2);
  __hip_bfloat16* aA_l = (__hip_bfloat16*)alloc((size_t)B_ * H_ * 2);
  __hip_bfloat16* cw1t_h = (__hip_bfloat16*)alloc((size_t)2048 * 1024 * 2);
  __hip_bfloat16* cw1t_l = (__hip_bfloat16*)alloc((size_t)2048 * 1024 * 2);
  __hip_bfloat16* cw2t_h = (__hip_bfloat16*)alloc((size_t)2048 * 2048 * 2);
  __hip_bfloat16* cw2t_l = (__hip_bfloat16*)alloc((size_t)2048 * 2048 * 2);
  __hip_bfloat16* tw1t_h = (__hip_bfloat16*)alloc((size_t)2048 * 2048 * 2);
  __hip_bfloat16* tw1t_l = (__hip_bfloat16*)alloc((size_t)2048 * 2048 * 2);
  __hip_bfloat16* tw2t_h = (__hip_bfloat16*)alloc((size_t)8192 * 2048 * 2);
  __hip_bfloat16* tw2t_l = (__hip_bfloat16*)alloc((size_t)8192 * 2048 * 2);
  float* skpart = h1;  // split-K partials (max 8*64*8192*4 = 16.78MB == h1 size)

  // ctx = mean_S
  colmean_partial<<<512, 256, 0, stream>>>(cur, part);
  colmean_final<<<256, 256, 0, stream>>>(part, ctx);

  // weight prep (refine/energy: plain bf16)
  transpose_to_bf16<<<dim3(2048 / 32, 3072 / 32), 256, 0, stream>>>(rn_w1, rn_w1t, 3072, 2048);
  transpose_to_bf16<<<dim3(1024 / 32, 2048 / 32), 256, 0, stream>>>(rn_w2, rn_w2t, 2048, 1024);
  transpose_to_bf16<<<dim3(2048 / 32, 2048 / 32), 256, 0, stream>>>(en_w1, en_w1t, 2048, 2048);
  transpose_to_bf16<<<dim3(1024 / 32, 2048 / 32), 256, 0, stream>>>(en_w2, en_w2t, 2048, 1024);
  // weight prep (ctx path: split)
  transpose_to_bf16x2<<<dim3(2048 / 32, 1024 / 32), 256, 0, stream>>>(ce_w1, cw1t_h, cw1t_l, 1024, 2048);
  transpose_to_bf16x2<<<dim3(2048 / 32, 2048 / 32), 256, 0, stream>>>(ce_w2, cw2t_h, cw2t_l, 2048, 2048);
  transpose_to_bf16x2<<<dim3(2048 / 32, 2048 / 32), 256, 0, stream>>>(tp_w1, tw1t_h, tw1t_l, 2048, 2048);
  transpose_to_bf16x2<<<dim3(8192 / 32, 2048 / 32), 256, 0, stream>>>(tp_w2, tw2t_h, tw2t_l, 2048, 8192);

  // ---- context/trajectory path via skinny MFMA GEMMs (M=64, split-bf16) ----
  split_f32<<<(B_ * E_) / 256, 256, 0, stream>>>(ctx, aA_h, aA_l);
  mfma_skinny3<<<dim3(2048 / 128, 4), 256, 0, stream>>>(aA_h, aA_l, cw1t_h, cw1t_l, skpart, 2048, 1024, 256);
  reduce_bias<<<(B_ * 2048) / 256, 256, 0, stream>>>(skpart, ce_b1, g1, 2048, 4);
  ln_kernel2<<<B_, 256, 0, stream>>>(g1, ce_g, ce_be, aA_h, aA_l, H_);
  mfma_skinny3<<<dim3(2048 / 128, 8), 256, 0, stream>>>(aA_h, aA_l, cw2t_h, cw2t_l, skpart, 2048, 2048, 256);
  reduce_bias<<<(B_ * 2048) / 256, 256, 0, stream>>>(skpart, ce_b2, ctx_h, 2048, 8);
  split_f32<<<(B_ * H_) / 256, 256, 0, stream>>>(ctx_h, aA_h, aA_l);
  mfma_skinny3<<<dim3(2048 / 128, 8), 256, 0, stream>>>(aA_h, aA_l, tw1t_h, tw1t_l, skpart, 2048, 2048, 256);
  reduce_bias<<<(B_ * 2048) / 256, 256, 0, stream>>>(skpart, tp_b1, g1, 2048, 8);
  ln_kernel2<<<B_, 256, 0, stream>>>(g1, tp_g, tp_be, aA_h, aA_l, H_);
  mfma_skinny3<<<dim3(8192 / 128, 8), 256, 0, stream>>>(aA_h, aA_l, tw2t_h, tw2t_l, skpart, 8192, 2048, 256);
  reduce_bias<<<(B_ * 8192) / 256, 256, 0, stream>>>(skpart, tp_b2, traj, 8192, 8);

  // hypotheses = traj + noise
  hyp_noise<<<4096, 256, 0, stream>>>(traj, x);

  // refinement loop (plain bf16 GEMMs — error budget analysis in journal)
  for (int it = 0; it < NIT_; ++it) {
    build_inp<<<dim3(12, 2048), 256, 0, stream>>>(x, ctx_h, inp_b);
    mfma_gemm<<<dim3(16, 16), 256, 0, stream>>>(inp_b, rn_w1t, rn_b1, h1, 2048, 2048, 3072, 0);
    ln_kernel<true, true><<<2048, 256, 0, stream>>>(h1, rn_g, rn_be, ub, 2048);
    mfma_gemm<<<dim3(8, 16), 256, 0, stream>>>(ub, rn_w2t, rn_b2, u, 2048, 1024, 2048, 0);
    update_x<<<4096, 256, 0, stream>>>(x, u, it);
  }

  // energy + softmax + weighted prediction
  build_xcat<<<dim3(8, 2048), 256, 0, stream>>>(x, ctx_h, inp_b);
  mfma_gemm<<<dim3(16, 16), 256, 0, stream>>>(inp_b, en_w1t, en_b1, h1, 2048, 2048, 2048, 0);
  ln_kernel<true, true><<<2048, 256, 0, stream>>>(h1, en_g, en_be, ub, 2048);
  mfma_gemm<<<dim3(8, 16), 256, 0, stream>>>(ub, en_w2t, en_b2, u, 2048, 1024, 2048, 1);
  rowdot<<<2048, 256, 0, stream>>>(u, en_w3, en_b3, srow);
  energy_final<<<256, 256, 0, stream>>>(x, ftrue, srow, energ);
  softmax_probs<<<1, 64, 0, stream>>>(energ, probs);
  predict<<<2048, 256, 0, stream>>>(x, probs, (float*)d_out);
}

// Round 7
// 1735.327 us; speedup vs baseline: 3.2647x; 1.0984x over previous
//
#include <hip/hip_runtime.h>
#include <hip/hip_bf16.h>
#include <stdint.h>

#define B_ 64
#define S_ 1024
#define E_ 1024
#define H_ 2048
#define NF_ 8
#define NH_ 4
#define NIT_ 10

typedef __attribute__((ext_vector_type(8))) short vshort8;
typedef __attribute__((ext_vector_type(8))) __bf16 vbf16x8;
typedef __attribute__((ext_vector_type(4))) float vfloat4;

// ---------------- async global->LDS, 16B per lane ----------------
typedef const __attribute__((address_space(1))) void* gas1_t;
typedef __attribute__((address_space(3))) void* las3_t;
__device__ __forceinline__ void gload16(const void* g, void* l) {
  __builtin_amdgcn_global_load_lds((gas1_t)g, (las3_t)l, 16, 0, 0);
}

// ---------------- threefry2x32 (JAX-exact) ----------------
__device__ __forceinline__ uint32_t rotl32(uint32_t v, int n) { return (v << n) | (v >> (32 - n)); }

__device__ __forceinline__ void threefry2x32(uint32_t k0, uint32_t k1, uint32_t x0, uint32_t x1,
                                             uint32_t& o0, uint32_t& o1) {
  uint32_t ks2 = k0 ^ k1 ^ 0x1BD11BDAu;
  x0 += k0; x1 += k1;
#define TF_R(r) { x0 += x1; x1 = rotl32(x1, (r)); x1 ^= x0; }
  TF_R(13) TF_R(15) TF_R(26) TF_R(6)
  x0 += k1;  x1 += ks2 + 1u;
  TF_R(17) TF_R(29) TF_R(16) TF_R(24)
  x0 += ks2; x1 += k0 + 2u;
  TF_R(13) TF_R(15) TF_R(26) TF_R(6)
  x0 += k0;  x1 += k1 + 3u;
  TF_R(17) TF_R(29) TF_R(16) TF_R(24)
  x0 += k1;  x1 += ks2 + 4u;
  TF_R(13) TF_R(15) TF_R(26) TF_R(6)
  x0 += ks2; x1 += k0 + 5u;
#undef TF_R
  o0 = x0; o1 = x1;
}

// partitionable threefry 32-bit bits: element i -> bits1 ^ bits2 of threefry(key, (0, i))
__device__ __forceinline__ uint32_t tf_bits_part(uint32_t k0, uint32_t k1, uint32_t i) {
  uint32_t o0, o1;
  threefry2x32(k0, k1, 0u, i, o0, o1);
  return o0 ^ o1;
}

// XLA/Giles erfinv (f32)
__device__ __forceinline__ float erfinv_f(float x) {
  float w = -log1pf(-x * x);
  float p;
  if (w < 5.0f) {
    w -= 2.5f;
    p = 2.81022636e-08f;
    p = 3.43273939e-07f + p * w;
    p = -3.5233877e-06f + p * w;
    p = -4.39150654e-06f + p * w;
    p = 0.00021858087f + p * w;
    p = -0.00125372503f + p * w;
    p = -0.00417768164f + p * w;
    p = 0.246640727f + p * w;
    p = 1.50140941f + p * w;
  } else {
    w = sqrtf(w) - 3.0f;
    p = -0.000200214257f;
    p = 0.000100950558f + p * w;
    p = 0.00134934322f + p * w;
    p = -0.00367342844f + p * w;
    p = 0.00573950773f + p * w;
    p = -0.0076224613f + p * w;
    p = 0.00943887047f + p * w;
    p = 1.00167406f + p * w;
    p = 2.83297682f + p * w;
  }
  return p * x;
}

__device__ __forceinline__ float bits_to_normal(uint32_t bits) {
  uint32_t fb = (bits >> 9) | 0x3F800000u;
  float f = __uint_as_float(fb) - 1.0f;       // [0,1)
  const float lo = -0.99999994f;              // nextafter(-1,0)
  float u = fmaxf(lo, f * 2.0f + lo);
  return 1.41421356f * erfinv_f(u);
}

// split helper: v = hi + lo (both bf16)
__device__ __forceinline__ void split_bf16(float v, __hip_bfloat16& hi, __hip_bfloat16& lo) {
  hi = __float2bfloat16(v);
  lo = __float2bfloat16(v - __bfloat162float(hi));
}

// ---------------- ctx = mean over S ----------------
__global__ __launch_bounds__(256) void colmean_partial(const float* __restrict__ cur,
                                                       float* __restrict__ part) {
  int blk = blockIdx.x;            // 512 blocks: b*8 + chunk
  int b = blk >> 3, c = blk & 7;
  int t = threadIdx.x;
  const float* base = cur + ((size_t)b * S_ + (size_t)c * 128) * E_;
  float4 s = {0.f, 0.f, 0.f, 0.f};
  for (int si = 0; si < 128; ++si) {
    float4 v = *(const float4*)(base + (size_t)si * E_ + t * 4);
    s.x += v.x; s.y += v.y; s.z += v.z; s.w += v.w;
  }
  *(float4*)(part + ((size_t)c * B_ + b) * E_ + t * 4) = s;
}

__global__ __launch_bounds__(256) void colmean_final(const float* __restrict__ part,
                                                     float* __restrict__ ctx) {
  int i = blockIdx.x * 256 + threadIdx.x;  // < 65536
  float s = 0.f;
#pragma unroll
  for (int c = 0; c < 8; ++c) s += part[(size_t)c * (B_ * E_) + i];
  ctx[i] = s * (1.0f / S_);
}

// ---------------- f32 -> split bf16 elementwise ----------------
__global__ __launch_bounds__(256) void split_f32(const float* __restrict__ X,
                                                 __hip_bfloat16* __restrict__ hi,
                                                 __hip_bfloat16* __restrict__ lo) {
  int i = blockIdx.x * 256 + threadIdx.x;
  __hip_bfloat16 h, l;
  split_bf16(X[i], h, l);
  hi[i] = h;
  lo[i] = l;
}

// ---------------- LayerNorm (+relu), f32 in, f32 or bf16 out ----------------
template <bool OUT_BF16, bool RELU>
__global__ __launch_bounds__(256) void ln_kernel(const float* __restrict__ X,
                                                 const float* __restrict__ g,
                                                 const float* __restrict__ be,
                                                 void* __restrict__ out, int Wd) {
  __shared__ float red[256];
  int row = blockIdx.x, t = threadIdx.x;
  const float* xr = X + (size_t)row * Wd;
  float s = 0.f;
  for (int c = t; c < Wd; c += 256) s += xr[c];
  red[t] = s; __syncthreads();
  for (int k = 128; k > 0; k >>= 1) { if (t < k) red[t] += red[t + k]; __syncthreads(); }
  float mean = red[0] / Wd;
  __syncthreads();
  float s2 = 0.f;
  for (int c = t; c < Wd; c += 256) { float d = xr[c] - mean; s2 += d * d; }
  red[t] = s2; __syncthreads();
  for (int k = 128; k > 0; k >>= 1) { if (t < k) red[t] += red[t + k]; __syncthreads(); }
  float rstd = rsqrtf(red[0] / Wd + 1e-5f);
  for (int c = t; c < Wd; c += 256) {
    float v = (xr[c] - mean) * rstd * g[c] + be[c];
    if (RELU) v = fmaxf(v, 0.f);
    if (OUT_BF16) ((__hip_bfloat16*)out)[(size_t)row * Wd + c] = __float2bfloat16(v);
    else          ((float*)out)[(size_t)row * Wd + c] = v;
  }
}

// ---------------- LayerNorm + relu, split hi/lo bf16 outputs ----------------
__global__ __launch_bounds__(256) void ln_kernel2(const float* __restrict__ X,
                                                  const float* __restrict__ g,
                                                  const float* __restrict__ be,
                                                  __hip_bfloat16* __restrict__ oh,
                                                  __hip_bfloat16* __restrict__ ol, int Wd) {
  __shared__ float red[256];
  int row = blockIdx.x, t = threadIdx.x;
  const float* xr = X + (size_t)row * Wd;
  float s = 0.f;
  for (int c = t; c < Wd; c += 256) s += xr[c];
  red[t] = s; __syncthreads();
  for (int k = 128; k > 0; k >>= 1) { if (t < k) red[t] += red[t + k]; __syncthreads(); }
  float mean = red[0] / Wd;
  __syncthreads();
  float s2 = 0.f;
  for (int c = t; c < Wd; c += 256) { float d = xr[c] - mean; s2 += d * d; }
  red[t] = s2; __syncthreads();
  for (int k = 128; k > 0; k >>= 1) { if (t < k) red[t] += red[t + k]; __syncthreads(); }
  float rstd = rsqrtf(red[0] / Wd + 1e-5f);
  for (int c = t; c < Wd; c += 256) {
    float v = (xr[c] - mean) * rstd * g[c] + be[c];
    v = fmaxf(v, 0.f);
    __hip_bfloat16 hi, lo;
    split_bf16(v, hi, lo);
    oh[(size_t)row * Wd + c] = hi;
    ol[(size_t)row * Wd + c] = lo;
  }
}

// ---------------- f32 -> bf16 transpose: Wt[n][k] = W[k][n] ----------------
__global__ __launch_bounds__(256) void transpose_to_bf16(const float* __restrict__ W,
                                                         __hip_bfloat16* __restrict__ Wt,
                                                         int K, int N) {
  __shared__ float tile[32][33];
  int n0 = blockIdx.x * 32, k0 = blockIdx.y * 32;
  int tx = threadIdx.x & 31, ty = threadIdx.x >> 5;
  for (int r = ty; r < 32; r += 8) tile[r][tx] = W[(size_t)(k0 + r) * N + n0 + tx];
  __syncthreads();
  for (int r = ty; r < 32; r += 8) Wt[(size_t)(n0 + r) * K + k0 + tx] = __float2bfloat16(tile[tx][r]);
}

// ---------------- f32 -> split bf16 transpose ----------------
__global__ __launch_bounds__(256) void transpose_to_bf16x2(const float* __restrict__ W,
                                                           __hip_bfloat16* __restrict__ Wh,
                                                           __hip_bfloat16* __restrict__ Wl,
                                                           int K, int N) {
  __shared__ float tile[32][33];
  int n0 = blockIdx.x * 32, k0 = blockIdx.y * 32;
  int tx = threadIdx.x & 31, ty = threadIdx.x >> 5;
  for (int r = ty; r < 32; r += 8) tile[r][tx] = W[(size_t)(k0 + r) * N + n0 + tx];
  __syncthreads();
  for (int r = ty; r < 32; r += 8) {
    __hip_bfloat16 hi, lo;
    split_bf16(tile[tx][r], hi, lo);
    Wh[(size_t)(n0 + r) * K + k0 + tx] = hi;
    Wl[(size_t)(n0 + r) * K + k0 + tx] = lo;
  }
}

// ---------------- skinny split-bf16 MFMA GEMM: M=64, tile 64x128, split-K ----------------
__global__ __launch_bounds__(256) void mfma_skinny3(const __hip_bfloat16* __restrict__ Ah,
                                                    const __hip_bfloat16* __restrict__ Al,
                                                    const __hip_bfloat16* __restrict__ Bh,
                                                    const __hip_bfloat16* __restrict__ Bl,
                                                    float* __restrict__ part,
                                                    int N, int K, int Kc) {
  __shared__ short AhS[64][40];
  __shared__ short AlS[64][40];
  __shared__ short BhS[128][40];
  __shared__ short BlS[128][40];
  int t = threadIdx.x;
  int n0 = blockIdx.x * 128;
  int kbeg = blockIdx.y * Kc;
  int lane = t & 63, wid = t >> 6;
  int wn = wid * 32;
  int lrow = lane & 15, kb = (lane >> 4) * 8;
  vfloat4 acc[4][2];
#pragma unroll
  for (int i = 0; i < 4; ++i)
#pragma unroll
    for (int j = 0; j < 2; ++j) acc[i][j] = (vfloat4){0.f, 0.f, 0.f, 0.f};
  const short* Ahg = (const short*)Ah;
  const short* Alg = (const short*)Al;
  const short* Bhg = (const short*)Bh;
  const short* Blg = (const short*)Bl;
  int srow = t >> 2, skc = (t & 3) * 8;
  for (int k0 = kbeg; k0 < kbeg + Kc; k0 += 32) {
    size_t ga = (size_t)srow * K + k0 + skc;
    *(vshort8*)&AhS[srow][skc] = *(const vshort8*)&Ahg[ga];
    *(vshort8*)&AlS[srow][skc] = *(const vshort8*)&Alg[ga];
#pragma unroll
    for (int rr = 0; rr < 128; rr += 64) {
      size_t gb = (size_t)(n0 + srow + rr) * K + k0 + skc;
      *(vshort8*)&BhS[srow + rr][skc] = *(const vshort8*)&Bhg[gb];
      *(vshort8*)&BlS[srow + rr][skc] = *(const vshort8*)&Blg[gb];
    }
    __syncthreads();
    vbf16x8 afh[4], afl[4], bqh[2], bql[2];
#pragma unroll
    for (int i = 0; i < 4; ++i) {
      afh[i] = *(const vbf16x8*)&AhS[i * 16 + lrow][kb];
      afl[i] = *(const vbf16x8*)&AlS[i * 16 + lrow][kb];
    }
#pragma unroll
    for (int j = 0; j < 2; ++j) {
      bqh[j] = *(const vbf16x8*)&BhS[wn + j * 16 + lrow][kb];
      bql[j] = *(const vbf16x8*)&BlS[wn + j * 16 + lrow][kb];
    }
#pragma unroll
    for (int i = 0; i < 4; ++i)
#pragma unroll
      for (int j = 0; j < 2; ++j) {
        acc[i][j] = __builtin_amdgcn_mfma_f32_16x16x32_bf16(afl[i], bqh[j], acc[i][j], 0, 0, 0);
        acc[i][j] = __builtin_amdgcn_mfma_f32_16x16x32_bf16(afh[i], bql[j], acc[i][j], 0, 0, 0);
        acc[i][j] = __builtin_amdgcn_mfma_f32_16x16x32_bf16(afh[i], bqh[j], acc[i][j], 0, 0, 0);
      }
    __syncthreads();
  }
  size_t zbase = (size_t)blockIdx.y * 64;
  int crow0 = (lane >> 4) * 4;
  int ccol0 = n0 + wn + lrow;
#pragma unroll
  for (int i = 0; i < 4; ++i) {
#pragma unroll
    for (int j = 0; j < 2; ++j) {
      int col = ccol0 + j * 16;
#pragma unroll
      for (int r = 0; r < 4; ++r) {
        int rowi = i * 16 + crow0 + r;
        part[(zbase + rowi) * N + col] = acc[i][j][r];
      }
    }
  }
}

// ---------------- C[64][N] = sum_z part[z][64][N] + bias ----------------
__global__ __launch_bounds__(256) void reduce_bias(const float* __restrict__ part,
                                                   const float* __restrict__ bias,
                                                   float* __restrict__ C, int N, int SK) {
  int i = blockIdx.x * 256 + threadIdx.x;  // < 64*N
  int col = i & (N - 1);                   // N is a power of two
  float s = bias[col];
  for (int z = 0; z < SK; ++z) s += part[(size_t)z * 64 * N + i];
  C[i] = s;
}

// ---------------- bf16 MFMA GEMM via global_load_lds (m97 recipe) ----------------
// tile: 128(M) x 64(N), 4 waves (2x2), acc[4][2] per wave. MODE: 0=bias, 1=bias+relu,
// 2 = fused x-update epilogue: Cout[i] = Cout[i] - 0.1*(acc+bias) (+0.01*noise if it<NIT-1)
template <int MODE>
__global__ __launch_bounds__(256) void gemm_gl(const __hip_bfloat16* __restrict__ A,
                                               const __hip_bfloat16* __restrict__ Bt,
                                               const float* __restrict__ bias,
                                               float* __restrict__ Cout,
                                               int M, int N, int K, int it) {
  __shared__ short Als[128 * 32];  // 8 KB, linear (global_load_lds requires no padding)
  __shared__ short Bls[64 * 32];   // 4 KB
  int t = threadIdx.x;
  int lane = t & 63, wv = t >> 6;
  int n0 = blockIdx.x * 64, m0 = blockIdx.y * 128;
  int wm = (wv >> 1) * 64, wn = (wv & 1) * 32;
  int lrow = lane & 15, kb = (lane >> 4) * 8;
  vfloat4 acc[4][2];
#pragma unroll
  for (int i = 0; i < 4; ++i)
#pragma unroll
    for (int j = 0; j < 2; ++j) acc[i][j] = (vfloat4){0.f, 0.f, 0.f, 0.f};
  const short* Ag = (const short*)A;
  const short* Bg = (const short*)Bt;
  int arow = lane >> 2;        // 0..15 (4 lanes per 64B row)
  int acol = (lane & 3) * 8;   // shorts
  for (int k0 = 0; k0 < K; k0 += 32) {
    // A: 128 rows; wave wv stages rows [wv*32, wv*32+32) in two 16-row calls
    gload16(Ag + (size_t)(m0 + wv * 32 + arow) * K + k0 + acol, &Als[(wv * 32) * 32]);
    gload16(Ag + (size_t)(m0 + wv * 32 + 16 + arow) * K + k0 + acol, &Als[(wv * 32 + 16) * 32]);
    // B: 64 rows; wave wv stages rows [wv*16, wv*16+16)
    gload16(Bg + (size_t)(n0 + wv * 16 + arow) * K + k0 + acol, &Bls[(wv * 16) * 32]);
    __syncthreads();
    vbf16x8 af[4], bq[2];
#pragma unroll
    for (int i = 0; i < 4; ++i) af[i] = *(const vbf16x8*)&Als[(wm + i * 16 + lrow) * 32 + kb];
#pragma unroll
    for (int j = 0; j < 2; ++j) bq[j] = *(const vbf16x8*)&Bls[(wn + j * 16 + lrow) * 32 + kb];
#pragma unroll
    for (int i = 0; i < 4; ++i)
#pragma unroll
      for (int j = 0; j < 2; ++j)
        acc[i][j] = __builtin_amdgcn_mfma_f32_16x16x32_bf16(af[i], bq[j], acc[i][j], 0, 0, 0);
    __syncthreads();
  }
  int crow0 = m0 + wm + (lane >> 4) * 4;
  int ccol0 = n0 + wn + lrow;
  if (MODE == 2) {
    uint32_t key0 = 0, key1 = 0;
    bool addn = (it < NIT_ - 1);
    if (addn) threefry2x32(0u, 7u, 0u, (uint32_t)it, key0, key1);  // fold_in(key(7), it)
#pragma unroll
    for (int i = 0; i < 4; ++i) {
#pragma unroll
      for (int j = 0; j < 2; ++j) {
        int col = ccol0 + j * 16;
        float bv = bias[col];
#pragma unroll
        for (int r = 0; r < 4; ++r) {
          uint32_t idx = (uint32_t)(crow0 + i * 16 + r) * N + col;
          float xv = Cout[idx] - 0.1f * (acc[i][j][r] + bv);
          if (addn) xv += 0.01f * bits_to_normal(tf_bits_part(key0, key1, idx));
          Cout[idx] = xv;
        }
      }
    }
  } else {
#pragma unroll
    for (int i = 0; i < 4; ++i) {
#pragma unroll
      for (int j = 0; j < 2; ++j) {
        int col = ccol0 + j * 16;
        float bv = bias[col];
#pragma unroll
        for (int r = 0; r < 4; ++r) {
          float v = acc[i][j][r] + bv;
          if (MODE == 1) v = fmaxf(v, 0.f);
          Cout[(size_t)(crow0 + i * 16 + r) * N + col] = v;
        }
      }
    }
  }
}

// ---------------- hyp = traj + 0.1 * normal(key(42)) ----------------
__global__ __launch_bounds__(256) void hyp_noise(const float* __restrict__ traj,
                                                 float* __restrict__ x) {
  uint32_t j = blockIdx.x * 256 + threadIdx.x;  // < 1048576
#pragma unroll
  for (int h = 0; h < 2; ++h) {
    uint32_t i = j + h * 1048576u;
    float n = bits_to_normal(tf_bits_part(0u, 42u, i));
    uint32_t b0 = i >> 15, fe0 = i & 8191u;
    x[i] = traj[((size_t)b0 << 13) + fe0] + 0.1f * n;
  }
}

// ---------------- build refine input (bf16): [x | ce | neighbor] ----------------
__global__ __launch_bounds__(256) void build_inp(const float* __restrict__ x,
                                                 const float* __restrict__ ctx_h,
                                                 __hip_bfloat16* __restrict__ inp) {
  int row = blockIdx.y;                      // 2048 = bh*8 + f
  int col = blockIdx.x * 256 + threadIdx.x;  // < 3072
  int bh = row >> 3, f = row & 7;
  float v;
  if (col < E_) {
    v = x[(size_t)row * E_ + col];
  } else if (col < 2 * E_) {
    v = ctx_h[(size_t)(bh >> 2) * H_ + (col - E_)];
  } else {
    int c = col - 2 * E_;
    int fp = (f == 0) ? 0 : f - 1;
    int fn = (f == NF_ - 1) ? NF_ - 1 : f + 1;
    v = 0.5f * (x[(size_t)(bh * NF_ + fp) * E_ + c] + x[(size_t)(bh * NF_ + fn) * E_ + c]);
  }
  inp[(size_t)row * 3072 + col] = __float2bfloat16(v);
}

// ---------------- energy: concat input (bf16) ----------------
__global__ __launch_bounds__(256) void build_xcat(const float* __restrict__ x,
                                                  const float* __restrict__ ctx_h,
                                                  __hip_bfloat16* __restrict__ xc) {
  int row = blockIdx.y;
  int col = blockIdx.x * 256 + threadIdx.x;  // < 2048
  int bh = row >> 3;
  float v = (col < E_) ? x[(size_t)row * E_ + col]
                       : ctx_h[(size_t)(bh >> 2) * H_ + (col - E_)];
  xc[(size_t)row * 2048 + col] = __float2bfloat16(v);
}

// ---------------- per-row dot with en_w3 ----------------
__global__ __launch_bounds__(256) void rowdot(const float* __restrict__ X2,
                                              const float* __restrict__ w3,
                                              const float* __restrict__ b3,
                                              float* __restrict__ srow) {
  __shared__ float red[256];
  int row = blockIdx.x, t = threadIdx.x;
  const float* xr = X2 + (size_t)row * E_;
  float s = 0.f;
  for (int c = t; c < E_; c += 256) s += xr[c] * w3[c];
  red[t] = s; __syncthreads();
  for (int k = 128; k > 0; k >>= 1) { if (t < k) red[t] += red[t + k]; __syncthreads(); }
  if (t == 0) srow[row] = red[0] + b3[0];
}

// ---------------- energies[bh] = coherence + 0.1*smoothness + supervision ----------------
__global__ __launch_bounds__(256) void energy_final(const float* __restrict__ x,
                                                    const float* __restrict__ ft,
                                                    const float* __restrict__ srow,
                                                    float* __restrict__ energ) {
  __shared__ float red[256];
  int bh = blockIdx.x, t = threadIdx.x;
  int b = bh >> 2;
  const float* xb = x + (size_t)bh * (NF_ * E_);
  const float* fb = ft + (size_t)b * (NF_ * E_);
  float sup = 0.f;
  for (int i = t; i < NF_ * E_; i += 256) { float d = xb[i] - fb[i]; sup += d * d; }
  red[t] = sup; __syncthreads();
  for (int k = 128; k > 0; k >>= 1) { if (t < k) red[t] += red[t + k]; __syncthreads(); }
  float supervision = red[0] / (NF_ * E_);
  float smooth = 0.f;
  for (int d = 0; d < NF_ - 1; ++d) {
    __syncthreads();
    float sd = 0.f;
    for (int e = t; e < E_; e += 256) {
      float df = xb[(d + 1) * E_ + e] - xb[d * E_ + e];
      sd += df * df;
    }
    red[t] = sd; __syncthreads();
    for (int k = 128; k > 0; k >>= 1) { if (t < k) red[t] += red[t + k]; __syncthreads(); }
    smooth += sqrtf(red[0]);
  }
  smooth *= (1.0f / (NF_ - 1));
  if (t == 0) {
    float coh = 0.f;
    for (int f = 0; f < NF_; ++f) coh += srow[bh * NF_ + f];
    coh *= (1.0f / NF_);
    energ[bh] = coh + 0.1f * smooth + supervision;
  }
}

__global__ void softmax_probs(const float* __restrict__ energ, float* __restrict__ probs) {
  int b = threadIdx.x;
  if (b < B_) {
    float e[NH_], m = -1e30f;
#pragma unroll
    for (int h = 0; h < NH_; ++h) { e[h] = -energ[b * NH_ + h]; m = fmaxf(m, e[h]); }
    float s = 0.f, p[NH_];
#pragma unroll
    for (int h = 0; h < NH_; ++h) { p[h] = expf(e[h] - m); s += p[h]; }
#pragma unroll
    for (int h = 0; h < NH_; ++h) probs[b * NH_ + h] = p[h] / s;
  }
}

__global__ __launch_bounds__(256) void predict(const float* __restrict__ x,
                                               const float* __restrict__ probs,
                                               float* __restrict__ out) {
  int i = blockIdx.x * 256 + threadIdx.x;  // < 524288
  int b = i >> 13, fe = i & 8191;
  float s = 0.f;
#pragma unroll
  for (int h = 0; h < NH_; ++h) s += x[(size_t)(b * NH_ + h) * 8192 + fe] * probs[b * NH_ + h];
  out[i] = s;
}

extern "C" void kernel_launch(void* const* d_in, const int* in_sizes, int n_in,
                              void* d_out, int out_size, void* d_ws, size_t ws_size,
                              hipStream_t stream) {
  const float* cur   = (const float*)d_in[0];
  const float* ftrue = (const float*)d_in[1];
  const float* ce_w1 = (const float*)d_in[2];
  const float* ce_b1 = (const float*)d_in[3];
  const float* ce_g  = (const float*)d_in[4];
  const float* ce_be = (const float*)d_in[5];
  const float* ce_w2 = (const float*)d_in[6];
  const float* ce_b2 = (const float*)d_in[7];
  const float* tp_w1 = (const float*)d_in[8];
  const float* tp_b1 = (const float*)d_in[9];
  const float* tp_g  = (const float*)d_in[10];
  const float* tp_be = (const float*)d_in[11];
  const float* tp_w2 = (const float*)d_in[12];
  const float* tp_b2 = (const float*)d_in[13];
  const float* en_w1 = (const float*)d_in[14];
  const float* en_b1 = (const float*)d_in[15];
  const float* en_g  = (const float*)d_in[16];
  const float* en_be = (const float*)d_in[17];
  const float* en_w2 = (const float*)d_in[18];
  const float* en_b2 = (const float*)d_in[19];
  const float* en_w3 = (const float*)d_in[20];
  const float* en_b3 = (const float*)d_in[21];
  const float* rn_w1 = (const float*)d_in[22];
  const float* rn_b1 = (const float*)d_in[23];
  const float* rn_g  = (const float*)d_in[24];
  const float* rn_be = (const float*)d_in[25];
  const float* rn_w2 = (const float*)d_in[26];
  const float* rn_b2 = (const float*)d_in[27];
  (void)in_sizes; (void)n_in; (void)out_size; (void)ws_size;

  char* w = (char*)d_ws;
  size_t off = 0;
  auto alloc = [&](size_t bytes) -> void* {
    void* p = w + off;
    off += (bytes + 255) & ~(size_t)255;
    return p;
  };
  float* part   = (float*)alloc((size_t)8 * B_ * E_ * 4);
  float* ctx    = (float*)alloc((size_t)B_ * E_ * 4);
  float* g1     = (float*)alloc((size_t)B_ * H_ * 4);
  float* ctx_h  = (float*)alloc((size_t)B_ * H_ * 4);
  float* traj   = (float*)alloc((size_t)B_ * NF_ * E_ * 4);
  float* x      = (float*)alloc((size_t)2097152 * 4);
  float* h1     = (float*)alloc((size_t)2048 * 2048 * 4);   // also aliased as split-K partial
  float* u      = (float*)alloc((size_t)2048 * 1024 * 4);
  __hip_bfloat16* inp_b  = (__hip_bfloat16*)alloc((size_t)2048 * 3072 * 2);
  __hip_bfloat16* ub     = (__hip_bfloat16*)alloc((size_t)2048 * 2048 * 2);
  float* srow   = (float*)alloc((size_t)2048 * 4);
  float* energ  = (float*)alloc((size_t)256 * 4);
  float* probs  = (float*)alloc((size_t)256 * 4);
  __hip_bfloat16* rn_w1t = (__hip_bfloat16*)alloc((size_t)2048 * 3072 * 2);
  __hip_bfloat16* rn_w2t = (__hip_bfloat16*)alloc((size_t)1024 * 2048 * 2);
  __hip_bfloat16* en_w1t = (__hip_bfloat16*)alloc((size_t)2048 * 2048 * 2);
  __hip_bfloat16* en_w2t = (__hip_bfloat16*)alloc((size_t)1024 * 2048 * 2);
  // ctx-path skinny-GEMM buffers (split-bf16 kept: exactness of ctx_h/traj base)
  __hip_bfloat16* aA_h = (__hip_bfloat16*)alloc((size_t)B_ * H_ * 2);
  __hip_bfloat16* aA_l = (__hip_bfloat16*)alloc((size_t)B_ * H_ * 2);
  __hip_bfloat16* cw1t_h = (__hip_bfloat16*)alloc((size_t)2048 * 1024 * 2);
  __hip_bfloat16* cw1t_l = (__hip_bfloat16*)alloc((size_t)2048 * 1024 * 2);
  __hip_bfloat16* cw2t_h = (__hip_bfloat16*)alloc((size_t)2048 * 2048 * 2);
  __hip_bfloat16* cw2t_l = (__hip_bfloat16*)alloc((size_t)2048 * 2048 * 2);
  __hip_bfloat16* tw1t_h = (__hip_bfloat16*)alloc((size_t)2048 * 2048 * 2);
  __hip_bfloat16* tw1t_l = (__hip_bfloat16*)alloc((size_t)2048 * 2048 * 2);
  __hip_bfloat16* tw2t_h = (__hip_bfloat16*)alloc((size_t)8192 * 2048 * 2);
  __hip_bfloat16* tw2t_l = (__hip_bfloat16*)alloc((size_t)8192 * 2048 * 2);
  float* skpart = h1;  // split-K partials (max 8*64*8192*4 = 16.78MB == h1 size)

  // ctx = mean_S
  colmean_partial<<<512, 256, 0, stream>>>(cur, part);
  colmean_final<<<256, 256, 0, stream>>>(part, ctx);

  // weight prep (refine/energy: plain bf16)
  transpose_to_bf16<<<dim3(2048 / 32, 3072 / 32), 256, 0, stream>>>(rn_w1, rn_w1t, 3072, 2048);
  transpose_to_bf16<<<dim3(1024 / 32, 2048 / 32), 256, 0, stream>>>(rn_w2, rn_w2t, 2048, 1024);
  transpose_to_bf16<<<dim3(2048 / 32, 2048 / 32), 256, 0, stream>>>(en_w1, en_w1t, 2048, 2048);
  transpose_to_bf16<<<dim3(1024 / 32, 2048 / 32), 256, 0, stream>>>(en_w2, en_w2t, 2048, 1024);
  // weight prep (ctx path: split)
  transpose_to_bf16x2<<<dim3(2048 / 32, 1024 / 32), 256, 0, stream>>>(ce_w1, cw1t_h, cw1t_l, 1024, 2048);
  transpose_to_bf16x2<<<dim3(2048 / 32, 2048 / 32), 256, 0, stream>>>(ce_w2, cw2t_h, cw2t_l, 2048, 2048);
  transpose_to_bf16x2<<<dim3(2048 / 32, 2048 / 32), 256, 0, stream>>>(tp_w1, tw1t_h, tw1t_l, 2048, 2048);
  transpose_to_bf16x2<<<dim3(8192 / 32, 2048 / 32), 256, 0, stream>>>(tp_w2, tw2t_h, tw2t_l, 2048, 8192);

  // ---- context/trajectory path via skinny MFMA GEMMs (M=64, split-bf16) ----
  split_f32<<<(B_ * E_) / 256, 256, 0, stream>>>(ctx, aA_h, aA_l);
  mfma_skinny3<<<dim3(2048 / 128, 4), 256, 0, stream>>>(aA_h, aA_l, cw1t_h, cw1t_l, skpart, 2048, 1024, 256);
  reduce_bias<<<(B_ * 2048) / 256, 256, 0, stream>>>(skpart, ce_b1, g1, 2048, 4);
  ln_kernel2<<<B_, 256, 0, stream>>>(g1, ce_g, ce_be, aA_h, aA_l, H_);
  mfma_skinny3<<<dim3(2048 / 128, 8), 256, 0, stream>>>(aA_h, aA_l, cw2t_h, cw2t_l, skpart, 2048, 2048, 256);
  reduce_bias<<<(B_ * 2048) / 256, 256, 0, stream>>>(skpart, ce_b2, ctx_h, 2048, 8);
  split_f32<<<(B_ * H_) / 256, 256, 0, stream>>>(ctx_h, aA_h, aA_l);
  mfma_skinny3<<<dim3(2048 / 128, 8), 256, 0, stream>>>(aA_h, aA_l, tw1t_h, tw1t_l, skpart, 2048, 2048, 256);
  reduce_bias<<<(B_ * 2048) / 256, 256, 0, stream>>>(skpart, tp_b1, g1, 2048, 8);
  ln_kernel2<<<B_, 256, 0, stream>>>(g1, tp_g, tp_be, aA_h, aA_l, H_);
  mfma_skinny3<<<dim3(8192 / 128, 8), 256, 0, stream>>>(aA_h, aA_l, tw2t_h, tw2t_l, skpart, 8192, 2048, 256);
  reduce_bias<<<(B_ * 8192) / 256, 256, 0, stream>>>(skpart, tp_b2, traj, 8192, 8);

  // hypotheses = traj + noise
  hyp_noise<<<4096, 256, 0, stream>>>(traj, x);

  // refinement loop (plain bf16 GEMMs; x-update fused into GEMM2 epilogue)
  for (int it = 0; it < NIT_; ++it) {
    build_inp<<<dim3(12, 2048), 256, 0, stream>>>(x, ctx_h, inp_b);
    gemm_gl<0><<<dim3(2048 / 64, 2048 / 128), 256, 0, stream>>>(inp_b, rn_w1t, rn_b1, h1,
                                                                2048, 2048, 3072, 0);
    ln_kernel<true, true><<<2048, 256, 0, stream>>>(h1, rn_g, rn_be, ub, 2048);
    gemm_gl<2><<<dim3(1024 / 64, 2048 / 128), 256, 0, stream>>>(ub, rn_w2t, rn_b2, x,
                                                                2048, 1024, 2048, it);
  }

  // energy + softmax + weighted prediction
  build_xcat<<<dim3(8, 2048), 256, 0, stream>>>(x, ctx_h, inp_b);
  gemm_gl<0><<<dim3(2048 / 64, 2048 / 128), 256, 0, stream>>>(inp_b, en_w1t, en_b1, h1,
                                                              2048, 2048, 2048, 0);
  ln_kernel<true, true><<<2048, 256, 0, stream>>>(h1, en_g, en_be, ub, 2048);
  gemm_gl<1><<<dim3(1024 / 64, 2048 / 128), 256, 0, stream>>>(ub, en_w2t, en_b2, u,
                                                              2048, 1024, 2048, 0);
  rowdot<<<2048, 256, 0, stream>>>(u, en_w3, en_b3, srow);
  energy_final<<<256, 256, 0, stream>>>(x, ftrue, srow, energ);
  softmax_probs<<<1, 64, 0, stream>>>(energ, probs);
  predict<<<2048, 256, 0, stream>>>(x, probs, (float*)d_out);
}

// Round 8
// 1700.529 us; speedup vs baseline: 3.3315x; 1.0205x over previous
//
#include <hip/hip_runtime.h>
#include <hip/hip_bf16.h>
#include <stdint.h>

#define B_ 64
#define S_ 1024
#define E_ 1024
#define H_ 2048
#define NF_ 8
#define NH_ 4
#define NIT_ 10

typedef __attribute__((ext_vector_type(8))) short vshort8;
typedef __attribute__((ext_vector_type(8))) __bf16 vbf16x8;
typedef __attribute__((ext_vector_type(4))) float vfloat4;

// ---------------- async global->LDS, 16B per lane ----------------
typedef const __attribute__((address_space(1))) void* gas1_t;
typedef __attribute__((address_space(3))) void* las3_t;
__device__ __forceinline__ void gload16(const void* g, void* l) {
  __builtin_amdgcn_global_load_lds((gas1_t)g, (las3_t)l, 16, 0, 0);
}

// ---------------- threefry2x32 (JAX-exact) ----------------
__device__ __forceinline__ uint32_t rotl32(uint32_t v, int n) { return (v << n) | (v >> (32 - n)); }

__device__ __forceinline__ void threefry2x32(uint32_t k0, uint32_t k1, uint32_t x0, uint32_t x1,
                                             uint32_t& o0, uint32_t& o1) {
  uint32_t ks2 = k0 ^ k1 ^ 0x1BD11BDAu;
  x0 += k0; x1 += k1;
#define TF_R(r) { x0 += x1; x1 = rotl32(x1, (r)); x1 ^= x0; }
  TF_R(13) TF_R(15) TF_R(26) TF_R(6)
  x0 += k1;  x1 += ks2 + 1u;
  TF_R(17) TF_R(29) TF_R(16) TF_R(24)
  x0 += ks2; x1 += k0 + 2u;
  TF_R(13) TF_R(15) TF_R(26) TF_R(6)
  x0 += k0;  x1 += k1 + 3u;
  TF_R(17) TF_R(29) TF_R(16) TF_R(24)
  x0 += k1;  x1 += ks2 + 4u;
  TF_R(13) TF_R(15) TF_R(26) TF_R(6)
  x0 += ks2; x1 += k0 + 5u;
#undef TF_R
  o0 = x0; o1 = x1;
}

// partitionable threefry 32-bit bits: element i -> bits1 ^ bits2 of threefry(key, (0, i))
__device__ __forceinline__ uint32_t tf_bits_part(uint32_t k0, uint32_t k1, uint32_t i) {
  uint32_t o0, o1;
  threefry2x32(k0, k1, 0u, i, o0, o1);
  return o0 ^ o1;
}

// XLA/Giles erfinv (f32)
__device__ __forceinline__ float erfinv_f(float x) {
  float w = -log1pf(-x * x);
  float p;
  if (w < 5.0f) {
    w -= 2.5f;
    p = 2.81022636e-08f;
    p = 3.43273939e-07f + p * w;
    p = -3.5233877e-06f + p * w;
    p = -4.39150654e-06f + p * w;
    p = 0.00021858087f + p * w;
    p = -0.00125372503f + p * w;
    p = -0.00417768164f + p * w;
    p = 0.246640727f + p * w;
    p = 1.50140941f + p * w;
  } else {
    w = sqrtf(w) - 3.0f;
    p = -0.000200214257f;
    p = 0.000100950558f + p * w;
    p = 0.00134934322f + p * w;
    p = -0.00367342844f + p * w;
    p = 0.00573950773f + p * w;
    p = -0.0076224613f + p * w;
    p = 0.00943887047f + p * w;
    p = 1.00167406f + p * w;
    p = 2.83297682f + p * w;
  }
  return p * x;
}

__device__ __forceinline__ float bits_to_normal(uint32_t bits) {
  uint32_t fb = (bits >> 9) | 0x3F800000u;
  float f = __uint_as_float(fb) - 1.0f;       // [0,1)
  const float lo = -0.99999994f;              // nextafter(-1,0)
  float u = fmaxf(lo, f * 2.0f + lo);
  return 1.41421356f * erfinv_f(u);
}

// ---------------- ctx = mean over S ----------------
__global__ __launch_bounds__(256) void colmean_partial(const float* __restrict__ cur,
                                                       float* __restrict__ part) {
  int blk = blockIdx.x;            // 512 blocks: b*8 + chunk
  int b = blk >> 3, c = blk & 7;
  int t = threadIdx.x;
  const float* base = cur + ((size_t)b * S_ + (size_t)c * 128) * E_;
  float4 s = {0.f, 0.f, 0.f, 0.f};
  for (int si = 0; si < 128; ++si) {
    float4 v = *(const float4*)(base + (size_t)si * E_ + t * 4);
    s.x += v.x; s.y += v.y; s.z += v.z; s.w += v.w;
  }
  *(float4*)(part + ((size_t)c * B_ + b) * E_ + t * 4) = s;
}

__global__ __launch_bounds__(256) void colmean_final(const float* __restrict__ part,
                                                     float* __restrict__ ctx) {
  int i = blockIdx.x * 256 + threadIdx.x;  // < 65536
  float s = 0.f;
#pragma unroll
  for (int c = 0; c < 8; ++c) s += part[(size_t)c * (B_ * E_) + i];
  ctx[i] = s * (1.0f / S_);
}

// ---------------- f32 -> bf16 elementwise, 8/thread ----------------
__global__ __launch_bounds__(256) void cvt_bf16_v(const float* __restrict__ X,
                                                  __hip_bfloat16* __restrict__ Y) {
  int i = (blockIdx.x * 256 + threadIdx.x) * 8;
  float4 v0 = *(const float4*)(X + i);
  float4 v1 = *(const float4*)(X + i + 4);
  float v[8] = {v0.x, v0.y, v0.z, v0.w, v1.x, v1.y, v1.z, v1.w};
  __hip_bfloat16 o[8];
#pragma unroll
  for (int j = 0; j < 8; ++j) o[j] = __float2bfloat16(v[j]);
  *(vshort8*)&Y[i] = *(vshort8*)o;
}

// ---------------- one-pass LayerNorm(2048) + relu -> bf16 ----------------
__global__ __launch_bounds__(256) void ln2048(const float* __restrict__ X,
                                              const float* __restrict__ g,
                                              const float* __restrict__ be,
                                              __hip_bfloat16* __restrict__ out) {
  __shared__ float red[256];
  int row = blockIdx.x, t = threadIdx.x;
  const float* xr = X + (size_t)row * 2048 + t * 8;
  float4 v0 = *(const float4*)xr;
  float4 v1 = *(const float4*)(xr + 4);
  float v[8] = {v0.x, v0.y, v0.z, v0.w, v1.x, v1.y, v1.z, v1.w};
  float s = 0.f;
#pragma unroll
  for (int j = 0; j < 8; ++j) s += v[j];
  red[t] = s; __syncthreads();
  for (int k = 128; k > 0; k >>= 1) { if (t < k) red[t] += red[t + k]; __syncthreads(); }
  float mean = red[0] * (1.0f / 2048.0f);
  __syncthreads();
  float s2 = 0.f;
#pragma unroll
  for (int j = 0; j < 8; ++j) { float d = v[j] - mean; s2 += d * d; }
  red[t] = s2; __syncthreads();
  for (int k = 128; k > 0; k >>= 1) { if (t < k) red[t] += red[t + k]; __syncthreads(); }
  float rstd = rsqrtf(red[0] * (1.0f / 2048.0f) + 1e-5f);
  float4 g0 = *(const float4*)(g + t * 8), g1 = *(const float4*)(g + t * 8 + 4);
  float4 b0 = *(const float4*)(be + t * 8), b1 = *(const float4*)(be + t * 8 + 4);
  float gg[8] = {g0.x, g0.y, g0.z, g0.w, g1.x, g1.y, g1.z, g1.w};
  float bb[8] = {b0.x, b0.y, b0.z, b0.w, b1.x, b1.y, b1.z, b1.w};
  __hip_bfloat16 o[8];
#pragma unroll
  for (int j = 0; j < 8; ++j) {
    float y = (v[j] - mean) * rstd * gg[j] + bb[j];
    o[j] = __float2bfloat16(fmaxf(y, 0.f));
  }
  *(vshort8*)&out[(size_t)row * 2048 + t * 8] = *(vshort8*)o;
}

// ---------------- f32 -> bf16 transpose: Wt[n][k] = W[k][n] ----------------
__global__ __launch_bounds__(256) void transpose_to_bf16(const float* __restrict__ W,
                                                         __hip_bfloat16* __restrict__ Wt,
                                                         int K, int N) {
  __shared__ float tile[32][33];
  int n0 = blockIdx.x * 32, k0 = blockIdx.y * 32;
  int tx = threadIdx.x & 31, ty = threadIdx.x >> 5;
  for (int r = ty; r < 32; r += 8) tile[r][tx] = W[(size_t)(k0 + r) * N + n0 + tx];
  __syncthreads();
  for (int r = ty; r < 32; r += 8) Wt[(size_t)(n0 + r) * K + k0 + tx] = __float2bfloat16(tile[tx][r]);
}

// ---------------- skinny bf16 MFMA GEMM (gload16): M=64, tile 64x128, split-K ----------------
__global__ __launch_bounds__(256) void mfma_skinny(const __hip_bfloat16* __restrict__ A,
                                                   const __hip_bfloat16* __restrict__ Bt,
                                                   float* __restrict__ part,
                                                   int N, int K, int Kc) {
  __shared__ short AS[64 * 32];   // 4 KB linear
  __shared__ short BS[128 * 32];  // 8 KB linear
  int t = threadIdx.x;
  int lane = t & 63, wv = t >> 6;
  int n0 = blockIdx.x * 128;
  int kbeg = blockIdx.y * Kc;
  int wn = wv * 32;
  int lrow = lane & 15, kb = (lane >> 4) * 8;
  vfloat4 acc[4][2];
#pragma unroll
  for (int i = 0; i < 4; ++i)
#pragma unroll
    for (int j = 0; j < 2; ++j) acc[i][j] = (vfloat4){0.f, 0.f, 0.f, 0.f};
  const short* Ag = (const short*)A;
  const short* Bg = (const short*)Bt;
  int arow = lane >> 2;        // 0..15
  int acol = (lane & 3) * 8;   // shorts
  for (int k0 = kbeg; k0 < kbeg + Kc; k0 += 32) {
    gload16(Ag + (size_t)(wv * 16 + arow) * K + k0 + acol, &AS[(wv * 16) * 32]);
#pragma unroll
    for (int c = 0; c < 2; ++c)
      gload16(Bg + (size_t)(n0 + c * 64 + wv * 16 + arow) * K + k0 + acol,
              &BS[(c * 64 + wv * 16) * 32]);
    __syncthreads();
    vbf16x8 af[4], bq[2];
#pragma unroll
    for (int i = 0; i < 4; ++i) af[i] = *(const vbf16x8*)&AS[(i * 16 + lrow) * 32 + kb];
#pragma unroll
    for (int j = 0; j < 2; ++j) bq[j] = *(const vbf16x8*)&BS[(wn + j * 16 + lrow) * 32 + kb];
#pragma unroll
    for (int i = 0; i < 4; ++i)
#pragma unroll
      for (int j = 0; j < 2; ++j)
        acc[i][j] = __builtin_amdgcn_mfma_f32_16x16x32_bf16(af[i], bq[j], acc[i][j], 0, 0, 0);
    __syncthreads();
  }
  size_t zbase = (size_t)blockIdx.y * 64;
  int crow0 = (lane >> 4) * 4;
  int ccol0 = n0 + wn + lrow;
#pragma unroll
  for (int i = 0; i < 4; ++i) {
#pragma unroll
    for (int j = 0; j < 2; ++j) {
      int col = ccol0 + j * 16;
#pragma unroll
      for (int r = 0; r < 4; ++r) {
        int rowi = i * 16 + crow0 + r;
        part[(zbase + rowi) * N + col] = acc[i][j][r];
      }
    }
  }
}

// ---------------- C[64][N] = sum_z part[z][64][N] + bias (opt. bf16 copy) ----------------
template <bool BF16OUT>
__global__ __launch_bounds__(256) void reduce_bias(const float* __restrict__ part,
                                                   const float* __restrict__ bias,
                                                   float* __restrict__ C,
                                                   __hip_bfloat16* __restrict__ Cb,
                                                   int N, int SK) {
  int i = blockIdx.x * 256 + threadIdx.x;  // < 64*N
  int col = i & (N - 1);                   // N is a power of two
  float s = bias[col];
  for (int z = 0; z < SK; ++z) s += part[(size_t)z * 64 * N + i];
  C[i] = s;
  if (BF16OUT) Cb[i] = __float2bfloat16(s);
}

// ---------------- bf16 MFMA GEMM via global_load_lds, BK=64 ----------------
// tile: 128(M) x 64(N), 4 waves (2x2), acc[4][2]. MODE: 0=bias, 1=bias+relu,
// 2 = fused x-update: Cout[i] = Cout[i] - 0.1*(acc+bias) (+0.01*noise if it<NIT-1)
template <int MODE>
__global__ __launch_bounds__(256) void gemm_gl(const __hip_bfloat16* __restrict__ A,
                                               const __hip_bfloat16* __restrict__ Bt,
                                               const float* __restrict__ bias,
                                               float* __restrict__ Cout,
                                               int M, int N, int K, int it) {
  __shared__ short Als[128 * 64];  // 16 KB linear
  __shared__ short Bls[64 * 64];   // 8 KB linear
  int t = threadIdx.x;
  int lane = t & 63, wv = t >> 6;
  int n0 = blockIdx.x * 64, m0 = blockIdx.y * 128;
  int wm = (wv >> 1) * 64, wn = (wv & 1) * 32;
  int lrow = lane & 15, kb = (lane >> 4) * 8;
  vfloat4 acc[4][2];
#pragma unroll
  for (int i = 0; i < 4; ++i)
#pragma unroll
    for (int j = 0; j < 2; ++j) acc[i][j] = (vfloat4){0.f, 0.f, 0.f, 0.f};
  const short* Ag = (const short*)A;
  const short* Bg = (const short*)Bt;
  int arow = lane >> 3;        // 0..7 (8 lanes per 128B row)
  int acol = (lane & 7) * 8;   // shorts
  for (int k0 = 0; k0 < K; k0 += 64) {
#pragma unroll
    for (int c = 0; c < 4; ++c)
      gload16(Ag + (size_t)(m0 + c * 32 + wv * 8 + arow) * K + k0 + acol,
              &Als[(c * 32 + wv * 8) * 64]);
#pragma unroll
    for (int c = 0; c < 2; ++c)
      gload16(Bg + (size_t)(n0 + c * 32 + wv * 8 + arow) * K + k0 + acol,
              &Bls[(c * 32 + wv * 8) * 64]);
    __syncthreads();
    vbf16x8 af[2][4], bq[2][2];
#pragma unroll
    for (int ks = 0; ks < 2; ++ks) {
#pragma unroll
      for (int i = 0; i < 4; ++i)
        af[ks][i] = *(const vbf16x8*)&Als[(wm + i * 16 + lrow) * 64 + ks * 32 + kb];
#pragma unroll
      for (int j = 0; j < 2; ++j)
        bq[ks][j] = *(const vbf16x8*)&Bls[(wn + j * 16 + lrow) * 64 + ks * 32 + kb];
    }
#pragma unroll
    for (int ks = 0; ks < 2; ++ks)
#pragma unroll
      for (int i = 0; i < 4; ++i)
#pragma unroll
        for (int j = 0; j < 2; ++j)
          acc[i][j] = __builtin_amdgcn_mfma_f32_16x16x32_bf16(af[ks][i], bq[ks][j], acc[i][j], 0, 0, 0);
    __syncthreads();
  }
  int crow0 = m0 + wm + (lane >> 4) * 4;
  int ccol0 = n0 + wn + lrow;
  if (MODE == 2) {
    uint32_t key0 = 0, key1 = 0;
    bool addn = (it < NIT_ - 1);
    if (addn) threefry2x32(0u, 7u, 0u, (uint32_t)it, key0, key1);  // fold_in(key(7), it)
#pragma unroll
    for (int i = 0; i < 4; ++i) {
#pragma unroll
      for (int j = 0; j < 2; ++j) {
        int col = ccol0 + j * 16;
        float bv = bias[col];
#pragma unroll
        for (int r = 0; r < 4; ++r) {
          uint32_t idx = (uint32_t)(crow0 + i * 16 + r) * N + col;
          float xv = Cout[idx] - 0.1f * (acc[i][j][r] + bv);
          if (addn) xv += 0.01f * bits_to_normal(tf_bits_part(key0, key1, idx));
          Cout[idx] = xv;
        }
      }
    }
  } else {
#pragma unroll
    for (int i = 0; i < 4; ++i) {
#pragma unroll
      for (int j = 0; j < 2; ++j) {
        int col = ccol0 + j * 16;
        float bv = bias[col];
#pragma unroll
        for (int r = 0; r < 4; ++r) {
          float v = acc[i][j][r] + bv;
          if (MODE == 1) v = fmaxf(v, 0.f);
          Cout[(size_t)(crow0 + i * 16 + r) * N + col] = v;
        }
      }
    }
  }
}

// ---------------- hyp = traj + 0.1 * normal(key(42)) ----------------
__global__ __launch_bounds__(256) void hyp_noise(const float* __restrict__ traj,
                                                 float* __restrict__ x) {
  uint32_t j = blockIdx.x * 256 + threadIdx.x;  // < 1048576
#pragma unroll
  for (int h = 0; h < 2; ++h) {
    uint32_t i = j + h * 1048576u;
    float n = bits_to_normal(tf_bits_part(0u, 42u, i));
    uint32_t b0 = i >> 15, fe0 = i & 8191u;
    x[i] = traj[((size_t)b0 << 13) + fe0] + 0.1f * n;
  }
}

// ---------------- build refine input (bf16), 8 cols/thread ----------------
__global__ __launch_bounds__(256) void build_inp_v(const float* __restrict__ x,
                                                   const float* __restrict__ ctx_h,
                                                   __hip_bfloat16* __restrict__ inp) {
  int i = blockIdx.x * 256 + threadIdx.x;  // < 786432 (2048 rows * 384 groups)
  int row = i / 384, cg = i - row * 384;
  int col0 = cg * 8;
  int bh = row >> 3, f = row & 7;
  float v[8];
  if (col0 < E_) {
    const float* p = &x[(size_t)row * E_ + col0];
    *(float4*)&v[0] = *(const float4*)p;
    *(float4*)&v[4] = *(const float4*)(p + 4);
  } else if (col0 < 2 * E_) {
    const float* p = &ctx_h[(size_t)(bh >> 2) * H_ + (col0 - E_)];
    *(float4*)&v[0] = *(const float4*)p;
    *(float4*)&v[4] = *(const float4*)(p + 4);
  } else {
    int c = col0 - 2 * E_;
    int fp = (f == 0) ? 0 : f - 1;
    int fn = (f == NF_ - 1) ? NF_ - 1 : f + 1;
    const float* pp = &x[(size_t)(bh * NF_ + fp) * E_ + c];
    const float* pn = &x[(size_t)(bh * NF_ + fn) * E_ + c];
    float a[8], b[8];
    *(float4*)&a[0] = *(const float4*)pp;
    *(float4*)&a[4] = *(const float4*)(pp + 4);
    *(float4*)&b[0] = *(const float4*)pn;
    *(float4*)&b[4] = *(const float4*)(pn + 4);
#pragma unroll
    for (int j = 0; j < 8; ++j) v[j] = 0.5f * (a[j] + b[j]);
  }
  __hip_bfloat16 o[8];
#pragma unroll
  for (int j = 0; j < 8; ++j) o[j] = __float2bfloat16(v[j]);
  *(vshort8*)&inp[(size_t)row * 3072 + col0] = *(vshort8*)o;
}

// ---------------- energy: concat input (bf16), 8 cols/thread ----------------
__global__ __launch_bounds__(256) void build_xcat_v(const float* __restrict__ x,
                                                    const float* __restrict__ ctx_h,
                                                    __hip_bfloat16* __restrict__ xc) {
  int i = blockIdx.x * 256 + threadIdx.x;  // < 524288 (2048 rows * 256 groups)
  int row = i >> 8, col0 = (i & 255) * 8;
  int bh = row >> 3;
  const float* p = (col0 < E_) ? &x[(size_t)row * E_ + col0]
                               : &ctx_h[(size_t)(bh >> 2) * H_ + (col0 - E_)];
  float v[8];
  *(float4*)&v[0] = *(const float4*)p;
  *(float4*)&v[4] = *(const float4*)(p + 4);
  __hip_bfloat16 o[8];
#pragma unroll
  for (int j = 0; j < 8; ++j) o[j] = __float2bfloat16(v[j]);
  *(vshort8*)&xc[(size_t)row * 2048 + col0] = *(vshort8*)o;
}

// ---------------- per-row dot with en_w3 ----------------
__global__ __launch_bounds__(256) void rowdot(const float* __restrict__ X2,
                                              const float* __restrict__ w3,
                                              const float* __restrict__ b3,
                                              float* __restrict__ srow) {
  __shared__ float red[256];
  int row = blockIdx.x, t = threadIdx.x;
  const float* xr = X2 + (size_t)row * E_;
  float s = 0.f;
  for (int c = t; c < E_; c += 256) s += xr[c] * w3[c];
  red[t] = s; __syncthreads();
  for (int k = 128; k > 0; k >>= 1) { if (t < k) red[t] += red[t + k]; __syncthreads(); }
  if (t == 0) srow[row] = red[0] + b3[0];
}

// ---------------- energies[bh] = coherence + 0.1*smoothness + supervision ----------------
__global__ __launch_bounds__(256) void energy_final(const float* __restrict__ x,
                                                    const float* __restrict__ ft,
                                                    const float* __restrict__ srow,
                                                    float* __restrict__ energ) {
  __shared__ float red[256];
  int bh = blockIdx.x, t = threadIdx.x;
  int b = bh >> 2;
  const float* xb = x + (size_t)bh * (NF_ * E_);
  const float* fb = ft + (size_t)b * (NF_ * E_);
  float sup = 0.f;
  for (int i = t; i < NF_ * E_; i += 256) { float d = xb[i] - fb[i]; sup += d * d; }
  red[t] = sup; __syncthreads();
  for (int k = 128; k > 0; k >>= 1) { if (t < k) red[t] += red[t + k]; __syncthreads(); }
  float supervision = red[0] / (NF_ * E_);
  float smooth = 0.f;
  for (int d = 0; d < NF_ - 1; ++d) {
    __syncthreads();
    float sd = 0.f;
    for (int e = t; e < E_; e += 256) {
      float df = xb[(d + 1) * E_ + e] - xb[d * E_ + e];
      sd += df * df;
    }
    red[t] = sd; __syncthreads();
    for (int k = 128; k > 0; k >>= 1) { if (t < k) red[t] += red[t + k]; __syncthreads(); }
    smooth += sqrtf(red[0]);
  }
  smooth *= (1.0f / (NF_ - 1));
  if (t == 0) {
    float coh = 0.f;
    for (int f = 0; f < NF_; ++f) coh += srow[bh * NF_ + f];
    coh *= (1.0f / NF_);
    energ[bh] = coh + 0.1f * smooth + supervision;
  }
}

__global__ void softmax_probs(const float* __restrict__ energ, float* __restrict__ probs) {
  int b = threadIdx.x;
  if (b < B_) {
    float e[NH_], m = -1e30f;
#pragma unroll
    for (int h = 0; h < NH_; ++h) { e[h] = -energ[b * NH_ + h]; m = fmaxf(m, e[h]); }
    float s = 0.f, p[NH_];
#pragma unroll
    for (int h = 0; h < NH_; ++h) { p[h] = expf(e[h] - m); s += p[h]; }
#pragma unroll
    for (int h = 0; h < NH_; ++h) probs[b * NH_ + h] = p[h] / s;
  }
}

__global__ __launch_bounds__(256) void predict(const float* __restrict__ x,
                                               const float* __restrict__ probs,
                                               float* __restrict__ out) {
  int i = blockIdx.x * 256 + threadIdx.x;  // < 524288
  int b = i >> 13, fe = i & 8191;
  float s = 0.f;
#pragma unroll
  for (int h = 0; h < NH_; ++h) s += x[(size_t)(b * NH_ + h) * 8192 + fe] * probs[b * NH_ + h];
  out[i] = s;
}

extern "C" void kernel_launch(void* const* d_in, const int* in_sizes, int n_in,
                              void* d_out, int out_size, void* d_ws, size_t ws_size,
                              hipStream_t stream) {
  const float* cur   = (const float*)d_in[0];
  const float* ftrue = (const float*)d_in[1];
  const float* ce_w1 = (const float*)d_in[2];
  const float* ce_b1 = (const float*)d_in[3];
  const float* ce_g  = (const float*)d_in[4];
  const float* ce_be = (const float*)d_in[5];
  const float* ce_w2 = (const float*)d_in[6];
  const float* ce_b2 = (const float*)d_in[7];
  const float* tp_w1 = (const float*)d_in[8];
  const float* tp_b1 = (const float*)d_in[9];
  const float* tp_g  = (const float*)d_in[10];
  const float* tp_be = (const float*)d_in[11];
  const float* tp_w2 = (const float*)d_in[12];
  const float* tp_b2 = (const float*)d_in[13];
  const float* en_w1 = (const float*)d_in[14];
  const float* en_b1 = (const float*)d_in[15];
  const float* en_g  = (const float*)d_in[16];
  const float* en_be = (const float*)d_in[17];
  const float* en_w2 = (const float*)d_in[18];
  const float* en_b2 = (const float*)d_in[19];
  const float* en_w3 = (const float*)d_in[20];
  const float* en_b3 = (const float*)d_in[21];
  const float* rn_w1 = (const float*)d_in[22];
  const float* rn_b1 = (const float*)d_in[23];
  const float* rn_g  = (const float*)d_in[24];
  const float* rn_be = (const float*)d_in[25];
  const float* rn_w2 = (const float*)d_in[26];
  const float* rn_b2 = (const float*)d_in[27];
  (void)in_sizes; (void)n_in; (void)out_size; (void)ws_size;

  char* w = (char*)d_ws;
  size_t off = 0;
  auto alloc = [&](size_t bytes) -> void* {
    void* p = w + off;
    off += (bytes + 255) & ~(size_t)255;
    return p;
  };
  float* part   = (float*)alloc((size_t)8 * B_ * E_ * 4);
  float* ctx    = (float*)alloc((size_t)B_ * E_ * 4);
  float* g1     = (float*)alloc((size_t)B_ * H_ * 4);
  float* ctx_h  = (float*)alloc((size_t)B_ * H_ * 4);
  float* traj   = (float*)alloc((size_t)B_ * NF_ * E_ * 4);
  float* x      = (float*)alloc((size_t)2097152 * 4);
  float* h1     = (float*)alloc((size_t)2048 * 2048 * 4);   // aliased as split-K partial
  float* u      = (float*)alloc((size_t)2048 * 1024 * 4);
  __hip_bfloat16* inp_b  = (__hip_bfloat16*)alloc((size_t)2048 * 3072 * 2);
  __hip_bfloat16* ub     = (__hip_bfloat16*)alloc((size_t)2048 * 2048 * 2);
  float* srow   = (float*)alloc((size_t)2048 * 4);
  float* energ  = (float*)alloc((size_t)256 * 4);
  float* probs  = (float*)alloc((size_t)256 * 4);
  __hip_bfloat16* rn_w1t = (__hip_bfloat16*)alloc((size_t)2048 * 3072 * 2);
  __hip_bfloat16* rn_w2t = (__hip_bfloat16*)alloc((size_t)1024 * 2048 * 2);
  __hip_bfloat16* en_w1t = (__hip_bfloat16*)alloc((size_t)2048 * 2048 * 2);
  __hip_bfloat16* en_w2t = (__hip_bfloat16*)alloc((size_t)1024 * 2048 * 2);
  // ctx-path (plain bf16)
  __hip_bfloat16* ctx_b  = (__hip_bfloat16*)alloc((size_t)B_ * E_ * 2);
  __hip_bfloat16* ctxh_b = (__hip_bfloat16*)alloc((size_t)B_ * H_ * 2);
  __hip_bfloat16* lnb    = (__hip_bfloat16*)alloc((size_t)B_ * H_ * 2);
  __hip_bfloat16* cw1t = (__hip_bfloat16*)alloc((size_t)2048 * 1024 * 2);
  __hip_bfloat16* cw2t = (__hip_bfloat16*)alloc((size_t)2048 * 2048 * 2);
  __hip_bfloat16* tw1t = (__hip_bfloat16*)alloc((size_t)2048 * 2048 * 2);
  __hip_bfloat16* tw2t = (__hip_bfloat16*)alloc((size_t)8192 * 2048 * 2);
  float* skpart = h1;  // split-K partials (max 8*64*8192*4 = 16.78MB == h1 size)

  // ctx = mean_S
  colmean_partial<<<512, 256, 0, stream>>>(cur, part);
  colmean_final<<<256, 256, 0, stream>>>(part, ctx);

  // weight prep (all plain bf16)
  transpose_to_bf16<<<dim3(2048 / 32, 3072 / 32), 256, 0, stream>>>(rn_w1, rn_w1t, 3072, 2048);
  transpose_to_bf16<<<dim3(1024 / 32, 2048 / 32), 256, 0, stream>>>(rn_w2, rn_w2t, 2048, 1024);
  transpose_to_bf16<<<dim3(2048 / 32, 2048 / 32), 256, 0, stream>>>(en_w1, en_w1t, 2048, 2048);
  transpose_to_bf16<<<dim3(1024 / 32, 2048 / 32), 256, 0, stream>>>(en_w2, en_w2t, 2048, 1024);
  transpose_to_bf16<<<dim3(2048 / 32, 1024 / 32), 256, 0, stream>>>(ce_w1, cw1t, 1024, 2048);
  transpose_to_bf16<<<dim3(2048 / 32, 2048 / 32), 256, 0, stream>>>(ce_w2, cw2t, 2048, 2048);
  transpose_to_bf16<<<dim3(2048 / 32, 2048 / 32), 256, 0, stream>>>(tp_w1, tw1t, 2048, 2048);
  transpose_to_bf16<<<dim3(8192 / 32, 2048 / 32), 256, 0, stream>>>(tp_w2, tw2t, 2048, 8192);

  // ---- context/trajectory path (plain bf16 skinny GEMMs, M=64) ----
  cvt_bf16_v<<<32, 256, 0, stream>>>(ctx, ctx_b);
  mfma_skinny<<<dim3(16, 4), 256, 0, stream>>>(ctx_b, cw1t, skpart, 2048, 1024, 256);
  reduce_bias<false><<<512, 256, 0, stream>>>(skpart, ce_b1, g1, nullptr, 2048, 4);
  ln2048<<<B_, 256, 0, stream>>>(g1, ce_g, ce_be, lnb);
  mfma_skinny<<<dim3(16, 8), 256, 0, stream>>>(lnb, cw2t, skpart, 2048, 2048, 256);
  reduce_bias<true><<<512, 256, 0, stream>>>(skpart, ce_b2, ctx_h, ctxh_b, 2048, 8);
  mfma_skinny<<<dim3(16, 8), 256, 0, stream>>>(ctxh_b, tw1t, skpart, 2048, 2048, 256);
  reduce_bias<false><<<512, 256, 0, stream>>>(skpart, tp_b1, g1, nullptr, 2048, 8);
  ln2048<<<B_, 256, 0, stream>>>(g1, tp_g, tp_be, lnb);
  mfma_skinny<<<dim3(64, 8), 256, 0, stream>>>(lnb, tw2t, skpart, 8192, 2048, 256);
  reduce_bias<false><<<2048, 256, 0, stream>>>(skpart, tp_b2, traj, nullptr, 8192, 8);

  // hypotheses = traj + noise
  hyp_noise<<<4096, 256, 0, stream>>>(traj, x);

  // refinement loop (bf16 GEMMs, BK=64; x-update fused into GEMM2 epilogue)
  for (int it = 0; it < NIT_; ++it) {
    build_inp_v<<<3072, 256, 0, stream>>>(x, ctx_h, inp_b);
    gemm_gl<0><<<dim3(2048 / 64, 2048 / 128), 256, 0, stream>>>(inp_b, rn_w1t, rn_b1, h1,
                                                                2048, 2048, 3072, 0);
    ln2048<<<2048, 256, 0, stream>>>(h1, rn_g, rn_be, ub);
    gemm_gl<2><<<dim3(1024 / 64, 2048 / 128), 256, 0, stream>>>(ub, rn_w2t, rn_b2, x,
                                                                2048, 1024, 2048, it);
  }

  // energy + softmax + weighted prediction
  build_xcat_v<<<2048, 256, 0, stream>>>(x, ctx_h, inp_b);
  gemm_gl<0><<<dim3(2048 / 64, 2048 / 128), 256, 0, stream>>>(inp_b, en_w1t, en_b1, h1,
                                                              2048, 2048, 2048, 0);
  ln2048<<<2048, 256, 0, stream>>>(h1, en_g, en_be, ub);
  gemm_gl<1><<<dim3(1024 / 64, 2048 / 128), 256, 0, stream>>>(ub, en_w2t, en_b2, u,
                                                              2048, 1024, 2048, 0);
  rowdot<<<2048, 256, 0, stream>>>(u, en_w3, en_b3, srow);
  energy_final<<<256, 256, 0, stream>>>(x, ftrue, srow, energ);
  softmax_probs<<<1, 64, 0, stream>>>(energ, probs);
  predict<<<2048, 256, 0, stream>>>(x, probs, (float*)d_out);
}

// Round 9
// 1353.007 us; speedup vs baseline: 4.1872x; 1.2569x over previous
//
#include <hip/hip_runtime.h>
#include <hip/hip_bf16.h>
#include <stdint.h>

#define B_ 64
#define S_ 1024
#define E_ 1024
#define H_ 2048
#define NF_ 8
#define NH_ 4
#define NIT_ 10

typedef __attribute__((ext_vector_type(8))) short vshort8;
typedef __attribute__((ext_vector_type(8))) __bf16 vbf16x8;
typedef __attribute__((ext_vector_type(4))) float vfloat4;

// ---------------- async global->LDS, 16B per lane ----------------
typedef const __attribute__((address_space(1))) void* gas1_t;
typedef __attribute__((address_space(3))) void* las3_t;
__device__ __forceinline__ void gload16(const void* g, void* l) {
  __builtin_amdgcn_global_load_lds((gas1_t)g, (las3_t)l, 16, 0, 0);
}

// ---------------- threefry2x32 (JAX-exact) ----------------
__device__ __forceinline__ uint32_t rotl32(uint32_t v, int n) { return (v << n) | (v >> (32 - n)); }

__device__ __forceinline__ void threefry2x32(uint32_t k0, uint32_t k1, uint32_t x0, uint32_t x1,
                                             uint32_t& o0, uint32_t& o1) {
  uint32_t ks2 = k0 ^ k1 ^ 0x1BD11BDAu;
  x0 += k0; x1 += k1;
#define TF_R(r) { x0 += x1; x1 = rotl32(x1, (r)); x1 ^= x0; }
  TF_R(13) TF_R(15) TF_R(26) TF_R(6)
  x0 += k1;  x1 += ks2 + 1u;
  TF_R(17) TF_R(29) TF_R(16) TF_R(24)
  x0 += ks2; x1 += k0 + 2u;
  TF_R(13) TF_R(15) TF_R(26) TF_R(6)
  x0 += k0;  x1 += k1 + 3u;
  TF_R(17) TF_R(29) TF_R(16) TF_R(24)
  x0 += k1;  x1 += ks2 + 4u;
  TF_R(13) TF_R(15) TF_R(26) TF_R(6)
  x0 += ks2; x1 += k0 + 5u;
#undef TF_R
  o0 = x0; o1 = x1;
}

// partitionable threefry 32-bit bits: element i -> bits1 ^ bits2 of threefry(key, (0, i))
__device__ __forceinline__ uint32_t tf_bits_part(uint32_t k0, uint32_t k1, uint32_t i) {
  uint32_t o0, o1;
  threefry2x32(k0, k1, 0u, i, o0, o1);
  return o0 ^ o1;
}

// XLA/Giles erfinv (f32)
__device__ __forceinline__ float erfinv_f(float x) {
  float w = -log1pf(-x * x);
  float p;
  if (w < 5.0f) {
    w -= 2.5f;
    p = 2.81022636e-08f;
    p = 3.43273939e-07f + p * w;
    p = -3.5233877e-06f + p * w;
    p = -4.39150654e-06f + p * w;
    p = 0.00021858087f + p * w;
    p = -0.00125372503f + p * w;
    p = -0.00417768164f + p * w;
    p = 0.246640727f + p * w;
    p = 1.50140941f + p * w;
  } else {
    w = sqrtf(w) - 3.0f;
    p = -0.000200214257f;
    p = 0.000100950558f + p * w;
    p = 0.00134934322f + p * w;
    p = -0.00367342844f + p * w;
    p = 0.00573950773f + p * w;
    p = -0.0076224613f + p * w;
    p = 0.00943887047f + p * w;
    p = 1.00167406f + p * w;
    p = 2.83297682f + p * w;
  }
  return p * x;
}

__device__ __forceinline__ float bits_to_normal(uint32_t bits) {
  uint32_t fb = (bits >> 9) | 0x3F800000u;
  float f = __uint_as_float(fb) - 1.0f;       // [0,1)
  const float lo = -0.99999994f;              // nextafter(-1,0)
  float u = fmaxf(lo, f * 2.0f + lo);
  return 1.41421356f * erfinv_f(u);
}

// ---------------- ctx = mean over S ----------------
__global__ __launch_bounds__(256) void colmean_partial(const float* __restrict__ cur,
                                                       float* __restrict__ part) {
  int blk = blockIdx.x;            // 512 blocks: b*8 + chunk
  int b = blk >> 3, c = blk & 7;
  int t = threadIdx.x;
  const float* base = cur + ((size_t)b * S_ + (size_t)c * 128) * E_;
  float4 s = {0.f, 0.f, 0.f, 0.f};
  for (int si = 0; si < 128; ++si) {
    float4 v = *(const float4*)(base + (size_t)si * E_ + t * 4);
    s.x += v.x; s.y += v.y; s.z += v.z; s.w += v.w;
  }
  *(float4*)(part + ((size_t)c * B_ + b) * E_ + t * 4) = s;
}

__global__ __launch_bounds__(256) void colmean_final(const float* __restrict__ part,
                                                     float* __restrict__ ctx) {
  int i = blockIdx.x * 256 + threadIdx.x;  // < 65536
  float s = 0.f;
#pragma unroll
  for (int c = 0; c < 8; ++c) s += part[(size_t)c * (B_ * E_) + i];
  ctx[i] = s * (1.0f / S_);
}

// ---------------- f32 -> bf16 elementwise, 8/thread ----------------
__global__ __launch_bounds__(256) void cvt_bf16_v(const float* __restrict__ X,
                                                  __hip_bfloat16* __restrict__ Y) {
  int i = (blockIdx.x * 256 + threadIdx.x) * 8;
  float4 v0 = *(const float4*)(X + i);
  float4 v1 = *(const float4*)(X + i + 4);
  float v[8] = {v0.x, v0.y, v0.z, v0.w, v1.x, v1.y, v1.z, v1.w};
  __hip_bfloat16 o[8];
#pragma unroll
  for (int j = 0; j < 8; ++j) o[j] = __float2bfloat16(v[j]);
  *(vshort8*)&Y[i] = *(vshort8*)o;
}

// ---------------- f32 -> bf16 transpose with scale: Wt[n][k] = s*W[k][n] ----------------
__global__ __launch_bounds__(256) void transpose_to_bf16(const float* __restrict__ W,
                                                         __hip_bfloat16* __restrict__ Wt,
                                                         int K, int N, float scale) {
  __shared__ float tile[32][33];
  int n0 = blockIdx.x * 32, k0 = blockIdx.y * 32;
  int tx = threadIdx.x & 31, ty = threadIdx.x >> 5;
  for (int r = ty; r < 32; r += 8) tile[r][tx] = W[(size_t)(k0 + r) * N + n0 + tx];
  __syncthreads();
  for (int r = ty; r < 32; r += 8)
    Wt[(size_t)(n0 + r) * K + k0 + tx] = __float2bfloat16(tile[tx][r] * scale);
}

// ---------------- skinny bf16 MFMA GEMM (gload16): M=64, tile 64x128, split-K ----------------
__global__ __launch_bounds__(256) void mfma_skinny(const __hip_bfloat16* __restrict__ A,
                                                   const __hip_bfloat16* __restrict__ Bt,
                                                   float* __restrict__ part,
                                                   int N, int K, int lda, int Kc) {
  __shared__ short AS[64 * 32];   // 4 KB linear
  __shared__ short BS[128 * 32];  // 8 KB linear
  int t = threadIdx.x;
  int lane = t & 63, wv = t >> 6;
  int n0 = blockIdx.x * 128;
  int kbeg = blockIdx.y * Kc;
  int wn = wv * 32;
  int lrow = lane & 15, kb = (lane >> 4) * 8;
  vfloat4 acc[4][2];
#pragma unroll
  for (int i = 0; i < 4; ++i)
#pragma unroll
    for (int j = 0; j < 2; ++j) acc[i][j] = (vfloat4){0.f, 0.f, 0.f, 0.f};
  const short* Ag = (const short*)A;
  const short* Bg = (const short*)Bt;
  int arow = lane >> 2;        // 0..15
  int acol = (lane & 3) * 8;   // shorts
  for (int k0 = kbeg; k0 < kbeg + Kc; k0 += 32) {
    gload16(Ag + (size_t)(wv * 16 + arow) * lda + k0 + acol, &AS[(wv * 16) * 32]);
#pragma unroll
    for (int c = 0; c < 2; ++c)
      gload16(Bg + (size_t)(n0 + c * 64 + wv * 16 + arow) * K + k0 + acol,
              &BS[(c * 64 + wv * 16) * 32]);
    __syncthreads();
    vbf16x8 af[4], bq[2];
#pragma unroll
    for (int i = 0; i < 4; ++i) af[i] = *(const vbf16x8*)&AS[(i * 16 + lrow) * 32 + kb];
#pragma unroll
    for (int j = 0; j < 2; ++j) bq[j] = *(const vbf16x8*)&BS[(wn + j * 16 + lrow) * 32 + kb];
#pragma unroll
    for (int i = 0; i < 4; ++i)
#pragma unroll
      for (int j = 0; j < 2; ++j)
        acc[i][j] = __builtin_amdgcn_mfma_f32_16x16x32_bf16(af[i], bq[j], acc[i][j], 0, 0, 0);
    __syncthreads();
  }
  size_t zbase = (size_t)blockIdx.y * 64;
  int crow0 = (lane >> 4) * 4;
  int ccol0 = n0 + wn + lrow;
#pragma unroll
  for (int i = 0; i < 4; ++i) {
#pragma unroll
    for (int j = 0; j < 2; ++j) {
      int col = ccol0 + j * 16;
#pragma unroll
      for (int r = 0; r < 4; ++r) {
        int rowi = i * 16 + crow0 + r;
        part[(zbase + rowi) * N + col] = acc[i][j][r];
      }
    }
  }
}

// ---------------- C[64][N] = sum_z part[z][64][N] + bias (opt. bf16 copy) ----------------
template <bool BF16OUT>
__global__ __launch_bounds__(256) void reduce_bias(const float* __restrict__ part,
                                                   const float* __restrict__ bias,
                                                   float* __restrict__ C,
                                                   __hip_bfloat16* __restrict__ Cb,
                                                   int N, int SK) {
  int i = blockIdx.x * 256 + threadIdx.x;  // < 64*N
  int col = i & (N - 1);                   // N is a power of two
  float s = bias[col];
  for (int z = 0; z < SK; ++z) s += part[(size_t)z * 64 * N + i];
  C[i] = s;
  if (BF16OUT) Cb[i] = __float2bfloat16(s);
}

// ---------------- fused split-K reduce + LayerNorm(2048) + relu -> bf16 (64 rows) ----------------
__global__ __launch_bounds__(256) void ln2048red(const float* __restrict__ part,
                                                 const float* __restrict__ bias,
                                                 const float* __restrict__ g,
                                                 const float* __restrict__ be,
                                                 __hip_bfloat16* __restrict__ out, int SK) {
  __shared__ float red[256];
  int row = blockIdx.x, t = threadIdx.x;
  int j0 = t * 8;
  float v[8];
  *(float4*)&v[0] = *(const float4*)(bias + j0);
  *(float4*)&v[4] = *(const float4*)(bias + j0 + 4);
  for (int z = 0; z < SK; ++z) {
    const float* p = part + (size_t)z * 64 * 2048 + (size_t)row * 2048 + j0;
    float4 a0 = *(const float4*)p, a1 = *(const float4*)(p + 4);
    v[0] += a0.x; v[1] += a0.y; v[2] += a0.z; v[3] += a0.w;
    v[4] += a1.x; v[5] += a1.y; v[6] += a1.z; v[7] += a1.w;
  }
  float s = 0.f;
#pragma unroll
  for (int j = 0; j < 8; ++j) s += v[j];
  red[t] = s; __syncthreads();
  for (int k = 128; k > 0; k >>= 1) { if (t < k) red[t] += red[t + k]; __syncthreads(); }
  float mean = red[0] * (1.0f / 2048.0f);
  __syncthreads();
  float s2 = 0.f;
#pragma unroll
  for (int j = 0; j < 8; ++j) { float d = v[j] - mean; s2 += d * d; }
  red[t] = s2; __syncthreads();
  for (int k = 128; k > 0; k >>= 1) { if (t < k) red[t] += red[t + k]; __syncthreads(); }
  float rstd = rsqrtf(red[0] * (1.0f / 2048.0f) + 1e-5f);
  __hip_bfloat16 o[8];
#pragma unroll
  for (int j = 0; j < 8; ++j) {
    float y = (v[j] - mean) * rstd * g[j0 + j] + be[j0 + j];
    o[j] = __float2bfloat16(fmaxf(y, 0.f));
  }
  *(vshort8*)&out[(size_t)row * 2048 + j0] = *(vshort8*)o;
}

// ---------------- combine + LayerNorm + relu -> bf16 ----------------
// NEIGH=1: v = G[row][j] + G[prow][2048+j] + G[nrow][2048+j] + cterm[b][j]   (G stride 4096)
// NEIGH=0: v = G[row][j] + cterm[b][j]                                      (G stride 2048)
template <int NEIGH>
__global__ __launch_bounds__(256) void ln_comb(const float* __restrict__ G,
                                               const float* __restrict__ cterm,
                                               const float* __restrict__ g,
                                               const float* __restrict__ be,
                                               __hip_bfloat16* __restrict__ out) {
  __shared__ float red[256];
  int row = blockIdx.x, t = threadIdx.x;
  int j0 = t * 8;
  const int GS = NEIGH ? 4096 : 2048;
  float v[8];
  {
    const float* p = G + (size_t)row * GS + j0;
    float4 a0 = *(const float4*)p, a1 = *(const float4*)(p + 4);
    v[0] = a0.x; v[1] = a0.y; v[2] = a0.z; v[3] = a0.w;
    v[4] = a1.x; v[5] = a1.y; v[6] = a1.z; v[7] = a1.w;
  }
  {
    const float* p = cterm + (size_t)(row >> 5) * 2048 + j0;
    float4 a0 = *(const float4*)p, a1 = *(const float4*)(p + 4);
    v[0] += a0.x; v[1] += a0.y; v[2] += a0.z; v[3] += a0.w;
    v[4] += a1.x; v[5] += a1.y; v[6] += a1.z; v[7] += a1.w;
  }
  if (NEIGH) {
    int f = row & 7;
    int prow = (f == 0) ? row : row - 1;
    int nrow = (f == NF_ - 1) ? row : row + 1;
    const float* pp = G + (size_t)prow * 4096 + 2048 + j0;
    const float* pn = G + (size_t)nrow * 4096 + 2048 + j0;
    float4 a0 = *(const float4*)pp, a1 = *(const float4*)(pp + 4);
    float4 b0 = *(const float4*)pn, b1 = *(const float4*)(pn + 4);
    v[0] += a0.x + b0.x; v[1] += a0.y + b0.y; v[2] += a0.z + b0.z; v[3] += a0.w + b0.w;
    v[4] += a1.x + b1.x; v[5] += a1.y + b1.y; v[6] += a1.z + b1.z; v[7] += a1.w + b1.w;
  }
  float s = 0.f;
#pragma unroll
  for (int j = 0; j < 8; ++j) s += v[j];
  red[t] = s; __syncthreads();
  for (int k = 128; k > 0; k >>= 1) { if (t < k) red[t] += red[t + k]; __syncthreads(); }
  float mean = red[0] * (1.0f / 2048.0f);
  __syncthreads();
  float s2 = 0.f;
#pragma unroll
  for (int j = 0; j < 8; ++j) { float d = v[j] - mean; s2 += d * d; }
  red[t] = s2; __syncthreads();
  for (int k = 128; k > 0; k >>= 1) { if (t < k) red[t] += red[t + k]; __syncthreads(); }
  float rstd = rsqrtf(red[0] * (1.0f / 2048.0f) + 1e-5f);
  __hip_bfloat16 o[8];
#pragma unroll
  for (int j = 0; j < 8; ++j) {
    float y = (v[j] - mean) * rstd * g[j0 + j] + be[j0 + j];
    o[j] = __float2bfloat16(fmaxf(y, 0.f));
  }
  *(vshort8*)&out[(size_t)row * 2048 + j0] = *(vshort8*)o;
}

// ---------------- bf16 MFMA GEMM via global_load_lds, BK=64 ----------------
// tile: 128(M) x 64(N), 4 waves (2x2), acc[4][2].
// MODE 0: bias; MODE 1: bias+relu; MODE 3: raw (no bias);
// MODE 2: fused x-update: x = x - 0.1*(acc+bias) (+0.01*noise if it<NIT-1), also writes bf16 copy
template <int MODE>
__global__ __launch_bounds__(256) void gemm_gl(const __hip_bfloat16* __restrict__ A,
                                               const __hip_bfloat16* __restrict__ Bt,
                                               const float* __restrict__ bias,
                                               float* __restrict__ Cout,
                                               __hip_bfloat16* __restrict__ Cbout,
                                               int M, int N, int K, int it) {
  __shared__ short Als[128 * 64];  // 16 KB linear
  __shared__ short Bls[64 * 64];   // 8 KB linear
  int t = threadIdx.x;
  int lane = t & 63, wv = t >> 6;
  int n0 = blockIdx.x * 64, m0 = blockIdx.y * 128;
  int wm = (wv >> 1) * 64, wn = (wv & 1) * 32;
  int lrow = lane & 15, kb = (lane >> 4) * 8;
  vfloat4 acc[4][2];
#pragma unroll
  for (int i = 0; i < 4; ++i)
#pragma unroll
    for (int j = 0; j < 2; ++j) acc[i][j] = (vfloat4){0.f, 0.f, 0.f, 0.f};
  const short* Ag = (const short*)A;
  const short* Bg = (const short*)Bt;
  int arow = lane >> 3;        // 0..7 (8 lanes per 128B row)
  int acol = (lane & 7) * 8;   // shorts
  for (int k0 = 0; k0 < K; k0 += 64) {
#pragma unroll
    for (int c = 0; c < 4; ++c)
      gload16(Ag + (size_t)(m0 + c * 32 + wv * 8 + arow) * K + k0 + acol,
              &Als[(c * 32 + wv * 8) * 64]);
#pragma unroll
    for (int c = 0; c < 2; ++c)
      gload16(Bg + (size_t)(n0 + c * 32 + wv * 8 + arow) * K + k0 + acol,
              &Bls[(c * 32 + wv * 8) * 64]);
    __syncthreads();
    vbf16x8 af[2][4], bq[2][2];
#pragma unroll
    for (int ks = 0; ks < 2; ++ks) {
#pragma unroll
      for (int i = 0; i < 4; ++i)
        af[ks][i] = *(const vbf16x8*)&Als[(wm + i * 16 + lrow) * 64 + ks * 32 + kb];
#pragma unroll
      for (int j = 0; j < 2; ++j)
        bq[ks][j] = *(const vbf16x8*)&Bls[(wn + j * 16 + lrow) * 64 + ks * 32 + kb];
    }
#pragma unroll
    for (int ks = 0; ks < 2; ++ks)
#pragma unroll
      for (int i = 0; i < 4; ++i)
#pragma unroll
        for (int j = 0; j < 2; ++j)
          acc[i][j] = __builtin_amdgcn_mfma_f32_16x16x32_bf16(af[ks][i], bq[ks][j], acc[i][j], 0, 0, 0);
    __syncthreads();
  }
  int crow0 = m0 + wm + (lane >> 4) * 4;
  int ccol0 = n0 + wn + lrow;
  if (MODE == 2) {
    uint32_t key0 = 0, key1 = 0;
    bool addn = (it < NIT_ - 1);
    if (addn) threefry2x32(0u, 7u, 0u, (uint32_t)it, key0, key1);  // fold_in(key(7), it)
#pragma unroll
    for (int i = 0; i < 4; ++i) {
#pragma unroll
      for (int j = 0; j < 2; ++j) {
        int col = ccol0 + j * 16;
        float bv = bias[col];
#pragma unroll
        for (int r = 0; r < 4; ++r) {
          uint32_t idx = (uint32_t)(crow0 + i * 16 + r) * N + col;
          float xv = Cout[idx] - 0.1f * (acc[i][j][r] + bv);
          if (addn) xv += 0.01f * bits_to_normal(tf_bits_part(key0, key1, idx));
          Cout[idx] = xv;
          Cbout[idx] = __float2bfloat16(xv);
        }
      }
    }
  } else {
#pragma unroll
    for (int i = 0; i < 4; ++i) {
#pragma unroll
      for (int j = 0; j < 2; ++j) {
        int col = ccol0 + j * 16;
        float bv = (MODE == 3) ? 0.f : bias[col];
#pragma unroll
        for (int r = 0; r < 4; ++r) {
          float v = acc[i][j][r] + bv;
          if (MODE == 1) v = fmaxf(v, 0.f);
          Cout[(size_t)(crow0 + i * 16 + r) * N + col] = v;
        }
      }
    }
  }
}

// ---------------- fused: traj = reduce(part)+bias; x[b,h] = traj + 0.1*normal ----------------
__global__ __launch_bounds__(256) void reduce_traj_noise(const float* __restrict__ part,
                                                         const float* __restrict__ bias,
                                                         float* __restrict__ x,
                                                         __hip_bfloat16* __restrict__ xb,
                                                         int SK) {
  int i = blockIdx.x * 256 + threadIdx.x;  // < 524288 (traj index)
  int fe = i & 8191;
  float s = bias[fe];
  for (int z = 0; z < SK; ++z) s += part[(size_t)z * 524288 + i];
  int b = i >> 13;
#pragma unroll
  for (int h = 0; h < NH_; ++h) {
    uint32_t xi = (uint32_t)(b * 32768 + h * 8192 + fe);
    float xv = s + 0.1f * bits_to_normal(tf_bits_part(0u, 42u, xi));
    x[xi] = xv;
    xb[xi] = __float2bfloat16(xv);
  }
}

// ---------------- per-row dot with en_w3 ----------------
__global__ __launch_bounds__(256) void rowdot(const float* __restrict__ X2,
                                              const float* __restrict__ w3,
                                              const float* __restrict__ b3,
                                              float* __restrict__ srow) {
  __shared__ float red[256];
  int row = blockIdx.x, t = threadIdx.x;
  const float* xr = X2 + (size_t)row * E_;
  float s = 0.f;
  for (int c = t; c < E_; c += 256) s += xr[c] * w3[c];
  red[t] = s; __syncthreads();
  for (int k = 128; k > 0; k >>= 1) { if (t < k) red[t] += red[t + k]; __syncthreads(); }
  if (t == 0) srow[row] = red[0] + b3[0];
}

// ---------------- energies[bh] = coherence + 0.1*smoothness + supervision ----------------
__global__ __launch_bounds__(256) void energy_final(const float* __restrict__ x,
                                                    const float* __restrict__ ft,
                                                    const float* __restrict__ srow,
                                                    float* __restrict__ energ) {
  __shared__ float red[256];
  int bh = blockIdx.x, t = threadIdx.x;
  int b = bh >> 2;
  const float* xb = x + (size_t)bh * (NF_ * E_);
  const float* fb = ft + (size_t)b * (NF_ * E_);
  float sup = 0.f;
  for (int i = t; i < NF_ * E_; i += 256) { float d = xb[i] - fb[i]; sup += d * d; }
  red[t] = sup; __syncthreads();
  for (int k = 128; k > 0; k >>= 1) { if (t < k) red[t] += red[t + k]; __syncthreads(); }
  float supervision = red[0] / (NF_ * E_);
  float smooth = 0.f;
  for (int d = 0; d < NF_ - 1; ++d) {
    __syncthreads();
    float sd = 0.f;
    for (int e = t; e < E_; e += 256) {
      float df = xb[(d + 1) * E_ + e] - xb[d * E_ + e];
      sd += df * df;
    }
    red[t] = sd; __syncthreads();
    for (int k = 128; k > 0; k >>= 1) { if (t < k) red[t] += red[t + k]; __syncthreads(); }
    smooth += sqrtf(red[0]);
  }
  smooth *= (1.0f / (NF_ - 1));
  if (t == 0) {
    float coh = 0.f;
    for (int f = 0; f < NF_; ++f) coh += srow[bh * NF_ + f];
    coh *= (1.0f / NF_);
    energ[bh] = coh + 0.1f * smooth + supervision;
  }
}

__global__ void softmax_probs(const float* __restrict__ energ, float* __restrict__ probs) {
  int b = threadIdx.x;
  if (b < B_) {
    float e[NH_], m = -1e30f;
#pragma unroll
    for (int h = 0; h < NH_; ++h) { e[h] = -energ[b * NH_ + h]; m = fmaxf(m, e[h]); }
    float s = 0.f, p[NH_];
#pragma unroll
    for (int h = 0; h < NH_; ++h) { p[h] = expf(e[h] - m); s += p[h]; }
#pragma unroll
    for (int h = 0; h < NH_; ++h) probs[b * NH_ + h] = p[h] / s;
  }
}

__global__ __launch_bounds__(256) void predict(const float* __restrict__ x,
                                               const float* __restrict__ probs,
                                               float* __restrict__ out) {
  int i = blockIdx.x * 256 + threadIdx.x;  // < 524288
  int b = i >> 13, fe = i & 8191;
  float s = 0.f;
#pragma unroll
  for (int h = 0; h < NH_; ++h) s += x[(size_t)(b * NH_ + h) * 8192 + fe] * probs[b * NH_ + h];
  out[i] = s;
}

extern "C" void kernel_launch(void* const* d_in, const int* in_sizes, int n_in,
                              void* d_out, int out_size, void* d_ws, size_t ws_size,
                              hipStream_t stream) {
  const float* cur   = (const float*)d_in[0];
  const float* ftrue = (const float*)d_in[1];
  const float* ce_w1 = (const float*)d_in[2];
  const float* ce_b1 = (const float*)d_in[3];
  const float* ce_g  = (const float*)d_in[4];
  const float* ce_be = (const float*)d_in[5];
  const float* ce_w2 = (const float*)d_in[6];
  const float* ce_b2 = (const float*)d_in[7];
  const float* tp_w1 = (const float*)d_in[8];
  const float* tp_b1 = (const float*)d_in[9];
  const float* tp_g  = (const float*)d_in[10];
  const float* tp_be = (const float*)d_in[11];
  const float* tp_w2 = (const float*)d_in[12];
  const float* tp_b2 = (const float*)d_in[13];
  const float* en_w1 = (const float*)d_in[14];
  const float* en_b1 = (const float*)d_in[15];
  const float* en_g  = (const float*)d_in[16];
  const float* en_be = (const float*)d_in[17];
  const float* en_w2 = (const float*)d_in[18];
  const float* en_b2 = (const float*)d_in[19];
  const float* en_w3 = (const float*)d_in[20];
  const float* en_b3 = (const float*)d_in[21];
  const float* rn_w1 = (const float*)d_in[22];
  const float* rn_b1 = (const float*)d_in[23];
  const float* rn_g  = (const float*)d_in[24];
  const float* rn_be = (const float*)d_in[25];
  const float* rn_w2 = (const float*)d_in[26];
  const float* rn_b2 = (const float*)d_in[27];
  (void)in_sizes; (void)n_in; (void)out_size; (void)ws_size;

  char* w = (char*)d_ws;
  size_t off = 0;
  auto alloc = [&](size_t bytes) -> void* {
    void* p = w + off;
    off += (bytes + 255) & ~(size_t)255;
    return p;
  };
  float* part   = (float*)alloc((size_t)8 * B_ * E_ * 4);
  float* ctx    = (float*)alloc((size_t)B_ * E_ * 4);
  float* g1     = (float*)alloc((size_t)B_ * H_ * 4);
  float* x      = (float*)alloc((size_t)2097152 * 4);
  float* skpart = (float*)alloc((size_t)8 * 64 * 8192 * 4);  // 16.78 MB split-K partials
  float* G      = (float*)alloc((size_t)2048 * 4096 * 4);    // big-GEMM output (33.5 MB)
  float* u      = (float*)alloc((size_t)2048 * 1024 * 4);
  __hip_bfloat16* ub   = (__hip_bfloat16*)alloc((size_t)2048 * 2048 * 2);
  __hip_bfloat16* x_b  = (__hip_bfloat16*)alloc((size_t)2048 * 1024 * 2);
  float* srow   = (float*)alloc((size_t)2048 * 4);
  float* energ  = (float*)alloc((size_t)256 * 4);
  float* probs  = (float*)alloc((size_t)256 * 4);
  float* cterm  = (float*)alloc((size_t)B_ * H_ * 4);
  float* ecterm = (float*)alloc((size_t)B_ * H_ * 4);
  __hip_bfloat16* Wcat_t = (__hip_bfloat16*)alloc((size_t)4096 * 1024 * 2);  // [W1a; 0.5*W1c]^T
  __hip_bfloat16* Wb_t   = (__hip_bfloat16*)alloc((size_t)2048 * 1024 * 2);  // W1b^T
  __hip_bfloat16* rn_w2t = (__hip_bfloat16*)alloc((size_t)1024 * 2048 * 2);
  __hip_bfloat16* en1a_t = (__hip_bfloat16*)alloc((size_t)2048 * 1024 * 2);
  __hip_bfloat16* en1b_t = (__hip_bfloat16*)alloc((size_t)2048 * 1024 * 2);
  __hip_bfloat16* en_w2t = (__hip_bfloat16*)alloc((size_t)1024 * 2048 * 2);
  __hip_bfloat16* ctx_b  = (__hip_bfloat16*)alloc((size_t)B_ * E_ * 2);
  __hip_bfloat16* ctxh_b = (__hip_bfloat16*)alloc((size_t)B_ * H_ * 2);
  __hip_bfloat16* lnb    = (__hip_bfloat16*)alloc((size_t)B_ * H_ * 2);
  __hip_bfloat16* cw1t = (__hip_bfloat16*)alloc((size_t)2048 * 1024 * 2);
  __hip_bfloat16* cw2t = (__hip_bfloat16*)alloc((size_t)2048 * 2048 * 2);
  __hip_bfloat16* tw1t = (__hip_bfloat16*)alloc((size_t)2048 * 2048 * 2);
  __hip_bfloat16* tw2t = (__hip_bfloat16*)alloc((size_t)8192 * 2048 * 2);

  // ctx = mean_S
  colmean_partial<<<512, 256, 0, stream>>>(cur, part);
  colmean_final<<<256, 256, 0, stream>>>(part, ctx);

  // weight prep (bf16, chunked for the concat-elimination)
  transpose_to_bf16<<<dim3(64, 32), 256, 0, stream>>>(rn_w1, Wcat_t, 1024, 2048, 1.0f);
  transpose_to_bf16<<<dim3(64, 32), 256, 0, stream>>>(rn_w1 + (size_t)2048 * 2048,
                                                      Wcat_t + (size_t)2048 * 1024, 1024, 2048, 0.5f);
  transpose_to_bf16<<<dim3(64, 32), 256, 0, stream>>>(rn_w1 + (size_t)1024 * 2048, Wb_t, 1024, 2048, 1.0f);
  transpose_to_bf16<<<dim3(32, 64), 256, 0, stream>>>(rn_w2, rn_w2t, 2048, 1024, 1.0f);
  transpose_to_bf16<<<dim3(64, 32), 256, 0, stream>>>(en_w1, en1a_t, 1024, 2048, 1.0f);
  transpose_to_bf16<<<dim3(64, 32), 256, 0, stream>>>(en_w1 + (size_t)1024 * 2048, en1b_t, 1024, 2048, 1.0f);
  transpose_to_bf16<<<dim3(32, 64), 256, 0, stream>>>(en_w2, en_w2t, 2048, 1024, 1.0f);
  transpose_to_bf16<<<dim3(64, 32), 256, 0, stream>>>(ce_w1, cw1t, 1024, 2048, 1.0f);
  transpose_to_bf16<<<dim3(64, 64), 256, 0, stream>>>(ce_w2, cw2t, 2048, 2048, 1.0f);
  transpose_to_bf16<<<dim3(64, 64), 256, 0, stream>>>(tp_w1, tw1t, 2048, 2048, 1.0f);
  transpose_to_bf16<<<dim3(256, 64), 256, 0, stream>>>(tp_w2, tw2t, 2048, 8192, 1.0f);

  // ---- context/trajectory path (plain bf16 skinny GEMMs, M=64) ----
  cvt_bf16_v<<<32, 256, 0, stream>>>(ctx, ctx_b);
  mfma_skinny<<<dim3(16, 4), 256, 0, stream>>>(ctx_b, cw1t, skpart, 2048, 1024, 1024, 256);
  ln2048red<<<B_, 256, 0, stream>>>(skpart, ce_b1, ce_g, ce_be, lnb, 4);
  mfma_skinny<<<dim3(16, 8), 256, 0, stream>>>(lnb, cw2t, skpart, 2048, 2048, 2048, 256);
  reduce_bias<true><<<512, 256, 0, stream>>>(skpart, ce_b2, g1, ctxh_b, 2048, 8);
  mfma_skinny<<<dim3(16, 8), 256, 0, stream>>>(ctxh_b, tw1t, skpart, 2048, 2048, 2048, 256);
  ln2048red<<<B_, 256, 0, stream>>>(skpart, tp_b1, tp_g, tp_be, lnb, 8);
  mfma_skinny<<<dim3(64, 8), 256, 0, stream>>>(lnb, tw2t, skpart, 8192, 2048, 2048, 256);
  reduce_traj_noise<<<2048, 256, 0, stream>>>(skpart, tp_b2, x, x_b, 8);

  // constant terms (once): cterm = ce @ W1b + rn_b1 ; ecterm = ce @ en_w1b + en_b1
  mfma_skinny<<<dim3(16, 4), 256, 0, stream>>>(ctxh_b, Wb_t, skpart, 2048, 1024, 2048, 256);
  reduce_bias<false><<<512, 256, 0, stream>>>(skpart, rn_b1, cterm, nullptr, 2048, 4);
  mfma_skinny<<<dim3(16, 4), 256, 0, stream>>>(ctxh_b, en1b_t, skpart, 2048, 1024, 2048, 256);
  reduce_bias<false><<<512, 256, 0, stream>>>(skpart, en_b1, ecterm, nullptr, 2048, 4);

  // refinement loop: 3 dispatches/iter
  for (int it = 0; it < NIT_; ++it) {
    gemm_gl<3><<<dim3(64, 16), 256, 0, stream>>>(x_b, Wcat_t, nullptr, G, nullptr,
                                                 2048, 4096, 1024, 0);
    ln_comb<1><<<2048, 256, 0, stream>>>(G, cterm, rn_g, rn_be, ub);
    gemm_gl<2><<<dim3(16, 16), 256, 0, stream>>>(ub, rn_w2t, rn_b2, x, x_b,
                                                 2048, 1024, 2048, it);
  }

  // energy + softmax + weighted prediction
  gemm_gl<3><<<dim3(32, 16), 256, 0, stream>>>(x_b, en1a_t, nullptr, G, nullptr,
                                               2048, 2048, 1024, 0);
  ln_comb<0><<<2048, 256, 0, stream>>>(G, ecterm, en_g, en_be, ub);
  gemm_gl<1><<<dim3(16, 16), 256, 0, stream>>>(ub, en_w2t, en_b2, u, nullptr,
                                               2048, 1024, 2048, 0);
  rowdot<<<2048, 256, 0, stream>>>(u, en_w3, en_b3, srow);
  energy_final<<<256, 256, 0, stream>>>(x, ftrue, srow, energ);
  softmax_probs<<<1, 64, 0, stream>>>(energ, probs);
  predict<<<2048, 256, 0, stream>>>(x, probs, (float*)d_out);
}